// Round 5
// baseline (1689.215 us; speedup 1.0000x reference)
//
#include <hip/hip_runtime.h>

#define NN 200000
#define NE 400000
#define DD 128
#define NL 5
#define AV 100
#define BV 10
#define EPSV 1e-5f
#define SCAN_BLKS 196   // ceil(NN/1024)

typedef short s8v __attribute__((ext_vector_type(8)));   // 8 bf16 (4 VGPRs)
typedef float f4v __attribute__((ext_vector_type(4)));   // 4 fp32 acc

__device__ __forceinline__ ushort f2bf(float f) {        // RNE float->bf16
  uint u = __float_as_uint(f);
  u += 0x7FFFu + ((u >> 16) & 1u);
  return (ushort)(u >> 16);
}

// ---------- encode: h = sum of atom embeddings; out(fp32) = h; hbuf(bf16) = h ----------
__global__ __launch_bounds__(256) void k_encode(const int* __restrict__ x,
    const float* __restrict__ at, ushort* __restrict__ hbuf, float* __restrict__ out) {
  int idx = blockIdx.x * 256 + threadIdx.x;       // N*D/2 threads exact
  int n = idx >> 6, dp = idx & 63;                // wave = one node -> x row broadcast
  const int* xr = x + n * 9;
  float s0 = 0.f, s1 = 0.f;
#pragma unroll
  for (int c = 0; c < 9; ++c) {
    float2 v = *(const float2*)&at[(c * AV + xr[c]) * DD + dp * 2];
    s0 += v.x; s1 += v.y;
  }
  *(float2*)&out[idx * 2] = make_float2(s0, s1);
  ((uint*)hbuf)[idx] = (uint)f2bf(s0) | ((uint)f2bf(s1) << 16);
}

// ---------- degree ----------
__global__ __launch_bounds__(256) void k_deg_init(float* __restrict__ deg,
                                                  int* __restrict__ cnt) {
  int i = blockIdx.x * 256 + threadIdx.x;
  if (i < NN) { deg[i] = 1.0f; cnt[i] = 0; }
}

__global__ __launch_bounds__(256) void k_deg_count(const int* __restrict__ ei,
    float* __restrict__ deg, int* __restrict__ cnt) {
  int e = blockIdx.x * 256 + threadIdx.x;
  if (e < NE) {
    atomicAdd(&deg[ei[e]], 1.0f);
    atomicAdd(&cnt[ei[NE + e]], 1);
  }
}

__global__ __launch_bounds__(256) void k_deg_fin(const float* __restrict__ deg,
    float* __restrict__ dis, float* __restrict__ invd) {
  int i = blockIdx.x * 256 + threadIdx.x;
  if (i < NN) {
    float dg = deg[i];
    dis[i] = rsqrtf(dg);
    invd[i] = 1.0f / dg;
  }
}

// ---------- exclusive scan of cnt -> off ----------
__global__ __launch_bounds__(256) void k_scan1(const int* __restrict__ cnt,
    int* __restrict__ off, int* __restrict__ bsum) {
  __shared__ int s[256];
  int t = threadIdx.x;
  int base = blockIdx.x * 1024 + t * 4;
  int c0 = (base + 0 < NN) ? cnt[base + 0] : 0;
  int c1 = (base + 1 < NN) ? cnt[base + 1] : 0;
  int c2 = (base + 2 < NN) ? cnt[base + 2] : 0;
  int c3 = (base + 3 < NN) ? cnt[base + 3] : 0;
  int tsum = c0 + c1 + c2 + c3;
  s[t] = tsum;
  __syncthreads();
  for (int o = 1; o < 256; o <<= 1) {
    int v = (t >= o) ? s[t - o] : 0;
    __syncthreads();
    s[t] += v;
    __syncthreads();
  }
  int excl = s[t] - tsum;
  if (base + 0 < NN) off[base + 0] = excl;
  if (base + 1 < NN) off[base + 1] = excl + c0;
  if (base + 2 < NN) off[base + 2] = excl + c0 + c1;
  if (base + 3 < NN) off[base + 3] = excl + c0 + c1 + c2;
  if (t == 255) bsum[blockIdx.x] = s[255];
}

__global__ __launch_bounds__(256) void k_scan2(const int* __restrict__ bsum,
    int* __restrict__ bbase) {
  __shared__ int s[256];
  int t = threadIdx.x;
  int v0 = (t < SCAN_BLKS) ? bsum[t] : 0;
  s[t] = v0;
  __syncthreads();
  for (int o = 1; o < 256; o <<= 1) {
    int v = (t >= o) ? s[t - o] : 0;
    __syncthreads();
    s[t] += v;
    __syncthreads();
  }
  if (t < SCAN_BLKS) bbase[t] = s[t] - v0;
}

__global__ __launch_bounds__(256) void k_scan3(int* __restrict__ off,
    const int* __restrict__ bbase, int* __restrict__ nxt) {
  int i = blockIdx.x * 256 + threadIdx.x;
  if (i < NN) {
    int v = off[i] + bbase[i >> 10];
    off[i] = v;
    nxt[i] = v;
  }
  if (i == 0) off[NN] = NE;
}

// ---------- fill CSR records: {row, packed_ea, norm_bits, 0} ----------
__global__ __launch_bounds__(256) void k_fill(const int* __restrict__ ei,
    const int* __restrict__ ea, const float* __restrict__ dis,
    int* __restrict__ nxt, int4* __restrict__ recs) {
  int e = blockIdx.x * 256 + threadIdx.x;
  if (e >= NE) return;
  int r = ei[e], c = ei[NE + e];
  int pa = ea[e * 3 + 0] + ea[e * 3 + 1] * 10 + ea[e * 3 + 2] * 100;
  float nr = dis[r] * dis[c];
  int pos = atomicAdd(&nxt[c], 1);
  recs[pos] = make_int4(r, pa, __float_as_int(nr), 0);
}

// ---------- combined bond table (fp32): btc[pa][d] ----------
__global__ __launch_bounds__(256) void k_btc(const float* __restrict__ bt,
    float* __restrict__ btc) {
  int idx = blockIdx.x * 256 + threadIdx.x;       // 1000*128 exact
  int p = idx >> 7, d = idx & 127;
  int a = p % 10, b = (p / 10) % 10, c = p / 100;
  btc[idx] = bt[(0 * BV + a) * DD + d] + bt[(1 * BV + b) * DD + d]
           + bt[(2 * BV + c) * DD + d];
}

// ---------- W -> bf16 ----------
__global__ __launch_bounds__(256) void k_wconv(const float* __restrict__ W,
    ushort* __restrict__ Wbf) {
  int i = blockIdx.x * 256 + threadIdx.x;         // 5*128*128 exact
  Wbf[i] = f2bf(W[i]);
}

// ---------- MFMA GEMM: hl(fp32) = A' @ Wl^T + bl ----------
// mode0: A' = hbuf (bf16).  mode1: A' = relu(pre*scale+shift) (fp32->bf16), fused out += A'.
// Per block: 128 nodes, 4 waves x 32 nodes. Fragments direct from global (no LDS).
__global__ __launch_bounds__(256) void k_gemm(const ushort* __restrict__ srcbf,
    const float* __restrict__ srcf, const ushort* __restrict__ Wbf,
    const float* __restrict__ bl, const float* __restrict__ scale,
    const float* __restrict__ shift, float* __restrict__ outacc,
    float* __restrict__ hl, int mode) {
  int t = threadIdx.x;
  int lane = t & 63, wave = t >> 6;
  int col = lane & 15, quad = lane >> 4;
  int nb = blockIdx.x * 128 + wave * 32;
  int r0 = nb + col, r1 = nb + 16 + col;
  bool v0 = r0 < NN, v1 = r1 < NN;
  long a0off = (long)(v0 ? r0 : NN - 1) * DD;
  long a1off = (long)(v1 ? r1 : NN - 1) * DD;

  f4v acc[2][8];
#pragma unroll
  for (int i = 0; i < 2; ++i)
#pragma unroll
    for (int j = 0; j < 8; ++j) acc[i][j] = (f4v)0.f;

#pragma unroll 1
  for (int ks = 0; ks < 4; ++ks) {
    int k0 = ks * 32 + quad * 8;                  // A[m=col][k=quad*8+j]
    s8v a0, a1;
    if (mode == 0) {
      a0 = *(const s8v*)&srcbf[a0off + k0];
      a1 = *(const s8v*)&srcbf[a1off + k0];
    } else {
      float4 sc0 = *(const float4*)&scale[k0];
      float4 sc1 = *(const float4*)&scale[k0 + 4];
      float4 sh0 = *(const float4*)&shift[k0];
      float4 sh1 = *(const float4*)&shift[k0 + 4];
      float scv[8] = {sc0.x, sc0.y, sc0.z, sc0.w, sc1.x, sc1.y, sc1.z, sc1.w};
      float shv[8] = {sh0.x, sh0.y, sh0.z, sh0.w, sh1.x, sh1.y, sh1.z, sh1.w};
      float4 p0 = *(const float4*)&srcf[a0off + k0];
      float4 p1 = *(const float4*)&srcf[a0off + k0 + 4];
      float w[8] = {p0.x, p0.y, p0.z, p0.w, p1.x, p1.y, p1.z, p1.w};
#pragma unroll
      for (int j = 0; j < 8; ++j) w[j] = fmaxf(w[j] * scv[j] + shv[j], 0.f);
      if (v0) {
        float4 o0 = *(const float4*)&outacc[a0off + k0];
        float4 o1 = *(const float4*)&outacc[a0off + k0 + 4];
        o0.x += w[0]; o0.y += w[1]; o0.z += w[2]; o0.w += w[3];
        o1.x += w[4]; o1.y += w[5]; o1.z += w[6]; o1.w += w[7];
        *(float4*)&outacc[a0off + k0] = o0;
        *(float4*)&outacc[a0off + k0 + 4] = o1;
      }
#pragma unroll
      for (int j = 0; j < 8; ++j) a0[j] = (short)f2bf(w[j]);
      p0 = *(const float4*)&srcf[a1off + k0];
      p1 = *(const float4*)&srcf[a1off + k0 + 4];
      float u[8] = {p0.x, p0.y, p0.z, p0.w, p1.x, p1.y, p1.z, p1.w};
#pragma unroll
      for (int j = 0; j < 8; ++j) u[j] = fmaxf(u[j] * scv[j] + shv[j], 0.f);
      if (v1) {
        float4 o0 = *(const float4*)&outacc[a1off + k0];
        float4 o1 = *(const float4*)&outacc[a1off + k0 + 4];
        o0.x += u[0]; o0.y += u[1]; o0.z += u[2]; o0.w += u[3];
        o1.x += u[4]; o1.y += u[5]; o1.z += u[6]; o1.w += u[7];
        *(float4*)&outacc[a1off + k0] = o0;
        *(float4*)&outacc[a1off + k0 + 4] = o1;
      }
#pragma unroll
      for (int j = 0; j < 8; ++j) a1[j] = (short)f2bf(u[j]);
    }
#pragma unroll
    for (int j = 0; j < 8; ++j) {                 // B[k][n=col] for out-tile j = W[j*16+col][k]
      s8v bf = *(const s8v*)&Wbf[(j * 16 + col) * DD + k0];
      acc[0][j] = __builtin_amdgcn_mfma_f32_16x16x32_bf16(a0, bf, acc[0][j], 0, 0, 0);
      acc[1][j] = __builtin_amdgcn_mfma_f32_16x16x32_bf16(a1, bf, acc[1][j], 0, 0, 0);
    }
  }

  float bb[8];
#pragma unroll
  for (int j = 0; j < 8; ++j) bb[j] = bl[j * 16 + col];
#pragma unroll
  for (int i = 0; i < 2; ++i) {
    int rowb = nb + i * 16 + quad * 4;            // D: col=lane&15, row=quad*4+reg
#pragma unroll
    for (int r = 0; r < 4; ++r) {
      int n = rowb + r;
      if (n < NN) {
#pragma unroll
        for (int j = 0; j < 8; ++j)
          hl[(long)n * DD + j * 16 + col] = acc[i][j][r] + bb[j];
      }
    }
  }
}

// ---------- gather-aggregate + self term + BN partials ----------
// QUARTER-wave (16 lanes) owns a CONTIGUOUS run of 8 nodes (base = blk*128 + qs*8);
// lane covers d = (lane&15)*8 .. +7 (2x float4 = 32B/lane, 512B row).
// Because the 8 nodes' CSR records are one contiguous recs range, the next
// record address is always eptr+2 independent of off[] -> rolling 2-record
// prefetch hides the recs latency under the gather wait, and off[base+j+2]
// is issued one node ahead. Steady state: ~1 exposed round-trip per 2 edges
// (the gather itself) instead of ~3 per node.
// NN%8==0 and grid*128 >= NN with 8|base  =>  base<NN implies all 8 nodes valid.
__global__ __launch_bounds__(256, 8) void k_aggregate(const float* __restrict__ hl,
    const int* __restrict__ off, const int4* __restrict__ recs,
    const float* __restrict__ btc, const float* __restrict__ rootl,
    const float* __restrict__ invd, float* __restrict__ pre,
    float* __restrict__ gsum, float* __restrict__ gss) {
  __shared__ float redS[256][9], redQ[256][9];     // +1 pad: conflict-free
  int t = threadIdx.x;
  int ql = t & 15;                                 // lane within quarter-wave
  int qs = t >> 4;                                 // quarter-slot 0..15
  int d0 = ql * 8;
  int base = blockIdx.x * 128 + qs * 8;
  float4 rt0 = *(const float4*)&rootl[d0];
  float4 rt1 = *(const float4*)&rootl[d0 + 4];
  float4 s0 = make_float4(0.f, 0.f, 0.f, 0.f), s1 = s0;
  float4 q0 = s0, q1 = s0;
  if (base < NN) {
    int eptr = off[base];
    int enext = off[base + 1];
    int4 r0 = recs[(eptr < NE) ? eptr : (NE - 1)];           // rolling prefetch regs
    int4 r1 = recs[(eptr + 1 < NE) ? eptr + 1 : (NE - 1)];
#pragma unroll 1
    for (int j = 0; j < 8; ++j) {
      int n = base + j;
      int ia = base + j + 2; if (ia > NN) ia = NN;
      int e_after = off[ia];                       // issued early, used next iter
      int eend = enext;
      float4 sva = *(const float4*)&hl[(long)n * DD + d0];   // self-term, overlaps
      float4 svb = *(const float4*)&hl[(long)n * DD + d0 + 4];
      float iv = invd[n];
      float4 aca = make_float4(0.f, 0.f, 0.f, 0.f), acb = aca;
      while (eptr + 2 <= eend) {                   // 2 edges per trip
        int4 ra = r0, rb = r1;
        int p0 = eptr + 2; if (p0 >= NE) p0 = NE - 1;
        int p1 = eptr + 3; if (p1 >= NE) p1 = NE - 1;
        r0 = recs[p0];                             // prefetch next pair (in flight
        r1 = recs[p1];                             //  during this trip's gathers)
        float4 ha0 = *(const float4*)&hl[(long)ra.x * DD + d0];
        float4 ha1 = *(const float4*)&hl[(long)ra.x * DD + d0 + 4];
        float4 ea0 = *(const float4*)&btc[ra.y * DD + d0];
        float4 ea1 = *(const float4*)&btc[ra.y * DD + d0 + 4];
        float4 hb0 = *(const float4*)&hl[(long)rb.x * DD + d0];
        float4 hb1 = *(const float4*)&hl[(long)rb.x * DD + d0 + 4];
        float4 eb0 = *(const float4*)&btc[rb.y * DD + d0];
        float4 eb1 = *(const float4*)&btc[rb.y * DD + d0 + 4];
        float na = __int_as_float(ra.z);
        float nb = __int_as_float(rb.z);
        aca.x += fmaxf(ha0.x + ea0.x, 0.f) * na + fmaxf(hb0.x + eb0.x, 0.f) * nb;
        aca.y += fmaxf(ha0.y + ea0.y, 0.f) * na + fmaxf(hb0.y + eb0.y, 0.f) * nb;
        aca.z += fmaxf(ha0.z + ea0.z, 0.f) * na + fmaxf(hb0.z + eb0.z, 0.f) * nb;
        aca.w += fmaxf(ha0.w + ea0.w, 0.f) * na + fmaxf(hb0.w + eb0.w, 0.f) * nb;
        acb.x += fmaxf(ha1.x + ea1.x, 0.f) * na + fmaxf(hb1.x + eb1.x, 0.f) * nb;
        acb.y += fmaxf(ha1.y + ea1.y, 0.f) * na + fmaxf(hb1.y + eb1.y, 0.f) * nb;
        acb.z += fmaxf(ha1.z + ea1.z, 0.f) * na + fmaxf(hb1.z + eb1.z, 0.f) * nb;
        acb.w += fmaxf(ha1.w + ea1.w, 0.f) * na + fmaxf(hb1.w + eb1.w, 0.f) * nb;
        eptr += 2;
      }
      if (eptr < eend) {                           // odd leftover edge
        int4 ra = r0;
        int4 tmp = r1;
        int p0 = eptr + 2; if (p0 >= NE) p0 = NE - 1;
        r1 = recs[p0];                             // maintain rolling invariant
        r0 = tmp;
        float4 hv0 = *(const float4*)&hl[(long)ra.x * DD + d0];
        float4 hv1 = *(const float4*)&hl[(long)ra.x * DD + d0 + 4];
        float4 ev0 = *(const float4*)&btc[ra.y * DD + d0];
        float4 ev1 = *(const float4*)&btc[ra.y * DD + d0 + 4];
        float nr = __int_as_float(ra.z);
        aca.x += fmaxf(hv0.x + ev0.x, 0.f) * nr;
        aca.y += fmaxf(hv0.y + ev0.y, 0.f) * nr;
        aca.z += fmaxf(hv0.z + ev0.z, 0.f) * nr;
        aca.w += fmaxf(hv0.w + ev0.w, 0.f) * nr;
        acb.x += fmaxf(hv1.x + ev1.x, 0.f) * nr;
        acb.y += fmaxf(hv1.y + ev1.y, 0.f) * nr;
        acb.z += fmaxf(hv1.z + ev1.z, 0.f) * nr;
        acb.w += fmaxf(hv1.w + ev1.w, 0.f) * nr;
        eptr += 1;
      }
      float4 pa, pb;
      pa.x = aca.x + fmaxf(sva.x + rt0.x, 0.f) * iv;
      pa.y = aca.y + fmaxf(sva.y + rt0.y, 0.f) * iv;
      pa.z = aca.z + fmaxf(sva.z + rt0.z, 0.f) * iv;
      pa.w = aca.w + fmaxf(sva.w + rt0.w, 0.f) * iv;
      pb.x = acb.x + fmaxf(svb.x + rt1.x, 0.f) * iv;
      pb.y = acb.y + fmaxf(svb.y + rt1.y, 0.f) * iv;
      pb.z = acb.z + fmaxf(svb.z + rt1.z, 0.f) * iv;
      pb.w = acb.w + fmaxf(svb.w + rt1.w, 0.f) * iv;
      *(float4*)&pre[(long)n * DD + d0] = pa;
      *(float4*)&pre[(long)n * DD + d0 + 4] = pb;
      s0.x += pa.x; s0.y += pa.y; s0.z += pa.z; s0.w += pa.w;
      s1.x += pb.x; s1.y += pb.y; s1.z += pb.z; s1.w += pb.w;
      q0.x += pa.x * pa.x; q0.y += pa.y * pa.y; q0.z += pa.z * pa.z; q0.w += pa.w * pa.w;
      q1.x += pb.x * pb.x; q1.y += pb.y * pb.y; q1.z += pb.z * pb.z; q1.w += pb.w * pb.w;
      enext = e_after;
    }
  }
  redS[t][0] = s0.x; redS[t][1] = s0.y; redS[t][2] = s0.z; redS[t][3] = s0.w;
  redS[t][4] = s1.x; redS[t][5] = s1.y; redS[t][6] = s1.z; redS[t][7] = s1.w;
  redQ[t][0] = q0.x; redQ[t][1] = q0.y; redQ[t][2] = q0.z; redQ[t][3] = q0.w;
  redQ[t][4] = q1.x; redQ[t][5] = q1.y; redQ[t][6] = q1.z; redQ[t][7] = q1.w;
  __syncthreads();
  if (t < 128) {                                   // d = t; lane qq=d>>3 covers d&7
    int qq = t >> 3, c = t & 7;
    float S = 0.f, Q = 0.f;
#pragma unroll
    for (int h = 0; h < 16; ++h) {
      S += redS[h * 16 + qq][c];
      Q += redQ[h * 16 + qq][c];
    }
    atomicAdd(&gsum[t], S);
    atomicAdd(&gss[t], Q);
  }
}

__global__ void k_bnfin(const float* __restrict__ gsum, const float* __restrict__ gss,
    const float* __restrict__ gl, const float* __restrict__ bl,
    float* __restrict__ scale, float* __restrict__ shift) {
  int d = threadIdx.x;
  float m = gsum[d] * (1.0f / NN);
  float v = gss[d] * (1.0f / NN) - m * m;
  float sc = gl[d] * rsqrtf(v + EPSV);
  scale[d] = sc;
  shift[d] = bl[d] - m * sc;
}

// ---------- final layer apply (no relu): out += pre*scale + shift ----------
__global__ __launch_bounds__(256) void k_apply_final(const float* __restrict__ pre,
    const float* __restrict__ scale, const float* __restrict__ shift,
    float* __restrict__ out) {
  int idx = blockIdx.x * 256 + threadIdx.x;       // N*D/2 exact
  int dp = idx & 63;
  float2 pv = *(const float2*)&pre[idx * 2];
  float2 o = *(const float2*)&out[idx * 2];
  o.x += pv.x * scale[dp * 2] + shift[dp * 2];
  o.y += pv.y * scale[dp * 2 + 1] + shift[dp * 2 + 1];
  *(float2*)&out[idx * 2] = o;
}

extern "C" void kernel_launch(void* const* d_in, const int* in_sizes, int n_in,
                              void* d_out, int out_size, void* d_ws, size_t ws_size,
                              hipStream_t stream) {
  const int*   x     = (const int*)d_in[0];
  const int*   ei    = (const int*)d_in[1];
  const int*   ea    = (const int*)d_in[2];
  const float* at    = (const float*)d_in[3];
  const float* bt    = (const float*)d_in[4];
  const float* W     = (const float*)d_in[5];
  const float* b     = (const float*)d_in[6];
  const float* root  = (const float*)d_in[7];
  const float* gamma = (const float*)d_in[8];
  const float* beta  = (const float*)d_in[9];
  float* out = (float*)d_out;

  char* ws = (char*)d_ws;
  size_t ND = (size_t)NN * DD;
  float*  hl   = (float*)ws;                        // ND fp32
  float*  pre  = hl + ND;                           // ND fp32
  ushort* hbuf = (ushort*)(pre + ND);               // ND bf16
  int4*   recs = (int4*)(hbuf + ND);                // NE * 16B (offset mult of 16B)
  ushort* Wbf  = (ushort*)(recs + NE);              // 5*128*128 bf16
  float*  btc  = (float*)(Wbf + NL * DD * DD);      // 1000*128 fp32
  float*  deg  = btc + 1000 * DD;                   // N
  float*  dis  = deg + NN;                          // N
  float*  invd = dis + NN;                          // N
  int*    cnt  = (int*)(invd + NN);                 // N
  int*    offa = cnt + NN;                          // N+1 (+3 pad)
  int*    nxt  = offa + NN + 4;                     // N
  int*    bsum = nxt + NN;                          // 256
  int*    bbase= bsum + 256;                        // 256
  float*  gsum = (float*)(bbase + 256);             // D
  float*  gss  = gsum + DD;                         // D
  float*  scaleb = gss + DD;                        // D
  float*  shiftb = scaleb + DD;                     // D

  // ---- precompute ----
  k_deg_init<<<(NN + 255) / 256, 256, 0, stream>>>(deg, cnt);
  k_deg_count<<<(NE + 255) / 256, 256, 0, stream>>>(ei, deg, cnt);
  k_deg_fin<<<(NN + 255) / 256, 256, 0, stream>>>(deg, dis, invd);
  k_scan1<<<SCAN_BLKS, 256, 0, stream>>>(cnt, offa, bsum);
  k_scan2<<<1, 256, 0, stream>>>(bsum, bbase);
  k_scan3<<<(NN + 255) / 256, 256, 0, stream>>>(offa, bbase, nxt);
  k_fill<<<(NE + 255) / 256, 256, 0, stream>>>(ei, ea, dis, nxt, recs);
  k_btc<<<1000 * DD / 256, 256, 0, stream>>>(bt, btc);
  k_wconv<<<NL * DD * DD / 256, 256, 0, stream>>>(W, Wbf);
  k_encode<<<(int)(ND / 2 / 256), 256, 0, stream>>>(x, at, hbuf, out);

  // ---- layers ----
  for (int l = 0; l < NL; ++l) {
    hipMemsetAsync(gsum, 0, 2 * DD * sizeof(float), stream);
    k_gemm<<<(NN + 127) / 128, 256, 0, stream>>>(
        hbuf, pre, Wbf + (size_t)l * DD * DD, b + l * DD,
        scaleb, shiftb, out, hl, (l == 0) ? 0 : 1);
    k_aggregate<<<(NN + 127) / 128, 256, 0, stream>>>(hl, offa, recs, btc,
        root + l * DD, invd, pre, gsum, gss);
    k_bnfin<<<1, DD, 0, stream>>>(gsum, gss, gamma + l * DD, beta + l * DD,
                                  scaleb, shiftb);
  }
  k_apply_final<<<(int)(ND / 2 / 256), 256, 0, stream>>>(pre, scaleb, shiftb, out);
}

// Round 6
// 1288.155 us; speedup vs baseline: 1.3113x; 1.3113x over previous
//
#include <hip/hip_runtime.h>

#define NN 200000
#define NE 400000
#define DD 128
#define NL 5
#define AV 100
#define BV 10
#define EPSV 1e-5f
#define SCAN_BLKS 196   // ceil(NN/1024)

typedef short s8v __attribute__((ext_vector_type(8)));   // 8 bf16 (4 VGPRs)
typedef float f4v __attribute__((ext_vector_type(4)));   // 4 fp32 acc

__device__ __forceinline__ ushort f2bf(float f) {        // RNE float->bf16
  uint u = __float_as_uint(f);
  u += 0x7FFFu + ((u >> 16) & 1u);
  return (ushort)(u >> 16);
}

// ---------- encode: h = sum of atom embeddings; out(fp32) = h; hbuf(bf16) = h ----------
__global__ __launch_bounds__(256) void k_encode(const int* __restrict__ x,
    const float* __restrict__ at, ushort* __restrict__ hbuf, float* __restrict__ out) {
  int idx = blockIdx.x * 256 + threadIdx.x;       // N*D/2 threads exact
  int n = idx >> 6, dp = idx & 63;                // wave = one node -> x row broadcast
  const int* xr = x + n * 9;
  float s0 = 0.f, s1 = 0.f;
#pragma unroll
  for (int c = 0; c < 9; ++c) {
    float2 v = *(const float2*)&at[(c * AV + xr[c]) * DD + dp * 2];
    s0 += v.x; s1 += v.y;
  }
  *(float2*)&out[idx * 2] = make_float2(s0, s1);
  ((uint*)hbuf)[idx] = (uint)f2bf(s0) | ((uint)f2bf(s1) << 16);
}

// ---------- degree ----------
__global__ __launch_bounds__(256) void k_deg_init(float* __restrict__ deg,
                                                  int* __restrict__ cnt) {
  int i = blockIdx.x * 256 + threadIdx.x;
  if (i < NN) { deg[i] = 1.0f; cnt[i] = 0; }
}

__global__ __launch_bounds__(256) void k_deg_count(const int* __restrict__ ei,
    float* __restrict__ deg, int* __restrict__ cnt) {
  int e = blockIdx.x * 256 + threadIdx.x;
  if (e < NE) {
    atomicAdd(&deg[ei[e]], 1.0f);
    atomicAdd(&cnt[ei[NE + e]], 1);
  }
}

__global__ __launch_bounds__(256) void k_deg_fin(const float* __restrict__ deg,
    float* __restrict__ dis, float* __restrict__ invd) {
  int i = blockIdx.x * 256 + threadIdx.x;
  if (i < NN) {
    float dg = deg[i];
    dis[i] = rsqrtf(dg);
    invd[i] = 1.0f / dg;
  }
}

// ---------- exclusive scan of cnt -> off ----------
__global__ __launch_bounds__(256) void k_scan1(const int* __restrict__ cnt,
    int* __restrict__ off, int* __restrict__ bsum) {
  __shared__ int s[256];
  int t = threadIdx.x;
  int base = blockIdx.x * 1024 + t * 4;
  int c0 = (base + 0 < NN) ? cnt[base + 0] : 0;
  int c1 = (base + 1 < NN) ? cnt[base + 1] : 0;
  int c2 = (base + 2 < NN) ? cnt[base + 2] : 0;
  int c3 = (base + 3 < NN) ? cnt[base + 3] : 0;
  int tsum = c0 + c1 + c2 + c3;
  s[t] = tsum;
  __syncthreads();
  for (int o = 1; o < 256; o <<= 1) {
    int v = (t >= o) ? s[t - o] : 0;
    __syncthreads();
    s[t] += v;
    __syncthreads();
  }
  int excl = s[t] - tsum;
  if (base + 0 < NN) off[base + 0] = excl;
  if (base + 1 < NN) off[base + 1] = excl + c0;
  if (base + 2 < NN) off[base + 2] = excl + c0 + c1;
  if (base + 3 < NN) off[base + 3] = excl + c0 + c1 + c2;
  if (t == 255) bsum[blockIdx.x] = s[255];
}

__global__ __launch_bounds__(256) void k_scan2(const int* __restrict__ bsum,
    int* __restrict__ bbase) {
  __shared__ int s[256];
  int t = threadIdx.x;
  int v0 = (t < SCAN_BLKS) ? bsum[t] : 0;
  s[t] = v0;
  __syncthreads();
  for (int o = 1; o < 256; o <<= 1) {
    int v = (t >= o) ? s[t - o] : 0;
    __syncthreads();
    s[t] += v;
    __syncthreads();
  }
  if (t < SCAN_BLKS) bbase[t] = s[t] - v0;
}

__global__ __launch_bounds__(256) void k_scan3(int* __restrict__ off,
    const int* __restrict__ bbase, int* __restrict__ nxt) {
  int i = blockIdx.x * 256 + threadIdx.x;
  if (i < NN) {
    int v = off[i] + bbase[i >> 10];
    off[i] = v;
    nxt[i] = v;
  }
  if (i == 0) off[NN] = NE;
}

// ---------- fill CSR records: {row, packed_ea, norm_bits, 0} ----------
__global__ __launch_bounds__(256) void k_fill(const int* __restrict__ ei,
    const int* __restrict__ ea, const float* __restrict__ dis,
    int* __restrict__ nxt, int4* __restrict__ recs) {
  int e = blockIdx.x * 256 + threadIdx.x;
  if (e >= NE) return;
  int r = ei[e], c = ei[NE + e];
  int pa = ea[e * 3 + 0] + ea[e * 3 + 1] * 10 + ea[e * 3 + 2] * 100;
  float nr = dis[r] * dis[c];
  int pos = atomicAdd(&nxt[c], 1);
  recs[pos] = make_int4(r, pa, __float_as_int(nr), 0);
}

// ---------- combined bond table (fp32): btc[pa][d] ----------
__global__ __launch_bounds__(256) void k_btc(const float* __restrict__ bt,
    float* __restrict__ btc) {
  int idx = blockIdx.x * 256 + threadIdx.x;       // 1000*128 exact
  int p = idx >> 7, d = idx & 127;
  int a = p % 10, b = (p / 10) % 10, c = p / 100;
  btc[idx] = bt[(0 * BV + a) * DD + d] + bt[(1 * BV + b) * DD + d]
           + bt[(2 * BV + c) * DD + d];
}

// ---------- W -> bf16 ----------
__global__ __launch_bounds__(256) void k_wconv(const float* __restrict__ W,
    ushort* __restrict__ Wbf) {
  int i = blockIdx.x * 256 + threadIdx.x;         // 5*128*128 exact
  Wbf[i] = f2bf(W[i]);
}

// ---------- MFMA GEMM: hl(fp32) = A' @ Wl^T + bl ----------
// mode0: A' = hbuf (bf16).  mode1: A' = relu(pre*scale+shift) (fp32->bf16), fused out += A'.
// Per block: 128 nodes, 4 waves x 32 nodes. Fragments direct from global (no LDS).
__global__ __launch_bounds__(256) void k_gemm(const ushort* __restrict__ srcbf,
    const float* __restrict__ srcf, const ushort* __restrict__ Wbf,
    const float* __restrict__ bl, const float* __restrict__ scale,
    const float* __restrict__ shift, float* __restrict__ outacc,
    float* __restrict__ hl, int mode) {
  int t = threadIdx.x;
  int lane = t & 63, wave = t >> 6;
  int col = lane & 15, quad = lane >> 4;
  int nb = blockIdx.x * 128 + wave * 32;
  int r0 = nb + col, r1 = nb + 16 + col;
  bool v0 = r0 < NN, v1 = r1 < NN;
  long a0off = (long)(v0 ? r0 : NN - 1) * DD;
  long a1off = (long)(v1 ? r1 : NN - 1) * DD;

  f4v acc[2][8];
#pragma unroll
  for (int i = 0; i < 2; ++i)
#pragma unroll
    for (int j = 0; j < 8; ++j) acc[i][j] = (f4v)0.f;

#pragma unroll 1
  for (int ks = 0; ks < 4; ++ks) {
    int k0 = ks * 32 + quad * 8;                  // A[m=col][k=quad*8+j]
    s8v a0, a1;
    if (mode == 0) {
      a0 = *(const s8v*)&srcbf[a0off + k0];
      a1 = *(const s8v*)&srcbf[a1off + k0];
    } else {
      float4 sc0 = *(const float4*)&scale[k0];
      float4 sc1 = *(const float4*)&scale[k0 + 4];
      float4 sh0 = *(const float4*)&shift[k0];
      float4 sh1 = *(const float4*)&shift[k0 + 4];
      float scv[8] = {sc0.x, sc0.y, sc0.z, sc0.w, sc1.x, sc1.y, sc1.z, sc1.w};
      float shv[8] = {sh0.x, sh0.y, sh0.z, sh0.w, sh1.x, sh1.y, sh1.z, sh1.w};
      float4 p0 = *(const float4*)&srcf[a0off + k0];
      float4 p1 = *(const float4*)&srcf[a0off + k0 + 4];
      float w[8] = {p0.x, p0.y, p0.z, p0.w, p1.x, p1.y, p1.z, p1.w};
#pragma unroll
      for (int j = 0; j < 8; ++j) w[j] = fmaxf(w[j] * scv[j] + shv[j], 0.f);
      if (v0) {
        float4 o0 = *(const float4*)&outacc[a0off + k0];
        float4 o1 = *(const float4*)&outacc[a0off + k0 + 4];
        o0.x += w[0]; o0.y += w[1]; o0.z += w[2]; o0.w += w[3];
        o1.x += w[4]; o1.y += w[5]; o1.z += w[6]; o1.w += w[7];
        *(float4*)&outacc[a0off + k0] = o0;
        *(float4*)&outacc[a0off + k0 + 4] = o1;
      }
#pragma unroll
      for (int j = 0; j < 8; ++j) a0[j] = (short)f2bf(w[j]);
      p0 = *(const float4*)&srcf[a1off + k0];
      p1 = *(const float4*)&srcf[a1off + k0 + 4];
      float u[8] = {p0.x, p0.y, p0.z, p0.w, p1.x, p1.y, p1.z, p1.w};
#pragma unroll
      for (int j = 0; j < 8; ++j) u[j] = fmaxf(u[j] * scv[j] + shv[j], 0.f);
      if (v1) {
        float4 o0 = *(const float4*)&outacc[a1off + k0];
        float4 o1 = *(const float4*)&outacc[a1off + k0 + 4];
        o0.x += u[0]; o0.y += u[1]; o0.z += u[2]; o0.w += u[3];
        o1.x += u[4]; o1.y += u[5]; o1.z += u[6]; o1.w += u[7];
        *(float4*)&outacc[a1off + k0] = o0;
        *(float4*)&outacc[a1off + k0 + 4] = o1;
      }
#pragma unroll
      for (int j = 0; j < 8; ++j) a1[j] = (short)f2bf(u[j]);
    }
#pragma unroll
    for (int j = 0; j < 8; ++j) {                 // B[k][n=col] for out-tile j = W[j*16+col][k]
      s8v bf = *(const s8v*)&Wbf[(j * 16 + col) * DD + k0];
      acc[0][j] = __builtin_amdgcn_mfma_f32_16x16x32_bf16(a0, bf, acc[0][j], 0, 0, 0);
      acc[1][j] = __builtin_amdgcn_mfma_f32_16x16x32_bf16(a1, bf, acc[1][j], 0, 0, 0);
    }
  }

  float bb[8];
#pragma unroll
  for (int j = 0; j < 8; ++j) bb[j] = bl[j * 16 + col];
#pragma unroll
  for (int i = 0; i < 2; ++i) {
    int rowb = nb + i * 16 + quad * 4;            // D: col=lane&15, row=quad*4+reg
#pragma unroll
    for (int r = 0; r < 4; ++r) {
      int n = rowb + r;
      if (n < NN) {
#pragma unroll
        for (int j = 0; j < 8; ++j)
          hl[(long)n * DD + j * 16 + col] = acc[i][j][r] + bb[j];
      }
    }
  }
}

// ---------- gather-aggregate + self term + BN partials ----------
// QUARTER-wave (16 lanes) owns a CONTIGUOUS run of 8 nodes; lane covers
// d = (lane&15)*8 .. +7 (2x float4 = 32B/lane, 512B row). Rolling 2-record
// recs prefetch (next pair addr = eptr+2, independent of off[]) hides recs
// latency under the gather wait; off[] for node j+2 issued one node ahead.
// NOTE: plain __launch_bounds__(256) -- round-5's (256,8) min-waves clause
// capped the allocator at 32 VGPR and spilled the pipeline state to scratch
// (+312 MB FETCH+WRITE, 112->192 us). Registers must breathe (~70 VGPR,
// 7 waves/SIMD); occupancy is not this kernel's constraint.
__global__ __launch_bounds__(256) void k_aggregate(const float* __restrict__ hl,
    const int* __restrict__ off, const int4* __restrict__ recs,
    const float* __restrict__ btc, const float* __restrict__ rootl,
    const float* __restrict__ invd, float* __restrict__ pre,
    float* __restrict__ gsum, float* __restrict__ gss) {
  __shared__ float redS[256][9], redQ[256][9];     // +1 pad: conflict-free
  int t = threadIdx.x;
  int ql = t & 15;                                 // lane within quarter-wave
  int qs = t >> 4;                                 // quarter-slot 0..15
  int d0 = ql * 8;
  int base = blockIdx.x * 128 + qs * 8;
  float4 rt0 = *(const float4*)&rootl[d0];
  float4 rt1 = *(const float4*)&rootl[d0 + 4];
  float4 s0 = make_float4(0.f, 0.f, 0.f, 0.f), s1 = s0;
  float4 q0 = s0, q1 = s0;
  if (base < NN) {
    int eptr = off[base];
    int enext = off[base + 1];
    int4 r0 = recs[(eptr < NE) ? eptr : (NE - 1)];           // rolling prefetch regs
    int4 r1 = recs[(eptr + 1 < NE) ? eptr + 1 : (NE - 1)];
#pragma unroll 1
    for (int j = 0; j < 8; ++j) {
      int n = base + j;
      int ia = base + j + 2; if (ia > NN) ia = NN;
      int e_after = off[ia];                       // issued early, used next iter
      int eend = enext;
      float4 sva = *(const float4*)&hl[(long)n * DD + d0];   // self-term, overlaps
      float4 svb = *(const float4*)&hl[(long)n * DD + d0 + 4];
      float iv = invd[n];
      float4 aca = make_float4(0.f, 0.f, 0.f, 0.f), acb = aca;
      while (eptr + 2 <= eend) {                   // 2 edges per trip
        int4 ra = r0, rb = r1;
        int p0 = eptr + 2; if (p0 >= NE) p0 = NE - 1;
        int p1 = eptr + 3; if (p1 >= NE) p1 = NE - 1;
        r0 = recs[p0];                             // prefetch next pair (in flight
        r1 = recs[p1];                             //  during this trip's gathers)
        float4 ha0 = *(const float4*)&hl[(long)ra.x * DD + d0];
        float4 ha1 = *(const float4*)&hl[(long)ra.x * DD + d0 + 4];
        float4 ea0 = *(const float4*)&btc[ra.y * DD + d0];
        float4 ea1 = *(const float4*)&btc[ra.y * DD + d0 + 4];
        float4 hb0 = *(const float4*)&hl[(long)rb.x * DD + d0];
        float4 hb1 = *(const float4*)&hl[(long)rb.x * DD + d0 + 4];
        float4 eb0 = *(const float4*)&btc[rb.y * DD + d0];
        float4 eb1 = *(const float4*)&btc[rb.y * DD + d0 + 4];
        float na = __int_as_float(ra.z);
        float nb = __int_as_float(rb.z);
        aca.x += fmaxf(ha0.x + ea0.x, 0.f) * na + fmaxf(hb0.x + eb0.x, 0.f) * nb;
        aca.y += fmaxf(ha0.y + ea0.y, 0.f) * na + fmaxf(hb0.y + eb0.y, 0.f) * nb;
        aca.z += fmaxf(ha0.z + ea0.z, 0.f) * na + fmaxf(hb0.z + eb0.z, 0.f) * nb;
        aca.w += fmaxf(ha0.w + ea0.w, 0.f) * na + fmaxf(hb0.w + eb0.w, 0.f) * nb;
        acb.x += fmaxf(ha1.x + ea1.x, 0.f) * na + fmaxf(hb1.x + eb1.x, 0.f) * nb;
        acb.y += fmaxf(ha1.y + ea1.y, 0.f) * na + fmaxf(hb1.y + eb1.y, 0.f) * nb;
        acb.z += fmaxf(ha1.z + ea1.z, 0.f) * na + fmaxf(hb1.z + eb1.z, 0.f) * nb;
        acb.w += fmaxf(ha1.w + ea1.w, 0.f) * na + fmaxf(hb1.w + eb1.w, 0.f) * nb;
        eptr += 2;
      }
      if (eptr < eend) {                           // odd leftover edge
        int4 ra = r0;
        int4 tmp = r1;
        int p0 = eptr + 2; if (p0 >= NE) p0 = NE - 1;
        r1 = recs[p0];                             // maintain rolling invariant
        r0 = tmp;
        float4 hv0 = *(const float4*)&hl[(long)ra.x * DD + d0];
        float4 hv1 = *(const float4*)&hl[(long)ra.x * DD + d0 + 4];
        float4 ev0 = *(const float4*)&btc[ra.y * DD + d0];
        float4 ev1 = *(const float4*)&btc[ra.y * DD + d0 + 4];
        float nr = __int_as_float(ra.z);
        aca.x += fmaxf(hv0.x + ev0.x, 0.f) * nr;
        aca.y += fmaxf(hv0.y + ev0.y, 0.f) * nr;
        aca.z += fmaxf(hv0.z + ev0.z, 0.f) * nr;
        aca.w += fmaxf(hv0.w + ev0.w, 0.f) * nr;
        acb.x += fmaxf(hv1.x + ev1.x, 0.f) * nr;
        acb.y += fmaxf(hv1.y + ev1.y, 0.f) * nr;
        acb.z += fmaxf(hv1.z + ev1.z, 0.f) * nr;
        acb.w += fmaxf(hv1.w + ev1.w, 0.f) * nr;
        eptr += 1;
      }
      float4 pa, pb;
      pa.x = aca.x + fmaxf(sva.x + rt0.x, 0.f) * iv;
      pa.y = aca.y + fmaxf(sva.y + rt0.y, 0.f) * iv;
      pa.z = aca.z + fmaxf(sva.z + rt0.z, 0.f) * iv;
      pa.w = aca.w + fmaxf(sva.w + rt0.w, 0.f) * iv;
      pb.x = acb.x + fmaxf(svb.x + rt1.x, 0.f) * iv;
      pb.y = acb.y + fmaxf(svb.y + rt1.y, 0.f) * iv;
      pb.z = acb.z + fmaxf(svb.z + rt1.z, 0.f) * iv;
      pb.w = acb.w + fmaxf(svb.w + rt1.w, 0.f) * iv;
      *(float4*)&pre[(long)n * DD + d0] = pa;
      *(float4*)&pre[(long)n * DD + d0 + 4] = pb;
      s0.x += pa.x; s0.y += pa.y; s0.z += pa.z; s0.w += pa.w;
      s1.x += pb.x; s1.y += pb.y; s1.z += pb.z; s1.w += pb.w;
      q0.x += pa.x * pa.x; q0.y += pa.y * pa.y; q0.z += pa.z * pa.z; q0.w += pa.w * pa.w;
      q1.x += pb.x * pb.x; q1.y += pb.y * pb.y; q1.z += pb.z * pb.z; q1.w += pb.w * pb.w;
      enext = e_after;
    }
  }
  redS[t][0] = s0.x; redS[t][1] = s0.y; redS[t][2] = s0.z; redS[t][3] = s0.w;
  redS[t][4] = s1.x; redS[t][5] = s1.y; redS[t][6] = s1.z; redS[t][7] = s1.w;
  redQ[t][0] = q0.x; redQ[t][1] = q0.y; redQ[t][2] = q0.z; redQ[t][3] = q0.w;
  redQ[t][4] = q1.x; redQ[t][5] = q1.y; redQ[t][6] = q1.z; redQ[t][7] = q1.w;
  __syncthreads();
  if (t < 128) {                                   // d = t; lane qq=d>>3 covers d&7
    int qq = t >> 3, c = t & 7;
    float S = 0.f, Q = 0.f;
#pragma unroll
    for (int h = 0; h < 16; ++h) {
      S += redS[h * 16 + qq][c];
      Q += redQ[h * 16 + qq][c];
    }
    atomicAdd(&gsum[t], S);
    atomicAdd(&gss[t], Q);
  }
}

__global__ void k_bnfin(const float* __restrict__ gsum, const float* __restrict__ gss,
    const float* __restrict__ gl, const float* __restrict__ bl,
    float* __restrict__ scale, float* __restrict__ shift) {
  int d = threadIdx.x;
  float m = gsum[d] * (1.0f / NN);
  float v = gss[d] * (1.0f / NN) - m * m;
  float sc = gl[d] * rsqrtf(v + EPSV);
  scale[d] = sc;
  shift[d] = bl[d] - m * sc;
}

// ---------- final layer apply (no relu): out += pre*scale + shift ----------
__global__ __launch_bounds__(256) void k_apply_final(const float* __restrict__ pre,
    const float* __restrict__ scale, const float* __restrict__ shift,
    float* __restrict__ out) {
  int idx = blockIdx.x * 256 + threadIdx.x;       // N*D/2 exact
  int dp = idx & 63;
  float2 pv = *(const float2*)&pre[idx * 2];
  float2 o = *(const float2*)&out[idx * 2];
  o.x += pv.x * scale[dp * 2] + shift[dp * 2];
  o.y += pv.y * scale[dp * 2 + 1] + shift[dp * 2 + 1];
  *(float2*)&out[idx * 2] = o;
}

extern "C" void kernel_launch(void* const* d_in, const int* in_sizes, int n_in,
                              void* d_out, int out_size, void* d_ws, size_t ws_size,
                              hipStream_t stream) {
  const int*   x     = (const int*)d_in[0];
  const int*   ei    = (const int*)d_in[1];
  const int*   ea    = (const int*)d_in[2];
  const float* at    = (const float*)d_in[3];
  const float* bt    = (const float*)d_in[4];
  const float* W     = (const float*)d_in[5];
  const float* b     = (const float*)d_in[6];
  const float* root  = (const float*)d_in[7];
  const float* gamma = (const float*)d_in[8];
  const float* beta  = (const float*)d_in[9];
  float* out = (float*)d_out;

  char* ws = (char*)d_ws;
  size_t ND = (size_t)NN * DD;
  float*  hl   = (float*)ws;                        // ND fp32
  float*  pre  = hl + ND;                           // ND fp32
  ushort* hbuf = (ushort*)(pre + ND);               // ND bf16
  int4*   recs = (int4*)(hbuf + ND);                // NE * 16B (offset mult of 16B)
  ushort* Wbf  = (ushort*)(recs + NE);              // 5*128*128 bf16
  float*  btc  = (float*)(Wbf + NL * DD * DD);      // 1000*128 fp32
  float*  deg  = btc + 1000 * DD;                   // N
  float*  dis  = deg + NN;                          // N
  float*  invd = dis + NN;                          // N
  int*    cnt  = (int*)(invd + NN);                 // N
  int*    offa = cnt + NN;                          // N+1 (+3 pad)
  int*    nxt  = offa + NN + 4;                     // N
  int*    bsum = nxt + NN;                          // 256
  int*    bbase= bsum + 256;                        // 256
  float*  gsum = (float*)(bbase + 256);             // D
  float*  gss  = gsum + DD;                         // D
  float*  scaleb = gss + DD;                        // D
  float*  shiftb = scaleb + DD;                     // D

  // ---- precompute ----
  k_deg_init<<<(NN + 255) / 256, 256, 0, stream>>>(deg, cnt);
  k_deg_count<<<(NE + 255) / 256, 256, 0, stream>>>(ei, deg, cnt);
  k_deg_fin<<<(NN + 255) / 256, 256, 0, stream>>>(deg, dis, invd);
  k_scan1<<<SCAN_BLKS, 256, 0, stream>>>(cnt, offa, bsum);
  k_scan2<<<1, 256, 0, stream>>>(bsum, bbase);
  k_scan3<<<(NN + 255) / 256, 256, 0, stream>>>(offa, bbase, nxt);
  k_fill<<<(NE + 255) / 256, 256, 0, stream>>>(ei, ea, dis, nxt, recs);
  k_btc<<<1000 * DD / 256, 256, 0, stream>>>(bt, btc);
  k_wconv<<<NL * DD * DD / 256, 256, 0, stream>>>(W, Wbf);
  k_encode<<<(int)(ND / 2 / 256), 256, 0, stream>>>(x, at, hbuf, out);

  // ---- layers ----
  for (int l = 0; l < NL; ++l) {
    hipMemsetAsync(gsum, 0, 2 * DD * sizeof(float), stream);
    k_gemm<<<(NN + 127) / 128, 256, 0, stream>>>(
        hbuf, pre, Wbf + (size_t)l * DD * DD, b + l * DD,
        scaleb, shiftb, out, hl, (l == 0) ? 0 : 1);
    k_aggregate<<<(NN + 127) / 128, 256, 0, stream>>>(hl, offa, recs, btc,
        root + l * DD, invd, pre, gsum, gss);
    k_bnfin<<<1, DD, 0, stream>>>(gsum, gss, gamma + l * DD, beta + l * DD,
                                  scaleb, shiftb);
  }
  k_apply_final<<<(int)(ND / 2 / 256), 256, 0, stream>>>(pre, scaleb, shiftb, out);
}

// Round 7
// 1139.880 us; speedup vs baseline: 1.4819x; 1.1301x over previous
//
#include <hip/hip_runtime.h>

#define NN 200000
#define NE 400000
#define DD 128
#define NL 5
#define AV 100
#define BV 10
#define EPSV 1e-5f
#define SCAN_BLKS 196   // ceil(NN/1024)

typedef short s8v __attribute__((ext_vector_type(8)));   // 8 bf16 (4 VGPRs)
typedef float f4v __attribute__((ext_vector_type(4)));   // 4 fp32 acc

__device__ __forceinline__ ushort f2bf(float f) {        // RNE float->bf16
  uint u = __float_as_uint(f);
  u += 0x7FFFu + ((u >> 16) & 1u);
  return (ushort)(u >> 16);
}

__device__ __forceinline__ float bf2f(ushort u) {        // bf16->float
  return __uint_as_float(((uint)u) << 16);
}

// ---------- encode: h = sum of atom embeddings; out(fp32) = h; hbuf(bf16) = h ----------
__global__ __launch_bounds__(256) void k_encode(const int* __restrict__ x,
    const float* __restrict__ at, ushort* __restrict__ hbuf, float* __restrict__ out) {
  int idx = blockIdx.x * 256 + threadIdx.x;       // N*D/2 threads exact
  int n = idx >> 6, dp = idx & 63;                // wave = one node -> x row broadcast
  const int* xr = x + n * 9;
  float s0 = 0.f, s1 = 0.f;
#pragma unroll
  for (int c = 0; c < 9; ++c) {
    float2 v = *(const float2*)&at[(c * AV + xr[c]) * DD + dp * 2];
    s0 += v.x; s1 += v.y;
  }
  *(float2*)&out[idx * 2] = make_float2(s0, s1);
  ((uint*)hbuf)[idx] = (uint)f2bf(s0) | ((uint)f2bf(s1) << 16);
}

// ---------- degree ----------
__global__ __launch_bounds__(256) void k_deg_init(float* __restrict__ deg,
                                                  int* __restrict__ cnt) {
  int i = blockIdx.x * 256 + threadIdx.x;
  if (i < NN) { deg[i] = 1.0f; cnt[i] = 0; }
}

__global__ __launch_bounds__(256) void k_deg_count(const int* __restrict__ ei,
    float* __restrict__ deg, int* __restrict__ cnt) {
  int e = blockIdx.x * 256 + threadIdx.x;
  if (e < NE) {
    atomicAdd(&deg[ei[e]], 1.0f);
    atomicAdd(&cnt[ei[NE + e]], 1);
  }
}

__global__ __launch_bounds__(256) void k_deg_fin(const float* __restrict__ deg,
    float* __restrict__ dis, float* __restrict__ invd) {
  int i = blockIdx.x * 256 + threadIdx.x;
  if (i < NN) {
    float dg = deg[i];
    dis[i] = rsqrtf(dg);
    invd[i] = 1.0f / dg;
  }
}

// ---------- exclusive scan of cnt -> off ----------
__global__ __launch_bounds__(256) void k_scan1(const int* __restrict__ cnt,
    int* __restrict__ off, int* __restrict__ bsum) {
  __shared__ int s[256];
  int t = threadIdx.x;
  int base = blockIdx.x * 1024 + t * 4;
  int c0 = (base + 0 < NN) ? cnt[base + 0] : 0;
  int c1 = (base + 1 < NN) ? cnt[base + 1] : 0;
  int c2 = (base + 2 < NN) ? cnt[base + 2] : 0;
  int c3 = (base + 3 < NN) ? cnt[base + 3] : 0;
  int tsum = c0 + c1 + c2 + c3;
  s[t] = tsum;
  __syncthreads();
  for (int o = 1; o < 256; o <<= 1) {
    int v = (t >= o) ? s[t - o] : 0;
    __syncthreads();
    s[t] += v;
    __syncthreads();
  }
  int excl = s[t] - tsum;
  if (base + 0 < NN) off[base + 0] = excl;
  if (base + 1 < NN) off[base + 1] = excl + c0;
  if (base + 2 < NN) off[base + 2] = excl + c0 + c1;
  if (base + 3 < NN) off[base + 3] = excl + c0 + c1 + c2;
  if (t == 255) bsum[blockIdx.x] = s[255];
}

__global__ __launch_bounds__(256) void k_scan2(const int* __restrict__ bsum,
    int* __restrict__ bbase) {
  __shared__ int s[256];
  int t = threadIdx.x;
  int v0 = (t < SCAN_BLKS) ? bsum[t] : 0;
  s[t] = v0;
  __syncthreads();
  for (int o = 1; o < 256; o <<= 1) {
    int v = (t >= o) ? s[t - o] : 0;
    __syncthreads();
    s[t] += v;
    __syncthreads();
  }
  if (t < SCAN_BLKS) bbase[t] = s[t] - v0;
}

__global__ __launch_bounds__(256) void k_scan3(int* __restrict__ off,
    const int* __restrict__ bbase, int* __restrict__ nxt) {
  int i = blockIdx.x * 256 + threadIdx.x;
  if (i < NN) {
    int v = off[i] + bbase[i >> 10];
    off[i] = v;
    nxt[i] = v;
  }
  if (i == 0) off[NN] = NE;
}

// ---------- fill CSR records: {row, packed_ea, norm_bits, 0} ----------
__global__ __launch_bounds__(256) void k_fill(const int* __restrict__ ei,
    const int* __restrict__ ea, const float* __restrict__ dis,
    int* __restrict__ nxt, int4* __restrict__ recs) {
  int e = blockIdx.x * 256 + threadIdx.x;
  if (e >= NE) return;
  int r = ei[e], c = ei[NE + e];
  int pa = ea[e * 3 + 0] + ea[e * 3 + 1] * 10 + ea[e * 3 + 2] * 100;
  float nr = dis[r] * dis[c];
  int pos = atomicAdd(&nxt[c], 1);
  recs[pos] = make_int4(r, pa, __float_as_int(nr), 0);
}

// ---------- combined bond table (fp32): btc[pa][d] ----------
__global__ __launch_bounds__(256) void k_btc(const float* __restrict__ bt,
    float* __restrict__ btc) {
  int idx = blockIdx.x * 256 + threadIdx.x;       // 1000*128 exact
  int p = idx >> 7, d = idx & 127;
  int a = p % 10, b = (p / 10) % 10, c = p / 100;
  btc[idx] = bt[(0 * BV + a) * DD + d] + bt[(1 * BV + b) * DD + d]
           + bt[(2 * BV + c) * DD + d];
}

// ---------- W -> bf16 ----------
__global__ __launch_bounds__(256) void k_wconv(const float* __restrict__ W,
    ushort* __restrict__ Wbf) {
  int i = blockIdx.x * 256 + threadIdx.x;         // 5*128*128 exact
  Wbf[i] = f2bf(W[i]);
}

// ---------- MFMA GEMM: hl(BF16) = A' @ Wl^T + bl ----------
// mode0: A' = hbuf (bf16).  mode1: A' = relu(pre*scale+shift) (fp32->bf16), fused out += A'.
// hl stored as bf16: halves the GEMM write (102->51 MB) and, critically,
// halves k_aggregate's gather footprint (102->51 MB -> L2/L3-resident).
// Per block: 128 nodes, 4 waves x 32 nodes. Fragments direct from global (no LDS).
__global__ __launch_bounds__(256) void k_gemm(const ushort* __restrict__ srcbf,
    const float* __restrict__ srcf, const ushort* __restrict__ Wbf,
    const float* __restrict__ bl, const float* __restrict__ scale,
    const float* __restrict__ shift, float* __restrict__ outacc,
    ushort* __restrict__ hl, int mode) {
  int t = threadIdx.x;
  int lane = t & 63, wave = t >> 6;
  int col = lane & 15, quad = lane >> 4;
  int nb = blockIdx.x * 128 + wave * 32;
  int r0 = nb + col, r1 = nb + 16 + col;
  bool v0 = r0 < NN, v1 = r1 < NN;
  long a0off = (long)(v0 ? r0 : NN - 1) * DD;
  long a1off = (long)(v1 ? r1 : NN - 1) * DD;

  f4v acc[2][8];
#pragma unroll
  for (int i = 0; i < 2; ++i)
#pragma unroll
    for (int j = 0; j < 8; ++j) acc[i][j] = (f4v)0.f;

#pragma unroll 1
  for (int ks = 0; ks < 4; ++ks) {
    int k0 = ks * 32 + quad * 8;                  // A[m=col][k=quad*8+j]
    s8v a0, a1;
    if (mode == 0) {
      a0 = *(const s8v*)&srcbf[a0off + k0];
      a1 = *(const s8v*)&srcbf[a1off + k0];
    } else {
      float4 sc0 = *(const float4*)&scale[k0];
      float4 sc1 = *(const float4*)&scale[k0 + 4];
      float4 sh0 = *(const float4*)&shift[k0];
      float4 sh1 = *(const float4*)&shift[k0 + 4];
      float scv[8] = {sc0.x, sc0.y, sc0.z, sc0.w, sc1.x, sc1.y, sc1.z, sc1.w};
      float shv[8] = {sh0.x, sh0.y, sh0.z, sh0.w, sh1.x, sh1.y, sh1.z, sh1.w};
      float4 p0 = *(const float4*)&srcf[a0off + k0];
      float4 p1 = *(const float4*)&srcf[a0off + k0 + 4];
      float w[8] = {p0.x, p0.y, p0.z, p0.w, p1.x, p1.y, p1.z, p1.w};
#pragma unroll
      for (int j = 0; j < 8; ++j) w[j] = fmaxf(w[j] * scv[j] + shv[j], 0.f);
      if (v0) {
        float4 o0 = *(const float4*)&outacc[a0off + k0];
        float4 o1 = *(const float4*)&outacc[a0off + k0 + 4];
        o0.x += w[0]; o0.y += w[1]; o0.z += w[2]; o0.w += w[3];
        o1.x += w[4]; o1.y += w[5]; o1.z += w[6]; o1.w += w[7];
        *(float4*)&outacc[a0off + k0] = o0;
        *(float4*)&outacc[a0off + k0 + 4] = o1;
      }
#pragma unroll
      for (int j = 0; j < 8; ++j) a0[j] = (short)f2bf(w[j]);
      p0 = *(const float4*)&srcf[a1off + k0];
      p1 = *(const float4*)&srcf[a1off + k0 + 4];
      float u[8] = {p0.x, p0.y, p0.z, p0.w, p1.x, p1.y, p1.z, p1.w};
#pragma unroll
      for (int j = 0; j < 8; ++j) u[j] = fmaxf(u[j] * scv[j] + shv[j], 0.f);
      if (v1) {
        float4 o0 = *(const float4*)&outacc[a1off + k0];
        float4 o1 = *(const float4*)&outacc[a1off + k0 + 4];
        o0.x += u[0]; o0.y += u[1]; o0.z += u[2]; o0.w += u[3];
        o1.x += u[4]; o1.y += u[5]; o1.z += u[6]; o1.w += u[7];
        *(float4*)&outacc[a1off + k0] = o0;
        *(float4*)&outacc[a1off + k0 + 4] = o1;
      }
#pragma unroll
      for (int j = 0; j < 8; ++j) a1[j] = (short)f2bf(u[j]);
    }
#pragma unroll
    for (int j = 0; j < 8; ++j) {                 // B[k][n=col] for out-tile j = W[j*16+col][k]
      s8v bf = *(const s8v*)&Wbf[(j * 16 + col) * DD + k0];
      acc[0][j] = __builtin_amdgcn_mfma_f32_16x16x32_bf16(a0, bf, acc[0][j], 0, 0, 0);
      acc[1][j] = __builtin_amdgcn_mfma_f32_16x16x32_bf16(a1, bf, acc[1][j], 0, 0, 0);
    }
  }

  float bb[8];
#pragma unroll
  for (int j = 0; j < 8; ++j) bb[j] = bl[j * 16 + col];
#pragma unroll
  for (int i = 0; i < 2; ++i) {
    int rowb = nb + i * 16 + quad * 4;            // D: col=lane&15, row=quad*4+reg
#pragma unroll
    for (int r = 0; r < 4; ++r) {
      int n = rowb + r;
      if (n < NN) {
#pragma unroll
        for (int j = 0; j < 8; ++j)
          hl[(long)n * DD + j * 16 + col] = f2bf(acc[i][j][r] + bb[j]);
      }
    }
  }
}

// ---------- gather-aggregate + self term + BN partials ----------
// QUARTER-wave (16 lanes) owns a CONTIGUOUS run of 8 nodes; lane covers
// d = (lane&15)*8 .. +7. hl is BF16: one 16B load per edge per lane (256B/row)
// -> 51 MB gather footprint, L2/L3-resident. Rolling 2-record recs prefetch
// kept from R6. Plain __launch_bounds__ (R5 lesson: min-waves clause spilled).
__global__ __launch_bounds__(256) void k_aggregate(const ushort* __restrict__ hl,
    const int* __restrict__ off, const int4* __restrict__ recs,
    const float* __restrict__ btc, const float* __restrict__ rootl,
    const float* __restrict__ invd, float* __restrict__ pre,
    float* __restrict__ gsum, float* __restrict__ gss) {
  __shared__ float redS[256][9], redQ[256][9];     // +1 pad: conflict-free
  int t = threadIdx.x;
  int ql = t & 15;                                 // lane within quarter-wave
  int qs = t >> 4;                                 // quarter-slot 0..15
  int d0 = ql * 8;
  int base = blockIdx.x * 128 + qs * 8;
  float4 rt0 = *(const float4*)&rootl[d0];
  float4 rt1 = *(const float4*)&rootl[d0 + 4];
  float4 s0 = make_float4(0.f, 0.f, 0.f, 0.f), s1 = s0;
  float4 q0 = s0, q1 = s0;
  if (base < NN) {
    int eptr = off[base];
    int enext = off[base + 1];
    int4 r0 = recs[(eptr < NE) ? eptr : (NE - 1)];           // rolling prefetch regs
    int4 r1 = recs[(eptr + 1 < NE) ? eptr + 1 : (NE - 1)];
#pragma unroll 1
    for (int j = 0; j < 8; ++j) {
      int n = base + j;
      int ia = base + j + 2; if (ia > NN) ia = NN;
      int e_after = off[ia];                       // issued early, used next iter
      int eend = enext;
      s8v sv = *(const s8v*)&hl[(long)n * DD + d0];          // self-term (bf16)
      float iv = invd[n];
      float4 aca = make_float4(0.f, 0.f, 0.f, 0.f), acb = aca;
      while (eptr + 2 <= eend) {                   // 2 edges per trip
        int4 ra = r0, rb = r1;
        int p0 = eptr + 2; if (p0 >= NE) p0 = NE - 1;
        int p1 = eptr + 3; if (p1 >= NE) p1 = NE - 1;
        r0 = recs[p0];                             // prefetch next pair
        r1 = recs[p1];
        s8v ha = *(const s8v*)&hl[(long)ra.x * DD + d0];     // 16B bf16 gather
        float4 ea0 = *(const float4*)&btc[ra.y * DD + d0];
        float4 ea1 = *(const float4*)&btc[ra.y * DD + d0 + 4];
        s8v hb = *(const s8v*)&hl[(long)rb.x * DD + d0];
        float4 eb0 = *(const float4*)&btc[rb.y * DD + d0];
        float4 eb1 = *(const float4*)&btc[rb.y * DD + d0 + 4];
        float na = __int_as_float(ra.z);
        float nb = __int_as_float(rb.z);
        aca.x += fmaxf(bf2f((ushort)ha[0]) + ea0.x, 0.f) * na + fmaxf(bf2f((ushort)hb[0]) + eb0.x, 0.f) * nb;
        aca.y += fmaxf(bf2f((ushort)ha[1]) + ea0.y, 0.f) * na + fmaxf(bf2f((ushort)hb[1]) + eb0.y, 0.f) * nb;
        aca.z += fmaxf(bf2f((ushort)ha[2]) + ea0.z, 0.f) * na + fmaxf(bf2f((ushort)hb[2]) + eb0.z, 0.f) * nb;
        aca.w += fmaxf(bf2f((ushort)ha[3]) + ea0.w, 0.f) * na + fmaxf(bf2f((ushort)hb[3]) + eb0.w, 0.f) * nb;
        acb.x += fmaxf(bf2f((ushort)ha[4]) + ea1.x, 0.f) * na + fmaxf(bf2f((ushort)hb[4]) + eb1.x, 0.f) * nb;
        acb.y += fmaxf(bf2f((ushort)ha[5]) + ea1.y, 0.f) * na + fmaxf(bf2f((ushort)hb[5]) + eb1.y, 0.f) * nb;
        acb.z += fmaxf(bf2f((ushort)ha[6]) + ea1.z, 0.f) * na + fmaxf(bf2f((ushort)hb[6]) + eb1.z, 0.f) * nb;
        acb.w += fmaxf(bf2f((ushort)ha[7]) + ea1.w, 0.f) * na + fmaxf(bf2f((ushort)hb[7]) + eb1.w, 0.f) * nb;
        eptr += 2;
      }
      if (eptr < eend) {                           // odd leftover edge
        int4 ra = r0;
        int4 tmp = r1;
        int p0 = eptr + 2; if (p0 >= NE) p0 = NE - 1;
        r1 = recs[p0];                             // maintain rolling invariant
        r0 = tmp;
        s8v hv = *(const s8v*)&hl[(long)ra.x * DD + d0];
        float4 ev0 = *(const float4*)&btc[ra.y * DD + d0];
        float4 ev1 = *(const float4*)&btc[ra.y * DD + d0 + 4];
        float nr = __int_as_float(ra.z);
        aca.x += fmaxf(bf2f((ushort)hv[0]) + ev0.x, 0.f) * nr;
        aca.y += fmaxf(bf2f((ushort)hv[1]) + ev0.y, 0.f) * nr;
        aca.z += fmaxf(bf2f((ushort)hv[2]) + ev0.z, 0.f) * nr;
        aca.w += fmaxf(bf2f((ushort)hv[3]) + ev0.w, 0.f) * nr;
        acb.x += fmaxf(bf2f((ushort)hv[4]) + ev1.x, 0.f) * nr;
        acb.y += fmaxf(bf2f((ushort)hv[5]) + ev1.y, 0.f) * nr;
        acb.z += fmaxf(bf2f((ushort)hv[6]) + ev1.z, 0.f) * nr;
        acb.w += fmaxf(bf2f((ushort)hv[7]) + ev1.w, 0.f) * nr;
        eptr += 1;
      }
      float4 pa, pb;
      pa.x = aca.x + fmaxf(bf2f((ushort)sv[0]) + rt0.x, 0.f) * iv;
      pa.y = aca.y + fmaxf(bf2f((ushort)sv[1]) + rt0.y, 0.f) * iv;
      pa.z = aca.z + fmaxf(bf2f((ushort)sv[2]) + rt0.z, 0.f) * iv;
      pa.w = aca.w + fmaxf(bf2f((ushort)sv[3]) + rt0.w, 0.f) * iv;
      pb.x = acb.x + fmaxf(bf2f((ushort)sv[4]) + rt1.x, 0.f) * iv;
      pb.y = acb.y + fmaxf(bf2f((ushort)sv[5]) + rt1.y, 0.f) * iv;
      pb.z = acb.z + fmaxf(bf2f((ushort)sv[6]) + rt1.z, 0.f) * iv;
      pb.w = acb.w + fmaxf(bf2f((ushort)sv[7]) + rt1.w, 0.f) * iv;
      *(float4*)&pre[(long)n * DD + d0] = pa;
      *(float4*)&pre[(long)n * DD + d0 + 4] = pb;
      s0.x += pa.x; s0.y += pa.y; s0.z += pa.z; s0.w += pa.w;
      s1.x += pb.x; s1.y += pb.y; s1.z += pb.z; s1.w += pb.w;
      q0.x += pa.x * pa.x; q0.y += pa.y * pa.y; q0.z += pa.z * pa.z; q0.w += pa.w * pa.w;
      q1.x += pb.x * pb.x; q1.y += pb.y * pb.y; q1.z += pb.z * pb.z; q1.w += pb.w * pb.w;
      enext = e_after;
    }
  }
  redS[t][0] = s0.x; redS[t][1] = s0.y; redS[t][2] = s0.z; redS[t][3] = s0.w;
  redS[t][4] = s1.x; redS[t][5] = s1.y; redS[t][6] = s1.z; redS[t][7] = s1.w;
  redQ[t][0] = q0.x; redQ[t][1] = q0.y; redQ[t][2] = q0.z; redQ[t][3] = q0.w;
  redQ[t][4] = q1.x; redQ[t][5] = q1.y; redQ[t][6] = q1.z; redQ[t][7] = q1.w;
  __syncthreads();
  if (t < 128) {                                   // d = t; lane qq=d>>3 covers d&7
    int qq = t >> 3, c = t & 7;
    float S = 0.f, Q = 0.f;
#pragma unroll
    for (int h = 0; h < 16; ++h) {
      S += redS[h * 16 + qq][c];
      Q += redQ[h * 16 + qq][c];
    }
    atomicAdd(&gsum[t], S);
    atomicAdd(&gss[t], Q);
  }
}

__global__ void k_bnfin(const float* __restrict__ gsum, const float* __restrict__ gss,
    const float* __restrict__ gl, const float* __restrict__ bl,
    float* __restrict__ scale, float* __restrict__ shift) {
  int d = threadIdx.x;
  float m = gsum[d] * (1.0f / NN);
  float v = gss[d] * (1.0f / NN) - m * m;
  float sc = gl[d] * rsqrtf(v + EPSV);
  scale[d] = sc;
  shift[d] = bl[d] - m * sc;
}

// ---------- final layer apply (no relu): out += pre*scale + shift ----------
__global__ __launch_bounds__(256) void k_apply_final(const float* __restrict__ pre,
    const float* __restrict__ scale, const float* __restrict__ shift,
    float* __restrict__ out) {
  int idx = blockIdx.x * 256 + threadIdx.x;       // N*D/2 exact
  int dp = idx & 63;
  float2 pv = *(const float2*)&pre[idx * 2];
  float2 o = *(const float2*)&out[idx * 2];
  o.x += pv.x * scale[dp * 2] + shift[dp * 2];
  o.y += pv.y * scale[dp * 2 + 1] + shift[dp * 2 + 1];
  *(float2*)&out[idx * 2] = o;
}

extern "C" void kernel_launch(void* const* d_in, const int* in_sizes, int n_in,
                              void* d_out, int out_size, void* d_ws, size_t ws_size,
                              hipStream_t stream) {
  const int*   x     = (const int*)d_in[0];
  const int*   ei    = (const int*)d_in[1];
  const int*   ea    = (const int*)d_in[2];
  const float* at    = (const float*)d_in[3];
  const float* bt    = (const float*)d_in[4];
  const float* W     = (const float*)d_in[5];
  const float* b     = (const float*)d_in[6];
  const float* root  = (const float*)d_in[7];
  const float* gamma = (const float*)d_in[8];
  const float* beta  = (const float*)d_in[9];
  float* out = (float*)d_out;

  char* ws = (char*)d_ws;
  size_t ND = (size_t)NN * DD;
  ushort* hl   = (ushort*)ws;                       // ND bf16
  float*  pre  = (float*)(hl + ND);                 // ND fp32
  ushort* hbuf = (ushort*)(pre + ND);               // ND bf16
  int4*   recs = (int4*)(hbuf + ND);                // NE * 16B (offset ND*8 B, 16B-aligned)
  ushort* Wbf  = (ushort*)(recs + NE);              // 5*128*128 bf16
  float*  btc  = (float*)(Wbf + NL * DD * DD);      // 1000*128 fp32
  float*  deg  = btc + 1000 * DD;                   // N
  float*  dis  = deg + NN;                          // N
  float*  invd = dis + NN;                          // N
  int*    cnt  = (int*)(invd + NN);                 // N
  int*    offa = cnt + NN;                          // N+1 (+3 pad)
  int*    nxt  = offa + NN + 4;                     // N
  int*    bsum = nxt + NN;                          // 256
  int*    bbase= bsum + 256;                        // 256
  float*  gsum = (float*)(bbase + 256);             // D
  float*  gss  = gsum + DD;                         // D
  float*  scaleb = gss + DD;                        // D
  float*  shiftb = scaleb + DD;                     // D

  // ---- precompute ----
  k_deg_init<<<(NN + 255) / 256, 256, 0, stream>>>(deg, cnt);
  k_deg_count<<<(NE + 255) / 256, 256, 0, stream>>>(ei, deg, cnt);
  k_deg_fin<<<(NN + 255) / 256, 256, 0, stream>>>(deg, dis, invd);
  k_scan1<<<SCAN_BLKS, 256, 0, stream>>>(cnt, offa, bsum);
  k_scan2<<<1, 256, 0, stream>>>(bsum, bbase);
  k_scan3<<<(NN + 255) / 256, 256, 0, stream>>>(offa, bbase, nxt);
  k_fill<<<(NE + 255) / 256, 256, 0, stream>>>(ei, ea, dis, nxt, recs);
  k_btc<<<1000 * DD / 256, 256, 0, stream>>>(bt, btc);
  k_wconv<<<NL * DD * DD / 256, 256, 0, stream>>>(W, Wbf);
  k_encode<<<(int)(ND / 2 / 256), 256, 0, stream>>>(x, at, hbuf, out);

  // ---- layers ----
  for (int l = 0; l < NL; ++l) {
    hipMemsetAsync(gsum, 0, 2 * DD * sizeof(float), stream);
    k_gemm<<<(NN + 127) / 128, 256, 0, stream>>>(
        hbuf, pre, Wbf + (size_t)l * DD * DD, b + l * DD,
        scaleb, shiftb, out, hl, (l == 0) ? 0 : 1);
    k_aggregate<<<(NN + 127) / 128, 256, 0, stream>>>(hl, offa, recs, btc,
        root + l * DD, invd, pre, gsum, gss);
    k_bnfin<<<1, DD, 0, stream>>>(gsum, gss, gamma + l * DD, beta + l * DD,
                                  scaleb, shiftb);
  }
  k_apply_final<<<(int)(ND / 2 / 256), 256, 0, stream>>>(pre, scaleb, shiftb, out);
}

// Round 8
// 1138.936 us; speedup vs baseline: 1.4832x; 1.0008x over previous
//
#include <hip/hip_runtime.h>

#define NN 200000
#define NE 400000
#define DD 128
#define NL 5
#define AV 100
#define BV 10
#define EPSV 1e-5f
#define SCAN_BLKS 196   // ceil(NN/1024)

typedef short s8v __attribute__((ext_vector_type(8)));   // 8 bf16 (4 VGPRs)
typedef float f4v __attribute__((ext_vector_type(4)));   // 4 fp32 acc

__device__ __forceinline__ ushort f2bf(float f) {        // RNE float->bf16
  uint u = __float_as_uint(f);
  u += 0x7FFFu + ((u >> 16) & 1u);
  return (ushort)(u >> 16);
}

__device__ __forceinline__ float bf2f(ushort u) {        // bf16->float
  return __uint_as_float(((uint)u) << 16);
}

// ---------- encode: h = sum of atom embeddings; out(fp32) = h; hbuf(bf16) = h ----------
__global__ __launch_bounds__(256) void k_encode(const int* __restrict__ x,
    const float* __restrict__ at, ushort* __restrict__ hbuf, float* __restrict__ out) {
  int idx = blockIdx.x * 256 + threadIdx.x;       // N*D/2 threads exact
  int n = idx >> 6, dp = idx & 63;                // wave = one node -> x row broadcast
  const int* xr = x + n * 9;
  float s0 = 0.f, s1 = 0.f;
#pragma unroll
  for (int c = 0; c < 9; ++c) {
    float2 v = *(const float2*)&at[(c * AV + xr[c]) * DD + dp * 2];
    s0 += v.x; s1 += v.y;
  }
  *(float2*)&out[idx * 2] = make_float2(s0, s1);
  ((uint*)hbuf)[idx] = (uint)f2bf(s0) | ((uint)f2bf(s1) << 16);
}

// ---------- degree ----------
__global__ __launch_bounds__(256) void k_deg_init(float* __restrict__ deg,
                                                  int* __restrict__ cnt) {
  int i = blockIdx.x * 256 + threadIdx.x;
  if (i < NN) { deg[i] = 1.0f; cnt[i] = 0; }
}

__global__ __launch_bounds__(256) void k_deg_count(const int* __restrict__ ei,
    float* __restrict__ deg, int* __restrict__ cnt) {
  int e = blockIdx.x * 256 + threadIdx.x;
  if (e < NE) {
    atomicAdd(&deg[ei[e]], 1.0f);
    atomicAdd(&cnt[ei[NE + e]], 1);
  }
}

__global__ __launch_bounds__(256) void k_deg_fin(const float* __restrict__ deg,
    float* __restrict__ dis, float* __restrict__ invd) {
  int i = blockIdx.x * 256 + threadIdx.x;
  if (i < NN) {
    float dg = deg[i];
    dis[i] = rsqrtf(dg);
    invd[i] = 1.0f / dg;
  }
}

// ---------- exclusive scan of cnt -> off ----------
__global__ __launch_bounds__(256) void k_scan1(const int* __restrict__ cnt,
    int* __restrict__ off, int* __restrict__ bsum) {
  __shared__ int s[256];
  int t = threadIdx.x;
  int base = blockIdx.x * 1024 + t * 4;
  int c0 = (base + 0 < NN) ? cnt[base + 0] : 0;
  int c1 = (base + 1 < NN) ? cnt[base + 1] : 0;
  int c2 = (base + 2 < NN) ? cnt[base + 2] : 0;
  int c3 = (base + 3 < NN) ? cnt[base + 3] : 0;
  int tsum = c0 + c1 + c2 + c3;
  s[t] = tsum;
  __syncthreads();
  for (int o = 1; o < 256; o <<= 1) {
    int v = (t >= o) ? s[t - o] : 0;
    __syncthreads();
    s[t] += v;
    __syncthreads();
  }
  int excl = s[t] - tsum;
  if (base + 0 < NN) off[base + 0] = excl;
  if (base + 1 < NN) off[base + 1] = excl + c0;
  if (base + 2 < NN) off[base + 2] = excl + c0 + c1;
  if (base + 3 < NN) off[base + 3] = excl + c0 + c1 + c2;
  if (t == 255) bsum[blockIdx.x] = s[255];
}

__global__ __launch_bounds__(256) void k_scan2(const int* __restrict__ bsum,
    int* __restrict__ bbase) {
  __shared__ int s[256];
  int t = threadIdx.x;
  int v0 = (t < SCAN_BLKS) ? bsum[t] : 0;
  s[t] = v0;
  __syncthreads();
  for (int o = 1; o < 256; o <<= 1) {
    int v = (t >= o) ? s[t - o] : 0;
    __syncthreads();
    s[t] += v;
    __syncthreads();
  }
  if (t < SCAN_BLKS) bbase[t] = s[t] - v0;
}

__global__ __launch_bounds__(256) void k_scan3(int* __restrict__ off,
    const int* __restrict__ bbase, int* __restrict__ nxt) {
  int i = blockIdx.x * 256 + threadIdx.x;
  if (i < NN) {
    int v = off[i] + bbase[i >> 10];
    off[i] = v;
    nxt[i] = v;
  }
  if (i == 0) off[NN] = NE;
}

// ---------- fill CSR records: {row, packed_ea, norm_bits, 0} ----------
__global__ __launch_bounds__(256) void k_fill(const int* __restrict__ ei,
    const int* __restrict__ ea, const float* __restrict__ dis,
    int* __restrict__ nxt, int4* __restrict__ recs) {
  int e = blockIdx.x * 256 + threadIdx.x;
  if (e >= NE) return;
  int r = ei[e], c = ei[NE + e];
  int pa = ea[e * 3 + 0] + ea[e * 3 + 1] * 10 + ea[e * 3 + 2] * 100;
  float nr = dis[r] * dis[c];
  int pos = atomicAdd(&nxt[c], 1);
  recs[pos] = make_int4(r, pa, __float_as_int(nr), 0);
}

// ---------- combined bond table (fp32): btc[pa][d] ----------
__global__ __launch_bounds__(256) void k_btc(const float* __restrict__ bt,
    float* __restrict__ btc) {
  int idx = blockIdx.x * 256 + threadIdx.x;       // 1000*128 exact
  int p = idx >> 7, d = idx & 127;
  int a = p % 10, b = (p / 10) % 10, c = p / 100;
  btc[idx] = bt[(0 * BV + a) * DD + d] + bt[(1 * BV + b) * DD + d]
           + bt[(2 * BV + c) * DD + d];
}

// ---------- W -> bf16 ----------
__global__ __launch_bounds__(256) void k_wconv(const float* __restrict__ W,
    ushort* __restrict__ Wbf) {
  int i = blockIdx.x * 256 + threadIdx.x;         // 5*128*128 exact
  Wbf[i] = f2bf(W[i]);
}

// ---------- MFMA GEMM: hl(BF16) = A' @ Wl^T + bl ----------
// mode0: A' = hbuf (bf16).  mode1: A' = relu(pre*scale+shift) (fp32->bf16), fused out += A'.
// PHASED structure (R8): (1) hoist ALL 16 pre loads into one issue burst,
// (2) activation+pack (VALU), (3) deferred out-RMW as 4 independent chains,
// (4) MFMA loop. Collapses ~8-12 serialized memory latencies per tile to ~2-3.
// VGPR ~190 (no launch_bounds min-waves clause -- R5 spill lesson).
__global__ __launch_bounds__(256) void k_gemm(const ushort* __restrict__ srcbf,
    const float* __restrict__ srcf, const ushort* __restrict__ Wbf,
    const float* __restrict__ bl, const float* __restrict__ scale,
    const float* __restrict__ shift, float* __restrict__ outacc,
    ushort* __restrict__ hl, int mode) {
  int t = threadIdx.x;
  int lane = t & 63, wave = t >> 6;
  int col = lane & 15, quad = lane >> 4;
  int nb = blockIdx.x * 128 + wave * 32;
  int r0 = nb + col, r1 = nb + 16 + col;
  bool v0 = r0 < NN, v1 = r1 < NN;
  long a0off = (long)(v0 ? r0 : NN - 1) * DD;
  long a1off = (long)(v1 ? r1 : NN - 1) * DD;

  s8v af0[4], af1[4];                             // A fragments, 4 k-slices

  if (mode == 0) {
#pragma unroll
    for (int ks = 0; ks < 4; ++ks) {              // 8 loads, one burst
      int k0 = ks * 32 + quad * 8;
      af0[ks] = *(const s8v*)&srcbf[a0off + k0];
      af1[ks] = *(const s8v*)&srcbf[a1off + k0];
    }
  } else {
    float4 pA[4][2], pB[4][2];                    // 64 VGPR of pre data
#pragma unroll
    for (int ks = 0; ks < 4; ++ks) {              // 16 loads, one burst
      int k0 = ks * 32 + quad * 8;
      pA[ks][0] = *(const float4*)&srcf[a0off + k0];
      pA[ks][1] = *(const float4*)&srcf[a0off + k0 + 4];
      pB[ks][0] = *(const float4*)&srcf[a1off + k0];
      pB[ks][1] = *(const float4*)&srcf[a1off + k0 + 4];
    }
#pragma unroll
    for (int ks = 0; ks < 4; ++ks) {              // activation + pack (VALU)
      int k0 = ks * 32 + quad * 8;
      float4 sc0 = *(const float4*)&scale[k0];
      float4 sc1 = *(const float4*)&scale[k0 + 4];
      float4 sh0 = *(const float4*)&shift[k0];
      float4 sh1 = *(const float4*)&shift[k0 + 4];
      float4 a = pA[ks][0], b4 = pA[ks][1];
      a.x  = fmaxf(a.x  * sc0.x + sh0.x, 0.f);
      a.y  = fmaxf(a.y  * sc0.y + sh0.y, 0.f);
      a.z  = fmaxf(a.z  * sc0.z + sh0.z, 0.f);
      a.w  = fmaxf(a.w  * sc0.w + sh0.w, 0.f);
      b4.x = fmaxf(b4.x * sc1.x + sh1.x, 0.f);
      b4.y = fmaxf(b4.y * sc1.y + sh1.y, 0.f);
      b4.z = fmaxf(b4.z * sc1.z + sh1.z, 0.f);
      b4.w = fmaxf(b4.w * sc1.w + sh1.w, 0.f);
      pA[ks][0] = a; pA[ks][1] = b4;
      af0[ks][0] = (short)f2bf(a.x);  af0[ks][1] = (short)f2bf(a.y);
      af0[ks][2] = (short)f2bf(a.z);  af0[ks][3] = (short)f2bf(a.w);
      af0[ks][4] = (short)f2bf(b4.x); af0[ks][5] = (short)f2bf(b4.y);
      af0[ks][6] = (short)f2bf(b4.z); af0[ks][7] = (short)f2bf(b4.w);
      float4 c = pB[ks][0], d4 = pB[ks][1];
      c.x  = fmaxf(c.x  * sc0.x + sh0.x, 0.f);
      c.y  = fmaxf(c.y  * sc0.y + sh0.y, 0.f);
      c.z  = fmaxf(c.z  * sc0.z + sh0.z, 0.f);
      c.w  = fmaxf(c.w  * sc0.w + sh0.w, 0.f);
      d4.x = fmaxf(d4.x * sc1.x + sh1.x, 0.f);
      d4.y = fmaxf(d4.y * sc1.y + sh1.y, 0.f);
      d4.z = fmaxf(d4.z * sc1.z + sh1.z, 0.f);
      d4.w = fmaxf(d4.w * sc1.w + sh1.w, 0.f);
      pB[ks][0] = c; pB[ks][1] = d4;
      af1[ks][0] = (short)f2bf(c.x);  af1[ks][1] = (short)f2bf(c.y);
      af1[ks][2] = (short)f2bf(c.z);  af1[ks][3] = (short)f2bf(c.w);
      af1[ks][4] = (short)f2bf(d4.x); af1[ks][5] = (short)f2bf(d4.y);
      af1[ks][6] = (short)f2bf(d4.z); af1[ks][7] = (short)f2bf(d4.w);
    }
    // deferred out RMW: 4 independent load->add->store chains, issued together
    if (v0) {
#pragma unroll
      for (int ks = 0; ks < 4; ++ks) {
        int k0 = ks * 32 + quad * 8;
        float4 o0 = *(const float4*)&outacc[a0off + k0];
        float4 o1 = *(const float4*)&outacc[a0off + k0 + 4];
        o0.x += pA[ks][0].x; o0.y += pA[ks][0].y; o0.z += pA[ks][0].z; o0.w += pA[ks][0].w;
        o1.x += pA[ks][1].x; o1.y += pA[ks][1].y; o1.z += pA[ks][1].z; o1.w += pA[ks][1].w;
        *(float4*)&outacc[a0off + k0] = o0;
        *(float4*)&outacc[a0off + k0 + 4] = o1;
      }
    }
    if (v1) {
#pragma unroll
      for (int ks = 0; ks < 4; ++ks) {
        int k0 = ks * 32 + quad * 8;
        float4 o0 = *(const float4*)&outacc[a1off + k0];
        float4 o1 = *(const float4*)&outacc[a1off + k0 + 4];
        o0.x += pB[ks][0].x; o0.y += pB[ks][0].y; o0.z += pB[ks][0].z; o0.w += pB[ks][0].w;
        o1.x += pB[ks][1].x; o1.y += pB[ks][1].y; o1.z += pB[ks][1].z; o1.w += pB[ks][1].w;
        *(float4*)&outacc[a1off + k0] = o0;
        *(float4*)&outacc[a1off + k0 + 4] = o1;
      }
    }
  }

  f4v acc[2][8];
#pragma unroll
  for (int i = 0; i < 2; ++i)
#pragma unroll
    for (int j = 0; j < 8; ++j) acc[i][j] = (f4v)0.f;

#pragma unroll
  for (int ks = 0; ks < 4; ++ks) {                // MFMA loop: W loads (L2) + 64 MFMA
    int k0 = ks * 32 + quad * 8;
#pragma unroll
    for (int j = 0; j < 8; ++j) {                 // B[k][n=col] for out-tile j = W[j*16+col][k]
      s8v bf = *(const s8v*)&Wbf[(j * 16 + col) * DD + k0];
      acc[0][j] = __builtin_amdgcn_mfma_f32_16x16x32_bf16(af0[ks], bf, acc[0][j], 0, 0, 0);
      acc[1][j] = __builtin_amdgcn_mfma_f32_16x16x32_bf16(af1[ks], bf, acc[1][j], 0, 0, 0);
    }
  }

  float bb[8];
#pragma unroll
  for (int j = 0; j < 8; ++j) bb[j] = bl[j * 16 + col];
#pragma unroll
  for (int i = 0; i < 2; ++i) {
    int rowb = nb + i * 16 + quad * 4;            // D: col=lane&15, row=quad*4+reg
#pragma unroll
    for (int r = 0; r < 4; ++r) {
      int n = rowb + r;
      if (n < NN) {
#pragma unroll
        for (int j = 0; j < 8; ++j)
          hl[(long)n * DD + j * 16 + col] = f2bf(acc[i][j][r] + bb[j]);
      }
    }
  }
}

// ---------- gather-aggregate + self term + BN partials ----------
// QUARTER-wave (16 lanes) owns a CONTIGUOUS run of 8 nodes; lane covers
// d = (lane&15)*8 .. +7. hl is BF16: one 16B load per edge per lane (256B/row)
// -> 51 MB gather footprint, L2/L3-resident. Rolling 2-record recs prefetch
// kept from R6. Plain __launch_bounds__ (R5 lesson: min-waves clause spilled).
__global__ __launch_bounds__(256) void k_aggregate(const ushort* __restrict__ hl,
    const int* __restrict__ off, const int4* __restrict__ recs,
    const float* __restrict__ btc, const float* __restrict__ rootl,
    const float* __restrict__ invd, float* __restrict__ pre,
    float* __restrict__ gsum, float* __restrict__ gss) {
  __shared__ float redS[256][9], redQ[256][9];     // +1 pad: conflict-free
  int t = threadIdx.x;
  int ql = t & 15;                                 // lane within quarter-wave
  int qs = t >> 4;                                 // quarter-slot 0..15
  int d0 = ql * 8;
  int base = blockIdx.x * 128 + qs * 8;
  float4 rt0 = *(const float4*)&rootl[d0];
  float4 rt1 = *(const float4*)&rootl[d0 + 4];
  float4 s0 = make_float4(0.f, 0.f, 0.f, 0.f), s1 = s0;
  float4 q0 = s0, q1 = s0;
  if (base < NN) {
    int eptr = off[base];
    int enext = off[base + 1];
    int4 r0 = recs[(eptr < NE) ? eptr : (NE - 1)];           // rolling prefetch regs
    int4 r1 = recs[(eptr + 1 < NE) ? eptr + 1 : (NE - 1)];
#pragma unroll 1
    for (int j = 0; j < 8; ++j) {
      int n = base + j;
      int ia = base + j + 2; if (ia > NN) ia = NN;
      int e_after = off[ia];                       // issued early, used next iter
      int eend = enext;
      s8v sv = *(const s8v*)&hl[(long)n * DD + d0];          // self-term (bf16)
      float iv = invd[n];
      float4 aca = make_float4(0.f, 0.f, 0.f, 0.f), acb = aca;
      while (eptr + 2 <= eend) {                   // 2 edges per trip
        int4 ra = r0, rb = r1;
        int p0 = eptr + 2; if (p0 >= NE) p0 = NE - 1;
        int p1 = eptr + 3; if (p1 >= NE) p1 = NE - 1;
        r0 = recs[p0];                             // prefetch next pair
        r1 = recs[p1];
        s8v ha = *(const s8v*)&hl[(long)ra.x * DD + d0];     // 16B bf16 gather
        float4 ea0 = *(const float4*)&btc[ra.y * DD + d0];
        float4 ea1 = *(const float4*)&btc[ra.y * DD + d0 + 4];
        s8v hb = *(const s8v*)&hl[(long)rb.x * DD + d0];
        float4 eb0 = *(const float4*)&btc[rb.y * DD + d0];
        float4 eb1 = *(const float4*)&btc[rb.y * DD + d0 + 4];
        float na = __int_as_float(ra.z);
        float nb = __int_as_float(rb.z);
        aca.x += fmaxf(bf2f((ushort)ha[0]) + ea0.x, 0.f) * na + fmaxf(bf2f((ushort)hb[0]) + eb0.x, 0.f) * nb;
        aca.y += fmaxf(bf2f((ushort)ha[1]) + ea0.y, 0.f) * na + fmaxf(bf2f((ushort)hb[1]) + eb0.y, 0.f) * nb;
        aca.z += fmaxf(bf2f((ushort)ha[2]) + ea0.z, 0.f) * na + fmaxf(bf2f((ushort)hb[2]) + eb0.z, 0.f) * nb;
        aca.w += fmaxf(bf2f((ushort)ha[3]) + ea0.w, 0.f) * na + fmaxf(bf2f((ushort)hb[3]) + eb0.w, 0.f) * nb;
        acb.x += fmaxf(bf2f((ushort)ha[4]) + ea1.x, 0.f) * na + fmaxf(bf2f((ushort)hb[4]) + eb1.x, 0.f) * nb;
        acb.y += fmaxf(bf2f((ushort)ha[5]) + ea1.y, 0.f) * na + fmaxf(bf2f((ushort)hb[5]) + eb1.y, 0.f) * nb;
        acb.z += fmaxf(bf2f((ushort)ha[6]) + ea1.z, 0.f) * na + fmaxf(bf2f((ushort)hb[6]) + eb1.z, 0.f) * nb;
        acb.w += fmaxf(bf2f((ushort)ha[7]) + ea1.w, 0.f) * na + fmaxf(bf2f((ushort)hb[7]) + eb1.w, 0.f) * nb;
        eptr += 2;
      }
      if (eptr < eend) {                           // odd leftover edge
        int4 ra = r0;
        int4 tmp = r1;
        int p0 = eptr + 2; if (p0 >= NE) p0 = NE - 1;
        r1 = recs[p0];                             // maintain rolling invariant
        r0 = tmp;
        s8v hv = *(const s8v*)&hl[(long)ra.x * DD + d0];
        float4 ev0 = *(const float4*)&btc[ra.y * DD + d0];
        float4 ev1 = *(const float4*)&btc[ra.y * DD + d0 + 4];
        float nr = __int_as_float(ra.z);
        aca.x += fmaxf(bf2f((ushort)hv[0]) + ev0.x, 0.f) * nr;
        aca.y += fmaxf(bf2f((ushort)hv[1]) + ev0.y, 0.f) * nr;
        aca.z += fmaxf(bf2f((ushort)hv[2]) + ev0.z, 0.f) * nr;
        aca.w += fmaxf(bf2f((ushort)hv[3]) + ev0.w, 0.f) * nr;
        acb.x += fmaxf(bf2f((ushort)hv[4]) + ev1.x, 0.f) * nr;
        acb.y += fmaxf(bf2f((ushort)hv[5]) + ev1.y, 0.f) * nr;
        acb.z += fmaxf(bf2f((ushort)hv[6]) + ev1.z, 0.f) * nr;
        acb.w += fmaxf(bf2f((ushort)hv[7]) + ev1.w, 0.f) * nr;
        eptr += 1;
      }
      float4 pa, pb;
      pa.x = aca.x + fmaxf(bf2f((ushort)sv[0]) + rt0.x, 0.f) * iv;
      pa.y = aca.y + fmaxf(bf2f((ushort)sv[1]) + rt0.y, 0.f) * iv;
      pa.z = aca.z + fmaxf(bf2f((ushort)sv[2]) + rt0.z, 0.f) * iv;
      pa.w = aca.w + fmaxf(bf2f((ushort)sv[3]) + rt0.w, 0.f) * iv;
      pb.x = acb.x + fmaxf(bf2f((ushort)sv[4]) + rt1.x, 0.f) * iv;
      pb.y = acb.y + fmaxf(bf2f((ushort)sv[5]) + rt1.y, 0.f) * iv;
      pb.z = acb.z + fmaxf(bf2f((ushort)sv[6]) + rt1.z, 0.f) * iv;
      pb.w = acb.w + fmaxf(bf2f((ushort)sv[7]) + rt1.w, 0.f) * iv;
      *(float4*)&pre[(long)n * DD + d0] = pa;
      *(float4*)&pre[(long)n * DD + d0 + 4] = pb;
      s0.x += pa.x; s0.y += pa.y; s0.z += pa.z; s0.w += pa.w;
      s1.x += pb.x; s1.y += pb.y; s1.z += pb.z; s1.w += pb.w;
      q0.x += pa.x * pa.x; q0.y += pa.y * pa.y; q0.z += pa.z * pa.z; q0.w += pa.w * pa.w;
      q1.x += pb.x * pb.x; q1.y += pb.y * pb.y; q1.z += pb.z * pb.z; q1.w += pb.w * pb.w;
      enext = e_after;
    }
  }
  redS[t][0] = s0.x; redS[t][1] = s0.y; redS[t][2] = s0.z; redS[t][3] = s0.w;
  redS[t][4] = s1.x; redS[t][5] = s1.y; redS[t][6] = s1.z; redS[t][7] = s1.w;
  redQ[t][0] = q0.x; redQ[t][1] = q0.y; redQ[t][2] = q0.z; redQ[t][3] = q0.w;
  redQ[t][4] = q1.x; redQ[t][5] = q1.y; redQ[t][6] = q1.z; redQ[t][7] = q1.w;
  __syncthreads();
  if (t < 128) {                                   // d = t; lane qq=d>>3 covers d&7
    int qq = t >> 3, c = t & 7;
    float S = 0.f, Q = 0.f;
#pragma unroll
    for (int h = 0; h < 16; ++h) {
      S += redS[h * 16 + qq][c];
      Q += redQ[h * 16 + qq][c];
    }
    atomicAdd(&gsum[t], S);
    atomicAdd(&gss[t], Q);
  }
}

__global__ void k_bnfin(const float* __restrict__ gsum, const float* __restrict__ gss,
    const float* __restrict__ gl, const float* __restrict__ bl,
    float* __restrict__ scale, float* __restrict__ shift) {
  int d = threadIdx.x;
  float m = gsum[d] * (1.0f / NN);
  float v = gss[d] * (1.0f / NN) - m * m;
  float sc = gl[d] * rsqrtf(v + EPSV);
  scale[d] = sc;
  shift[d] = bl[d] - m * sc;
}

// ---------- final layer apply (no relu): out += pre*scale + shift ----------
__global__ __launch_bounds__(256) void k_apply_final(const float* __restrict__ pre,
    const float* __restrict__ scale, const float* __restrict__ shift,
    float* __restrict__ out) {
  int idx = blockIdx.x * 256 + threadIdx.x;       // N*D/2 exact
  int dp = idx & 63;
  float2 pv = *(const float2*)&pre[idx * 2];
  float2 o = *(const float2*)&out[idx * 2];
  o.x += pv.x * scale[dp * 2] + shift[dp * 2];
  o.y += pv.y * scale[dp * 2 + 1] + shift[dp * 2 + 1];
  *(float2*)&out[idx * 2] = o;
}

extern "C" void kernel_launch(void* const* d_in, const int* in_sizes, int n_in,
                              void* d_out, int out_size, void* d_ws, size_t ws_size,
                              hipStream_t stream) {
  const int*   x     = (const int*)d_in[0];
  const int*   ei    = (const int*)d_in[1];
  const int*   ea    = (const int*)d_in[2];
  const float* at    = (const float*)d_in[3];
  const float* bt    = (const float*)d_in[4];
  const float* W     = (const float*)d_in[5];
  const float* b     = (const float*)d_in[6];
  const float* root  = (const float*)d_in[7];
  const float* gamma = (const float*)d_in[8];
  const float* beta  = (const float*)d_in[9];
  float* out = (float*)d_out;

  char* ws = (char*)d_ws;
  size_t ND = (size_t)NN * DD;
  ushort* hl   = (ushort*)ws;                       // ND bf16
  float*  pre  = (float*)(hl + ND);                 // ND fp32
  ushort* hbuf = (ushort*)(pre + ND);               // ND bf16
  int4*   recs = (int4*)(hbuf + ND);                // NE * 16B (offset ND*8 B, 16B-aligned)
  ushort* Wbf  = (ushort*)(recs + NE);              // 5*128*128 bf16
  float*  btc  = (float*)(Wbf + NL * DD * DD);      // 1000*128 fp32
  float*  deg  = btc + 1000 * DD;                   // N
  float*  dis  = deg + NN;                          // N
  float*  invd = dis + NN;                          // N
  int*    cnt  = (int*)(invd + NN);                 // N
  int*    offa = cnt + NN;                          // N+1 (+3 pad)
  int*    nxt  = offa + NN + 4;                     // N
  int*    bsum = nxt + NN;                          // 256
  int*    bbase= bsum + 256;                        // 256
  float*  gsum = (float*)(bbase + 256);             // D
  float*  gss  = gsum + DD;                         // D
  float*  scaleb = gss + DD;                        // D
  float*  shiftb = scaleb + DD;                     // D

  // ---- precompute ----
  k_deg_init<<<(NN + 255) / 256, 256, 0, stream>>>(deg, cnt);
  k_deg_count<<<(NE + 255) / 256, 256, 0, stream>>>(ei, deg, cnt);
  k_deg_fin<<<(NN + 255) / 256, 256, 0, stream>>>(deg, dis, invd);
  k_scan1<<<SCAN_BLKS, 256, 0, stream>>>(cnt, offa, bsum);
  k_scan2<<<1, 256, 0, stream>>>(bsum, bbase);
  k_scan3<<<(NN + 255) / 256, 256, 0, stream>>>(offa, bbase, nxt);
  k_fill<<<(NE + 255) / 256, 256, 0, stream>>>(ei, ea, dis, nxt, recs);
  k_btc<<<1000 * DD / 256, 256, 0, stream>>>(bt, btc);
  k_wconv<<<NL * DD * DD / 256, 256, 0, stream>>>(W, Wbf);
  k_encode<<<(int)(ND / 2 / 256), 256, 0, stream>>>(x, at, hbuf, out);

  // ---- layers ----
  for (int l = 0; l < NL; ++l) {
    hipMemsetAsync(gsum, 0, 2 * DD * sizeof(float), stream);
    k_gemm<<<(NN + 127) / 128, 256, 0, stream>>>(
        hbuf, pre, Wbf + (size_t)l * DD * DD, b + l * DD,
        scaleb, shiftb, out, hl, (l == 0) ? 0 : 1);
    k_aggregate<<<(NN + 127) / 128, 256, 0, stream>>>(hl, offa, recs, btc,
        root + l * DD, invd, pre, gsum, gss);
    k_bnfin<<<1, DD, 0, stream>>>(gsum, gss, gamma + l * DD, beta + l * DD,
                                  scaleb, shiftb);
  }
  k_apply_final<<<(int)(ND / 2 / 256), 256, 0, stream>>>(pre, scaleb, shiftb, out);
}

// Round 10
// 1061.027 us; speedup vs baseline: 1.5921x; 1.0734x over previous
//
#include <hip/hip_runtime.h>

#define NN 200000
#define NE 400000
#define DD 128
#define NL 5
#define AV 100
#define BV 10
#define EPSV 1e-5f
#define SCAN_BLKS 196   // ceil(NN/1024)

typedef short s8v __attribute__((ext_vector_type(8)));   // 8 bf16 (4 VGPRs)
typedef float f4v __attribute__((ext_vector_type(4)));   // 4 fp32 acc

__device__ __forceinline__ ushort f2bf(float f) {        // RNE float->bf16
  uint u = __float_as_uint(f);
  u += 0x7FFFu + ((u >> 16) & 1u);
  return (ushort)(u >> 16);
}

__device__ __forceinline__ float bf2f(ushort u) {        // bf16->float
  return __uint_as_float(((uint)u) << 16);
}

// ---------- encode: h = sum of atom embeddings; out(fp32) = h; acts[0](bf16) = h ----------
__global__ __launch_bounds__(256) void k_encode(const int* __restrict__ x,
    const float* __restrict__ at, ushort* __restrict__ hbuf, float* __restrict__ out) {
  int idx = blockIdx.x * 256 + threadIdx.x;       // N*D/2 threads exact
  int n = idx >> 6, dp = idx & 63;                // wave = one node -> x row broadcast
  const int* xr = x + n * 9;
  float s0 = 0.f, s1 = 0.f;
#pragma unroll
  for (int c = 0; c < 9; ++c) {
    float2 v = *(const float2*)&at[(c * AV + xr[c]) * DD + dp * 2];
    s0 += v.x; s1 += v.y;
  }
  *(float2*)&out[idx * 2] = make_float2(s0, s1);
  ((uint*)hbuf)[idx] = (uint)f2bf(s0) | ((uint)f2bf(s1) << 16);
}

// ---------- degree ----------
__global__ __launch_bounds__(256) void k_deg_init(float* __restrict__ deg,
                                                  int* __restrict__ cnt) {
  int i = blockIdx.x * 256 + threadIdx.x;
  if (i < NN) { deg[i] = 1.0f; cnt[i] = 0; }
}

__global__ __launch_bounds__(256) void k_deg_count(const int* __restrict__ ei,
    float* __restrict__ deg, int* __restrict__ cnt) {
  int e = blockIdx.x * 256 + threadIdx.x;
  if (e < NE) {
    atomicAdd(&deg[ei[e]], 1.0f);
    atomicAdd(&cnt[ei[NE + e]], 1);
  }
}

__global__ __launch_bounds__(256) void k_deg_fin(const float* __restrict__ deg,
    float* __restrict__ dis, float* __restrict__ invd) {
  int i = blockIdx.x * 256 + threadIdx.x;
  if (i < NN) {
    float dg = deg[i];
    dis[i] = rsqrtf(dg);
    invd[i] = 1.0f / dg;
  }
}

// ---------- exclusive scan of cnt -> off ----------
__global__ __launch_bounds__(256) void k_scan1(const int* __restrict__ cnt,
    int* __restrict__ off, int* __restrict__ bsum) {
  __shared__ int s[256];
  int t = threadIdx.x;
  int base = blockIdx.x * 1024 + t * 4;
  int c0 = (base + 0 < NN) ? cnt[base + 0] : 0;
  int c1 = (base + 1 < NN) ? cnt[base + 1] : 0;
  int c2 = (base + 2 < NN) ? cnt[base + 2] : 0;
  int c3 = (base + 3 < NN) ? cnt[base + 3] : 0;
  int tsum = c0 + c1 + c2 + c3;
  s[t] = tsum;
  __syncthreads();
  for (int o = 1; o < 256; o <<= 1) {
    int v = (t >= o) ? s[t - o] : 0;
    __syncthreads();
    s[t] += v;
    __syncthreads();
  }
  int excl = s[t] - tsum;
  if (base + 0 < NN) off[base + 0] = excl;
  if (base + 1 < NN) off[base + 1] = excl + c0;
  if (base + 2 < NN) off[base + 2] = excl + c0 + c1;
  if (base + 3 < NN) off[base + 3] = excl + c0 + c1 + c2;
  if (t == 255) bsum[blockIdx.x] = s[255];
}

__global__ __launch_bounds__(256) void k_scan2(const int* __restrict__ bsum,
    int* __restrict__ bbase) {
  __shared__ int s[256];
  int t = threadIdx.x;
  int v0 = (t < SCAN_BLKS) ? bsum[t] : 0;
  s[t] = v0;
  __syncthreads();
  for (int o = 1; o < 256; o <<= 1) {
    int v = (t >= o) ? s[t - o] : 0;
    __syncthreads();
    s[t] += v;
    __syncthreads();
  }
  if (t < SCAN_BLKS) bbase[t] = s[t] - v0;
}

__global__ __launch_bounds__(256) void k_scan3(int* __restrict__ off,
    const int* __restrict__ bbase, int* __restrict__ nxt) {
  int i = blockIdx.x * 256 + threadIdx.x;
  if (i < NN) {
    int v = off[i] + bbase[i >> 10];
    off[i] = v;
    nxt[i] = v;
  }
  if (i == 0) off[NN] = NE;
}

// ---------- fill CSR records: {row, packed_ea, norm_bits, 0} ----------
__global__ __launch_bounds__(256) void k_fill(const int* __restrict__ ei,
    const int* __restrict__ ea, const float* __restrict__ dis,
    int* __restrict__ nxt, int4* __restrict__ recs) {
  int e = blockIdx.x * 256 + threadIdx.x;
  if (e >= NE) return;
  int r = ei[e], c = ei[NE + e];
  int pa = ea[e * 3 + 0] + ea[e * 3 + 1] * 10 + ea[e * 3 + 2] * 100;
  float nr = dis[r] * dis[c];
  int pos = atomicAdd(&nxt[c], 1);
  recs[pos] = make_int4(r, pa, __float_as_int(nr), 0);
}

// ---------- combined bond table (fp32): btc[pa][d] ----------
__global__ __launch_bounds__(256) void k_btc(const float* __restrict__ bt,
    float* __restrict__ btc) {
  int idx = blockIdx.x * 256 + threadIdx.x;       // 1000*128 exact
  int p = idx >> 7, d = idx & 127;
  int a = p % 10, b = (p / 10) % 10, c = p / 100;
  btc[idx] = bt[(0 * BV + a) * DD + d] + bt[(1 * BV + b) * DD + d]
           + bt[(2 * BV + c) * DD + d];
}

// ---------- W -> bf16 ----------
__global__ __launch_bounds__(256) void k_wconv(const float* __restrict__ W,
    ushort* __restrict__ Wbf) {
  int i = blockIdx.x * 256 + threadIdx.x;         // 5*128*128 exact
  Wbf[i] = f2bf(W[i]);
}

// ---------- MFMA GEMM: hl(BF16) = A' @ Wl^T + bl ----------
// mode0: A' = srcbf (bf16, = acts slot 0 from encode).
// mode1: A' = relu(pre_fp32*scale+shift); A' (bf16) STORED to actl for the
//        deferred out-sum in k_apply_final (no out RMW here).
// pre is FP32 (R9's bf16 pre compounded error through the layer recurrence,
// absmax 2.75 > 1.94 -> reverted). Phased: load burst / activation / act store
// / MFMA loop (R8).
__global__ __launch_bounds__(256) void k_gemm(const ushort* __restrict__ srcbf,
    const float* __restrict__ srcp, const ushort* __restrict__ Wbf,
    const float* __restrict__ bl, const float* __restrict__ scale,
    const float* __restrict__ shift, ushort* __restrict__ actl,
    ushort* __restrict__ hl, int mode) {
  int t = threadIdx.x;
  int lane = t & 63, wave = t >> 6;
  int col = lane & 15, quad = lane >> 4;
  int nb = blockIdx.x * 128 + wave * 32;
  int r0 = nb + col, r1 = nb + 16 + col;
  bool v0 = r0 < NN, v1 = r1 < NN;
  long a0off = (long)(v0 ? r0 : NN - 1) * DD;
  long a1off = (long)(v1 ? r1 : NN - 1) * DD;

  s8v af0[4], af1[4];                             // A fragments, 4 k-slices

  if (mode == 0) {
#pragma unroll
    for (int ks = 0; ks < 4; ++ks) {              // 8 loads, one burst
      int k0 = ks * 32 + quad * 8;
      af0[ks] = *(const s8v*)&srcbf[a0off + k0];
      af1[ks] = *(const s8v*)&srcbf[a1off + k0];
    }
  } else {
    float4 pA[4][2], pB[4][2];                    // 64 VGPR of fp32 pre
#pragma unroll
    for (int ks = 0; ks < 4; ++ks) {              // 16 loads, one burst
      int k0 = ks * 32 + quad * 8;
      pA[ks][0] = *(const float4*)&srcp[a0off + k0];
      pA[ks][1] = *(const float4*)&srcp[a0off + k0 + 4];
      pB[ks][0] = *(const float4*)&srcp[a1off + k0];
      pB[ks][1] = *(const float4*)&srcp[a1off + k0 + 4];
    }
#pragma unroll
    for (int ks = 0; ks < 4; ++ks) {              // activation + pack (VALU)
      int k0 = ks * 32 + quad * 8;
      float4 sc0 = *(const float4*)&scale[k0];
      float4 sc1 = *(const float4*)&scale[k0 + 4];
      float4 sh0 = *(const float4*)&shift[k0];
      float4 sh1 = *(const float4*)&shift[k0 + 4];
      float scv[8] = {sc0.x, sc0.y, sc0.z, sc0.w, sc1.x, sc1.y, sc1.z, sc1.w};
      float shv[8] = {sh0.x, sh0.y, sh0.z, sh0.w, sh1.x, sh1.y, sh1.z, sh1.w};
      float pv0[8] = {pA[ks][0].x, pA[ks][0].y, pA[ks][0].z, pA[ks][0].w,
                      pA[ks][1].x, pA[ks][1].y, pA[ks][1].z, pA[ks][1].w};
      float pv1[8] = {pB[ks][0].x, pB[ks][0].y, pB[ks][0].z, pB[ks][0].w,
                      pB[ks][1].x, pB[ks][1].y, pB[ks][1].z, pB[ks][1].w};
#pragma unroll
      for (int j = 0; j < 8; ++j) {
        float w = fmaxf(pv0[j] * scv[j] + shv[j], 0.f);
        af0[ks][j] = (short)f2bf(w);
        float u = fmaxf(pv1[j] * scv[j] + shv[j], 0.f);
        af1[ks][j] = (short)f2bf(u);
      }
    }
    // store A' (bf16) for deferred out-sum (replaces the 102R+102W out RMW)
    if (v0) {
#pragma unroll
      for (int ks = 0; ks < 4; ++ks)
        *(s8v*)&actl[a0off + ks * 32 + quad * 8] = af0[ks];
    }
    if (v1) {
#pragma unroll
      for (int ks = 0; ks < 4; ++ks)
        *(s8v*)&actl[a1off + ks * 32 + quad * 8] = af1[ks];
    }
  }

  f4v acc[2][8];
#pragma unroll
  for (int i = 0; i < 2; ++i)
#pragma unroll
    for (int j = 0; j < 8; ++j) acc[i][j] = (f4v)0.f;

#pragma unroll
  for (int ks = 0; ks < 4; ++ks) {                // MFMA loop: W loads (L2) + 64 MFMA
    int k0 = ks * 32 + quad * 8;
#pragma unroll
    for (int j = 0; j < 8; ++j) {                 // B[k][n=col] for out-tile j = W[j*16+col][k]
      s8v bf = *(const s8v*)&Wbf[(j * 16 + col) * DD + k0];
      acc[0][j] = __builtin_amdgcn_mfma_f32_16x16x32_bf16(af0[ks], bf, acc[0][j], 0, 0, 0);
      acc[1][j] = __builtin_amdgcn_mfma_f32_16x16x32_bf16(af1[ks], bf, acc[1][j], 0, 0, 0);
    }
  }

  float bb[8];
#pragma unroll
  for (int j = 0; j < 8; ++j) bb[j] = bl[j * 16 + col];
#pragma unroll
  for (int i = 0; i < 2; ++i) {
    int rowb = nb + i * 16 + quad * 4;            // D: col=lane&15, row=quad*4+reg
#pragma unroll
    for (int r = 0; r < 4; ++r) {
      int n = rowb + r;
      if (n < NN) {
#pragma unroll
        for (int j = 0; j < 8; ++j)
          hl[(long)n * DD + j * 16 + col] = f2bf(acc[i][j][r] + bb[j]);
      }
    }
  }
}

// ---------- gather-aggregate + self term + BN partials ----------
// QUARTER-wave (16 lanes) owns a CONTIGUOUS run of 8 nodes; lane covers
// d = (lane&15)*8 .. +7. hl bf16 (16B/edge/lane); pre written FP32 (recurrence
// accuracy). Rolling 2-record recs prefetch. Plain __launch_bounds__ (R5 lesson).
__global__ __launch_bounds__(256) void k_aggregate(const ushort* __restrict__ hl,
    const int* __restrict__ off, const int4* __restrict__ recs,
    const float* __restrict__ btc, const float* __restrict__ rootl,
    const float* __restrict__ invd, float* __restrict__ pre,
    float* __restrict__ gsum, float* __restrict__ gss) {
  __shared__ float redS[256][9], redQ[256][9];     // +1 pad: conflict-free
  int t = threadIdx.x;
  int ql = t & 15;                                 // lane within quarter-wave
  int qs = t >> 4;                                 // quarter-slot 0..15
  int d0 = ql * 8;
  int base = blockIdx.x * 128 + qs * 8;
  float4 rt0 = *(const float4*)&rootl[d0];
  float4 rt1 = *(const float4*)&rootl[d0 + 4];
  float4 s0 = make_float4(0.f, 0.f, 0.f, 0.f), s1 = s0;
  float4 q0 = s0, q1 = s0;
  if (base < NN) {
    int eptr = off[base];
    int enext = off[base + 1];
    int4 r0 = recs[(eptr < NE) ? eptr : (NE - 1)];           // rolling prefetch regs
    int4 r1 = recs[(eptr + 1 < NE) ? eptr + 1 : (NE - 1)];
#pragma unroll 1
    for (int j = 0; j < 8; ++j) {
      int n = base + j;
      int ia = base + j + 2; if (ia > NN) ia = NN;
      int e_after = off[ia];                       // issued early, used next iter
      int eend = enext;
      s8v sv = *(const s8v*)&hl[(long)n * DD + d0];          // self-term (bf16)
      float iv = invd[n];
      float4 aca = make_float4(0.f, 0.f, 0.f, 0.f), acb = aca;
      while (eptr + 2 <= eend) {                   // 2 edges per trip
        int4 ra = r0, rb = r1;
        int p0 = eptr + 2; if (p0 >= NE) p0 = NE - 1;
        int p1 = eptr + 3; if (p1 >= NE) p1 = NE - 1;
        r0 = recs[p0];                             // prefetch next pair
        r1 = recs[p1];
        s8v ha = *(const s8v*)&hl[(long)ra.x * DD + d0];     // 16B bf16 gather
        float4 ea0 = *(const float4*)&btc[ra.y * DD + d0];
        float4 ea1 = *(const float4*)&btc[ra.y * DD + d0 + 4];
        s8v hb = *(const s8v*)&hl[(long)rb.x * DD + d0];
        float4 eb0 = *(const float4*)&btc[rb.y * DD + d0];
        float4 eb1 = *(const float4*)&btc[rb.y * DD + d0 + 4];
        float na = __int_as_float(ra.z);
        float nb = __int_as_float(rb.z);
        aca.x += fmaxf(bf2f((ushort)ha[0]) + ea0.x, 0.f) * na + fmaxf(bf2f((ushort)hb[0]) + eb0.x, 0.f) * nb;
        aca.y += fmaxf(bf2f((ushort)ha[1]) + ea0.y, 0.f) * na + fmaxf(bf2f((ushort)hb[1]) + eb0.y, 0.f) * nb;
        aca.z += fmaxf(bf2f((ushort)ha[2]) + ea0.z, 0.f) * na + fmaxf(bf2f((ushort)hb[2]) + eb0.z, 0.f) * nb;
        aca.w += fmaxf(bf2f((ushort)ha[3]) + ea0.w, 0.f) * na + fmaxf(bf2f((ushort)hb[3]) + eb0.w, 0.f) * nb;
        acb.x += fmaxf(bf2f((ushort)ha[4]) + ea1.x, 0.f) * na + fmaxf(bf2f((ushort)hb[4]) + eb1.x, 0.f) * nb;
        acb.y += fmaxf(bf2f((ushort)ha[5]) + ea1.y, 0.f) * na + fmaxf(bf2f((ushort)hb[5]) + eb1.y, 0.f) * nb;
        acb.z += fmaxf(bf2f((ushort)ha[6]) + ea1.z, 0.f) * na + fmaxf(bf2f((ushort)hb[6]) + eb1.z, 0.f) * nb;
        acb.w += fmaxf(bf2f((ushort)ha[7]) + ea1.w, 0.f) * na + fmaxf(bf2f((ushort)hb[7]) + eb1.w, 0.f) * nb;
        eptr += 2;
      }
      if (eptr < eend) {                           // odd leftover edge
        int4 ra = r0;
        int4 tmp = r1;
        int p0 = eptr + 2; if (p0 >= NE) p0 = NE - 1;
        r1 = recs[p0];                             // maintain rolling invariant
        r0 = tmp;
        s8v hv = *(const s8v*)&hl[(long)ra.x * DD + d0];
        float4 ev0 = *(const float4*)&btc[ra.y * DD + d0];
        float4 ev1 = *(const float4*)&btc[ra.y * DD + d0 + 4];
        float nr = __int_as_float(ra.z);
        aca.x += fmaxf(bf2f((ushort)hv[0]) + ev0.x, 0.f) * nr;
        aca.y += fmaxf(bf2f((ushort)hv[1]) + ev0.y, 0.f) * nr;
        aca.z += fmaxf(bf2f((ushort)hv[2]) + ev0.z, 0.f) * nr;
        aca.w += fmaxf(bf2f((ushort)hv[3]) + ev0.w, 0.f) * nr;
        acb.x += fmaxf(bf2f((ushort)hv[4]) + ev1.x, 0.f) * nr;
        acb.y += fmaxf(bf2f((ushort)hv[5]) + ev1.y, 0.f) * nr;
        acb.z += fmaxf(bf2f((ushort)hv[6]) + ev1.z, 0.f) * nr;
        acb.w += fmaxf(bf2f((ushort)hv[7]) + ev1.w, 0.f) * nr;
        eptr += 1;
      }
      float4 pa, pb;
      pa.x = aca.x + fmaxf(bf2f((ushort)sv[0]) + rt0.x, 0.f) * iv;
      pa.y = aca.y + fmaxf(bf2f((ushort)sv[1]) + rt0.y, 0.f) * iv;
      pa.z = aca.z + fmaxf(bf2f((ushort)sv[2]) + rt0.z, 0.f) * iv;
      pa.w = aca.w + fmaxf(bf2f((ushort)sv[3]) + rt0.w, 0.f) * iv;
      pb.x = acb.x + fmaxf(bf2f((ushort)sv[4]) + rt1.x, 0.f) * iv;
      pb.y = acb.y + fmaxf(bf2f((ushort)sv[5]) + rt1.y, 0.f) * iv;
      pb.z = acb.z + fmaxf(bf2f((ushort)sv[6]) + rt1.z, 0.f) * iv;
      pb.w = acb.w + fmaxf(bf2f((ushort)sv[7]) + rt1.w, 0.f) * iv;
      *(float4*)&pre[(long)n * DD + d0] = pa;
      *(float4*)&pre[(long)n * DD + d0 + 4] = pb;
      s0.x += pa.x; s0.y += pa.y; s0.z += pa.z; s0.w += pa.w;
      s1.x += pb.x; s1.y += pb.y; s1.z += pb.z; s1.w += pb.w;
      q0.x += pa.x * pa.x; q0.y += pa.y * pa.y; q0.z += pa.z * pa.z; q0.w += pa.w * pa.w;
      q1.x += pb.x * pb.x; q1.y += pb.y * pb.y; q1.z += pb.z * pb.z; q1.w += pb.w * pb.w;
      enext = e_after;
    }
  }
  redS[t][0] = s0.x; redS[t][1] = s0.y; redS[t][2] = s0.z; redS[t][3] = s0.w;
  redS[t][4] = s1.x; redS[t][5] = s1.y; redS[t][6] = s1.z; redS[t][7] = s1.w;
  redQ[t][0] = q0.x; redQ[t][1] = q0.y; redQ[t][2] = q0.z; redQ[t][3] = q0.w;
  redQ[t][4] = q1.x; redQ[t][5] = q1.y; redQ[t][6] = q1.z; redQ[t][7] = q1.w;
  __syncthreads();
  if (t < 128) {                                   // d = t; lane qq=d>>3 covers d&7
    int qq = t >> 3, c = t & 7;
    float S = 0.f, Q = 0.f;
#pragma unroll
    for (int h = 0; h < 16; ++h) {
      S += redS[h * 16 + qq][c];
      Q += redQ[h * 16 + qq][c];
    }
    atomicAdd(&gsum[t], S);
    atomicAdd(&gss[t], Q);
  }
}

__global__ void k_bnfin(const float* __restrict__ gsum, const float* __restrict__ gss,
    const float* __restrict__ gl, const float* __restrict__ bl,
    float* __restrict__ scale, float* __restrict__ shift) {
  int d = threadIdx.x;
  float m = gsum[d] * (1.0f / NN);
  float v = gss[d] * (1.0f / NN) - m * m;
  float sc = gl[d] * rsqrtf(v + EPSV);
  scale[d] = sc;
  shift[d] = bl[d] - m * sc;
}

// ---------- final: out = h + sum_{l=0..3} act_l + (pre4*scale4 + shift4) ----------
__global__ __launch_bounds__(256) void k_apply_final(const float* __restrict__ pre,
    const ushort* __restrict__ acts, const float* __restrict__ scale,
    const float* __restrict__ shift, float* __restrict__ out) {
  const int NDH = NN * DD / 2;                    // uint elements per slot
  int idx = blockIdx.x * 256 + threadIdx.x;       // N*D/2 exact
  int dp = idx & 63;
  uint a0 = ((const uint*)acts)[idx];
  uint a1 = ((const uint*)acts)[idx + NDH];
  uint a2 = ((const uint*)acts)[idx + 2 * NDH];
  uint a3 = ((const uint*)acts)[idx + 3 * NDH];
  float2 pv = *(const float2*)&pre[idx * 2];
  float2 o = *(const float2*)&out[idx * 2];
  o.x += bf2f((ushort)a0) + bf2f((ushort)a1) + bf2f((ushort)a2) + bf2f((ushort)a3)
       + pv.x * scale[dp * 2] + shift[dp * 2];
  o.y += bf2f((ushort)(a0 >> 16)) + bf2f((ushort)(a1 >> 16)) + bf2f((ushort)(a2 >> 16))
       + bf2f((ushort)(a3 >> 16))
       + pv.y * scale[dp * 2 + 1] + shift[dp * 2 + 1];
  *(float2*)&out[idx * 2] = o;
}

extern "C" void kernel_launch(void* const* d_in, const int* in_sizes, int n_in,
                              void* d_out, int out_size, void* d_ws, size_t ws_size,
                              hipStream_t stream) {
  const int*   x     = (const int*)d_in[0];
  const int*   ei    = (const int*)d_in[1];
  const int*   ea    = (const int*)d_in[2];
  const float* at    = (const float*)d_in[3];
  const float* bt    = (const float*)d_in[4];
  const float* W     = (const float*)d_in[5];
  const float* b     = (const float*)d_in[6];
  const float* root  = (const float*)d_in[7];
  const float* gamma = (const float*)d_in[8];
  const float* beta  = (const float*)d_in[9];
  float* out = (float*)d_out;

  char* ws = (char*)d_ws;
  size_t ND = (size_t)NN * DD;
  ushort* hl   = (ushort*)ws;                       // ND bf16
  float*  pre  = (float*)(hl + ND);                 // ND fp32
  ushort* acts = (ushort*)(pre + ND);               // 4*ND bf16; slot0 doubles as encode hbuf
  int4*   recs = (int4*)(acts + 4 * ND);            // NE * 16B (byte off 14*ND, 16B-aligned)
  ushort* Wbf  = (ushort*)(recs + NE);              // 5*128*128 bf16
  float*  btc  = (float*)(Wbf + NL * DD * DD);      // 1000*128 fp32
  float*  deg  = btc + 1000 * DD;                   // N
  float*  dis  = deg + NN;                          // N
  float*  invd = dis + NN;                          // N
  int*    cnt  = (int*)(invd + NN);                 // N
  int*    offa = cnt + NN;                          // N+1 (+3 pad)
  int*    nxt  = offa + NN + 4;                     // N
  int*    bsum = nxt + NN;                          // 256
  int*    bbase= bsum + 256;                        // 256
  float*  gsum = (float*)(bbase + 256);             // D
  float*  gss  = gsum + DD;                         // D
  float*  scaleb = gss + DD;                        // D
  float*  shiftb = scaleb + DD;                     // D

  // ---- precompute ----
  k_deg_init<<<(NN + 255) / 256, 256, 0, stream>>>(deg, cnt);
  k_deg_count<<<(NE + 255) / 256, 256, 0, stream>>>(ei, deg, cnt);
  k_deg_fin<<<(NN + 255) / 256, 256, 0, stream>>>(deg, dis, invd);
  k_scan1<<<SCAN_BLKS, 256, 0, stream>>>(cnt, offa, bsum);
  k_scan2<<<1, 256, 0, stream>>>(bsum, bbase);
  k_scan3<<<(NN + 255) / 256, 256, 0, stream>>>(offa, bbase, nxt);
  k_fill<<<(NE + 255) / 256, 256, 0, stream>>>(ei, ea, dis, nxt, recs);
  k_btc<<<1000 * DD / 256, 256, 0, stream>>>(bt, btc);
  k_wconv<<<NL * DD * DD / 256, 256, 0, stream>>>(W, Wbf);
  k_encode<<<(int)(ND / 2 / 256), 256, 0, stream>>>(x, at, acts, out);

  // ---- layers ----
  for (int l = 0; l < NL; ++l) {
    hipMemsetAsync(gsum, 0, 2 * DD * sizeof(float), stream);
    // mode1 (l>=1) writes A'_{l-1} (= out_{l-1}) into acts slot l-1; slot0's
    // encode content is consumed by gemm_0 before gemm_1 overwrites it.
    k_gemm<<<(NN + 127) / 128, 256, 0, stream>>>(
        acts, pre, Wbf + (size_t)l * DD * DD, b + l * DD,
        scaleb, shiftb, acts + (size_t)(l == 0 ? 0 : l - 1) * ND,
        hl, (l == 0) ? 0 : 1);
    k_aggregate<<<(NN + 127) / 128, 256, 0, stream>>>(hl, offa, recs, btc,
        root + l * DD, invd, pre, gsum, gss);
    k_bnfin<<<1, DD, 0, stream>>>(gsum, gss, gamma + l * DD, beta + l * DD,
                                  scaleb, shiftb);
  }
  k_apply_final<<<(int)(ND / 2 / 256), 256, 0, stream>>>(pre, acts, scaleb,
                                                         shiftb, out);
}

// Round 12
// 1045.518 us; speedup vs baseline: 1.6157x; 1.0148x over previous
//
#include <hip/hip_runtime.h>

#define NN 200000
#define NE 400000
#define DD 128
#define NL 5
#define AV 100
#define BV 10
#define EPSV 1e-5f
#define SCAN_BLKS 196   // ceil(NN/1024)

typedef short s8v __attribute__((ext_vector_type(8)));   // 8 bf16 (4 VGPRs)
typedef float f4v __attribute__((ext_vector_type(4)));   // 4 fp32 acc

__device__ __forceinline__ ushort f2bf(float f) {        // RNE float->bf16
  uint u = __float_as_uint(f);
  u += 0x7FFFu + ((u >> 16) & 1u);
  return (ushort)(u >> 16);
}

__device__ __forceinline__ float bf2f(ushort u) {        // bf16->float
  return __uint_as_float(((uint)u) << 16);
}

// ---------- encode: h = sum of atom embeddings -> acts slot 0 (bf16 only).
// No fp32 out write: k_apply_final reconstructs out (h is folded into act_0
// by gemm_1 before slot 0 is overwritten). ----------
__global__ __launch_bounds__(256) void k_encode(const int* __restrict__ x,
    const float* __restrict__ at, ushort* __restrict__ hbuf) {
  int idx = blockIdx.x * 256 + threadIdx.x;       // N*D/2 threads exact
  int n = idx >> 6, dp = idx & 63;                // wave = one node -> x row broadcast
  const int* xr = x + n * 9;
  float s0 = 0.f, s1 = 0.f;
#pragma unroll
  for (int c = 0; c < 9; ++c) {
    float2 v = *(const float2*)&at[(c * AV + xr[c]) * DD + dp * 2];
    s0 += v.x; s1 += v.y;
  }
  ((uint*)hbuf)[idx] = (uint)f2bf(s0) | ((uint)f2bf(s1) << 16);
}

// ---------- degree ----------
__global__ __launch_bounds__(256) void k_deg_init(float* __restrict__ deg,
                                                  int* __restrict__ cnt) {
  int i = blockIdx.x * 256 + threadIdx.x;
  if (i < NN) { deg[i] = 1.0f; cnt[i] = 0; }
}

__global__ __launch_bounds__(256) void k_deg_count(const int* __restrict__ ei,
    float* __restrict__ deg, int* __restrict__ cnt) {
  int e = blockIdx.x * 256 + threadIdx.x;
  if (e < NE) {
    atomicAdd(&deg[ei[e]], 1.0f);
    atomicAdd(&cnt[ei[NE + e]], 1);
  }
}

__global__ __launch_bounds__(256) void k_deg_fin(const float* __restrict__ deg,
    float* __restrict__ dis, float* __restrict__ invd) {
  int i = blockIdx.x * 256 + threadIdx.x;
  if (i < NN) {
    float dg = deg[i];
    dis[i] = rsqrtf(dg);
    invd[i] = 1.0f / dg;
  }
}

// ---------- exclusive scan of cnt -> off ----------
__global__ __launch_bounds__(256) void k_scan1(const int* __restrict__ cnt,
    int* __restrict__ off, int* __restrict__ bsum) {
  __shared__ int s[256];
  int t = threadIdx.x;
  int base = blockIdx.x * 1024 + t * 4;
  int c0 = (base + 0 < NN) ? cnt[base + 0] : 0;
  int c1 = (base + 1 < NN) ? cnt[base + 1] : 0;
  int c2 = (base + 2 < NN) ? cnt[base + 2] : 0;
  int c3 = (base + 3 < NN) ? cnt[base + 3] : 0;
  int tsum = c0 + c1 + c2 + c3;
  s[t] = tsum;
  __syncthreads();
  for (int o = 1; o < 256; o <<= 1) {
    int v = (t >= o) ? s[t - o] : 0;
    __syncthreads();
    s[t] += v;
    __syncthreads();
  }
  int excl = s[t] - tsum;
  if (base + 0 < NN) off[base + 0] = excl;
  if (base + 1 < NN) off[base + 1] = excl + c0;
  if (base + 2 < NN) off[base + 2] = excl + c0 + c1;
  if (base + 3 < NN) off[base + 3] = excl + c0 + c1 + c2;
  if (t == 255) bsum[blockIdx.x] = s[255];
}

__global__ __launch_bounds__(256) void k_scan2(const int* __restrict__ bsum,
    int* __restrict__ bbase) {
  __shared__ int s[256];
  int t = threadIdx.x;
  int v0 = (t < SCAN_BLKS) ? bsum[t] : 0;
  s[t] = v0;
  __syncthreads();
  for (int o = 1; o < 256; o <<= 1) {
    int v = (t >= o) ? s[t - o] : 0;
    __syncthreads();
    s[t] += v;
    __syncthreads();
  }
  if (t < SCAN_BLKS) bbase[t] = s[t] - v0;
}

__global__ __launch_bounds__(256) void k_scan3(int* __restrict__ off,
    const int* __restrict__ bbase, int* __restrict__ nxt) {
  int i = blockIdx.x * 256 + threadIdx.x;
  if (i < NN) {
    int v = off[i] + bbase[i >> 10];
    off[i] = v;
    nxt[i] = v;
  }
  if (i == 0) off[NN] = NE;
}

// ---------- fill CSR records: {row, packed_ea, norm_bits, 0} ----------
__global__ __launch_bounds__(256) void k_fill(const int* __restrict__ ei,
    const int* __restrict__ ea, const float* __restrict__ dis,
    int* __restrict__ nxt, int4* __restrict__ recs) {
  int e = blockIdx.x * 256 + threadIdx.x;
  if (e >= NE) return;
  int r = ei[e], c = ei[NE + e];
  int pa = ea[e * 3 + 0] + ea[e * 3 + 1] * 10 + ea[e * 3 + 2] * 100;
  float nr = dis[r] * dis[c];
  int pos = atomicAdd(&nxt[c], 1);
  recs[pos] = make_int4(r, pa, __float_as_int(nr), 0);
}

// ---------- combined bond table (fp32): btc[pa][d] ----------
__global__ __launch_bounds__(256) void k_btc(const float* __restrict__ bt,
    float* __restrict__ btc) {
  int idx = blockIdx.x * 256 + threadIdx.x;       // 1000*128 exact
  int p = idx >> 7, d = idx & 127;
  int a = p % 10, b = (p / 10) % 10, c = p / 100;
  btc[idx] = bt[(0 * BV + a) * DD + d] + bt[(1 * BV + b) * DD + d]
           + bt[(2 * BV + c) * DD + d];
}

// ---------- W -> bf16 ----------
__global__ __launch_bounds__(256) void k_wconv(const float* __restrict__ W,
    ushort* __restrict__ Wbf) {
  int i = blockIdx.x * 256 + threadIdx.x;         // 5*128*128 exact
  Wbf[i] = f2bf(W[i]);
}

// ---------- MFMA GEMM: hl(BF16) = A' @ Wl^T + bl ----------
// mode0: A' = srcbf (bf16 h from encode, = acts slot 0).
// mode1: A' = relu(pre_fp32*scale+shift); A' (bf16) stored to actl.
// mode2: same as mode1, but actl currently holds h (slot 0, l==1 launch):
//        store bf16(h + A') so h is folded into act_0 and k_apply_final
//        needs no separate h read. Workspace identical to R10 (no hbf buffer
//        -- R11's +51MB layout may have exceeded ws_size and crashed).
// pre is FP32 (recurrence accuracy). Phased: load burst / activation /
// act store / MFMA loop.
__global__ __launch_bounds__(256) void k_gemm(const ushort* __restrict__ srcbf,
    const float* __restrict__ srcp, const ushort* __restrict__ Wbf,
    const float* __restrict__ bl, const float* __restrict__ scale,
    const float* __restrict__ shift, ushort* __restrict__ actl,
    ushort* __restrict__ hl, int mode) {
  int t = threadIdx.x;
  int lane = t & 63, wave = t >> 6;
  int col = lane & 15, quad = lane >> 4;
  int nb = blockIdx.x * 128 + wave * 32;
  int r0 = nb + col, r1 = nb + 16 + col;
  bool v0 = r0 < NN, v1 = r1 < NN;
  long a0off = (long)(v0 ? r0 : NN - 1) * DD;
  long a1off = (long)(v1 ? r1 : NN - 1) * DD;

  s8v af0[4], af1[4];                             // A fragments, 4 k-slices

  if (mode == 0) {
#pragma unroll
    for (int ks = 0; ks < 4; ++ks) {              // 8 loads, one burst
      int k0 = ks * 32 + quad * 8;
      af0[ks] = *(const s8v*)&srcbf[a0off + k0];
      af1[ks] = *(const s8v*)&srcbf[a1off + k0];
    }
  } else {
    float4 pA[4][2], pB[4][2];                    // 64 VGPR of fp32 pre
#pragma unroll
    for (int ks = 0; ks < 4; ++ks) {              // 16 loads, one burst
      int k0 = ks * 32 + quad * 8;
      pA[ks][0] = *(const float4*)&srcp[a0off + k0];
      pA[ks][1] = *(const float4*)&srcp[a0off + k0 + 4];
      pB[ks][0] = *(const float4*)&srcp[a1off + k0];
      pB[ks][1] = *(const float4*)&srcp[a1off + k0 + 4];
    }
#pragma unroll
    for (int ks = 0; ks < 4; ++ks) {              // activation + pack (VALU)
      int k0 = ks * 32 + quad * 8;
      float4 sc0 = *(const float4*)&scale[k0];
      float4 sc1 = *(const float4*)&scale[k0 + 4];
      float4 sh0 = *(const float4*)&shift[k0];
      float4 sh1 = *(const float4*)&shift[k0 + 4];
      float scv[8] = {sc0.x, sc0.y, sc0.z, sc0.w, sc1.x, sc1.y, sc1.z, sc1.w};
      float shv[8] = {sh0.x, sh0.y, sh0.z, sh0.w, sh1.x, sh1.y, sh1.z, sh1.w};
      float pv0[8] = {pA[ks][0].x, pA[ks][0].y, pA[ks][0].z, pA[ks][0].w,
                      pA[ks][1].x, pA[ks][1].y, pA[ks][1].z, pA[ks][1].w};
      float pv1[8] = {pB[ks][0].x, pB[ks][0].y, pB[ks][0].z, pB[ks][0].w,
                      pB[ks][1].x, pB[ks][1].y, pB[ks][1].z, pB[ks][1].w};
#pragma unroll
      for (int j = 0; j < 8; ++j) {
        float w = fmaxf(pv0[j] * scv[j] + shv[j], 0.f);
        af0[ks][j] = (short)f2bf(w);
        float u = fmaxf(pv1[j] * scv[j] + shv[j], 0.f);
        af1[ks][j] = (short)f2bf(u);
      }
    }
    // store A' (bf16); mode2 folds the h currently in actl (read-then-write,
    // same thread, same addresses -- no race)
    if (v0) {
#pragma unroll
      for (int ks = 0; ks < 4; ++ks) {
        int k0 = ks * 32 + quad * 8;
        s8v st = af0[ks];
        if (mode == 2) {
          s8v h8 = *(const s8v*)&actl[a0off + k0];
#pragma unroll
          for (int j = 0; j < 8; ++j)
            st[j] = (short)f2bf(bf2f((ushort)h8[j]) + bf2f((ushort)af0[ks][j]));
        }
        *(s8v*)&actl[a0off + k0] = st;
      }
    }
    if (v1) {
#pragma unroll
      for (int ks = 0; ks < 4; ++ks) {
        int k0 = ks * 32 + quad * 8;
        s8v st = af1[ks];
        if (mode == 2) {
          s8v h8 = *(const s8v*)&actl[a1off + k0];
#pragma unroll
          for (int j = 0; j < 8; ++j)
            st[j] = (short)f2bf(bf2f((ushort)h8[j]) + bf2f((ushort)af1[ks][j]));
        }
        *(s8v*)&actl[a1off + k0] = st;
      }
    }
  }

  f4v acc[2][8];
#pragma unroll
  for (int i = 0; i < 2; ++i)
#pragma unroll
    for (int j = 0; j < 8; ++j) acc[i][j] = (f4v)0.f;

#pragma unroll
  for (int ks = 0; ks < 4; ++ks) {                // MFMA loop: W loads (L2) + 64 MFMA
    int k0 = ks * 32 + quad * 8;
#pragma unroll
    for (int j = 0; j < 8; ++j) {                 // B[k][n=col] for out-tile j = W[j*16+col][k]
      s8v bf = *(const s8v*)&Wbf[(j * 16 + col) * DD + k0];
      acc[0][j] = __builtin_amdgcn_mfma_f32_16x16x32_bf16(af0[ks], bf, acc[0][j], 0, 0, 0);
      acc[1][j] = __builtin_amdgcn_mfma_f32_16x16x32_bf16(af1[ks], bf, acc[1][j], 0, 0, 0);
    }
  }

  float bb[8];
#pragma unroll
  for (int j = 0; j < 8; ++j) bb[j] = bl[j * 16 + col];
#pragma unroll
  for (int i = 0; i < 2; ++i) {
    int rowb = nb + i * 16 + quad * 4;            // D: col=lane&15, row=quad*4+reg
#pragma unroll
    for (int r = 0; r < 4; ++r) {
      int n = rowb + r;
      if (n < NN) {
#pragma unroll
        for (int j = 0; j < 8; ++j)
          hl[(long)n * DD + j * 16 + col] = f2bf(acc[i][j][r] + bb[j]);
      }
    }
  }
}

// ---------- gather-aggregate + self term + BN partials ----------
// QUARTER-wave (16 lanes) owns a CONTIGUOUS run of 8 nodes; lane covers
// d = (lane&15)*8 .. +7. hl bf16 (16B/edge/lane); pre written FP32 (recurrence
// accuracy). Rolling 2-record recs prefetch. Plain __launch_bounds__ (R5 lesson).
__global__ __launch_bounds__(256) void k_aggregate(const ushort* __restrict__ hl,
    const int* __restrict__ off, const int4* __restrict__ recs,
    const float* __restrict__ btc, const float* __restrict__ rootl,
    const float* __restrict__ invd, float* __restrict__ pre,
    float* __restrict__ gsum, float* __restrict__ gss) {
  __shared__ float redS[256][9], redQ[256][9];     // +1 pad: conflict-free
  int t = threadIdx.x;
  int ql = t & 15;                                 // lane within quarter-wave
  int qs = t >> 4;                                 // quarter-slot 0..15
  int d0 = ql * 8;
  int base = blockIdx.x * 128 + qs * 8;
  float4 rt0 = *(const float4*)&rootl[d0];
  float4 rt1 = *(const float4*)&rootl[d0 + 4];
  float4 s0 = make_float4(0.f, 0.f, 0.f, 0.f), s1 = s0;
  float4 q0 = s0, q1 = s0;
  if (base < NN) {
    int eptr = off[base];
    int enext = off[base + 1];
    int4 r0 = recs[(eptr < NE) ? eptr : (NE - 1)];           // rolling prefetch regs
    int4 r1 = recs[(eptr + 1 < NE) ? eptr + 1 : (NE - 1)];
#pragma unroll 1
    for (int j = 0; j < 8; ++j) {
      int n = base + j;
      int ia = base + j + 2; if (ia > NN) ia = NN;
      int e_after = off[ia];                       // issued early, used next iter
      int eend = enext;
      s8v sv = *(const s8v*)&hl[(long)n * DD + d0];          // self-term (bf16)
      float iv = invd[n];
      float4 aca = make_float4(0.f, 0.f, 0.f, 0.f), acb = aca;
      while (eptr + 2 <= eend) {                   // 2 edges per trip
        int4 ra = r0, rb = r1;
        int p0 = eptr + 2; if (p0 >= NE) p0 = NE - 1;
        int p1 = eptr + 3; if (p1 >= NE) p1 = NE - 1;
        r0 = recs[p0];                             // prefetch next pair
        r1 = recs[p1];
        s8v ha = *(const s8v*)&hl[(long)ra.x * DD + d0];     // 16B bf16 gather
        float4 ea0 = *(const float4*)&btc[ra.y * DD + d0];
        float4 ea1 = *(const float4*)&btc[ra.y * DD + d0 + 4];
        s8v hb = *(const s8v*)&hl[(long)rb.x * DD + d0];
        float4 eb0 = *(const float4*)&btc[rb.y * DD + d0];
        float4 eb1 = *(const float4*)&btc[rb.y * DD + d0 + 4];
        float na = __int_as_float(ra.z);
        float nb = __int_as_float(rb.z);
        aca.x += fmaxf(bf2f((ushort)ha[0]) + ea0.x, 0.f) * na + fmaxf(bf2f((ushort)hb[0]) + eb0.x, 0.f) * nb;
        aca.y += fmaxf(bf2f((ushort)ha[1]) + ea0.y, 0.f) * na + fmaxf(bf2f((ushort)hb[1]) + eb0.y, 0.f) * nb;
        aca.z += fmaxf(bf2f((ushort)ha[2]) + ea0.z, 0.f) * na + fmaxf(bf2f((ushort)hb[2]) + eb0.z, 0.f) * nb;
        aca.w += fmaxf(bf2f((ushort)ha[3]) + ea0.w, 0.f) * na + fmaxf(bf2f((ushort)hb[3]) + eb0.w, 0.f) * nb;
        acb.x += fmaxf(bf2f((ushort)ha[4]) + ea1.x, 0.f) * na + fmaxf(bf2f((ushort)hb[4]) + eb1.x, 0.f) * nb;
        acb.y += fmaxf(bf2f((ushort)ha[5]) + ea1.y, 0.f) * na + fmaxf(bf2f((ushort)hb[5]) + eb1.y, 0.f) * nb;
        acb.z += fmaxf(bf2f((ushort)ha[6]) + ea1.z, 0.f) * na + fmaxf(bf2f((ushort)hb[6]) + eb1.z, 0.f) * nb;
        acb.w += fmaxf(bf2f((ushort)ha[7]) + ea1.w, 0.f) * na + fmaxf(bf2f((ushort)hb[7]) + eb1.w, 0.f) * nb;
        eptr += 2;
      }
      if (eptr < eend) {                           // odd leftover edge
        int4 ra = r0;
        int4 tmp = r1;
        int p0 = eptr + 2; if (p0 >= NE) p0 = NE - 1;
        r1 = recs[p0];                             // maintain rolling invariant
        r0 = tmp;
        s8v hv = *(const s8v*)&hl[(long)ra.x * DD + d0];
        float4 ev0 = *(const float4*)&btc[ra.y * DD + d0];
        float4 ev1 = *(const float4*)&btc[ra.y * DD + d0 + 4];
        float nr = __int_as_float(ra.z);
        aca.x += fmaxf(bf2f((ushort)hv[0]) + ev0.x, 0.f) * nr;
        aca.y += fmaxf(bf2f((ushort)hv[1]) + ev0.y, 0.f) * nr;
        aca.z += fmaxf(bf2f((ushort)hv[2]) + ev0.z, 0.f) * nr;
        aca.w += fmaxf(bf2f((ushort)hv[3]) + ev0.w, 0.f) * nr;
        acb.x += fmaxf(bf2f((ushort)hv[4]) + ev1.x, 0.f) * nr;
        acb.y += fmaxf(bf2f((ushort)hv[5]) + ev1.y, 0.f) * nr;
        acb.z += fmaxf(bf2f((ushort)hv[6]) + ev1.z, 0.f) * nr;
        acb.w += fmaxf(bf2f((ushort)hv[7]) + ev1.w, 0.f) * nr;
        eptr += 1;
      }
      float4 pa, pb;
      pa.x = aca.x + fmaxf(bf2f((ushort)sv[0]) + rt0.x, 0.f) * iv;
      pa.y = aca.y + fmaxf(bf2f((ushort)sv[1]) + rt0.y, 0.f) * iv;
      pa.z = aca.z + fmaxf(bf2f((ushort)sv[2]) + rt0.z, 0.f) * iv;
      pa.w = aca.w + fmaxf(bf2f((ushort)sv[3]) + rt0.w, 0.f) * iv;
      pb.x = acb.x + fmaxf(bf2f((ushort)sv[4]) + rt1.x, 0.f) * iv;
      pb.y = acb.y + fmaxf(bf2f((ushort)sv[5]) + rt1.y, 0.f) * iv;
      pb.z = acb.z + fmaxf(bf2f((ushort)sv[6]) + rt1.z, 0.f) * iv;
      pb.w = acb.w + fmaxf(bf2f((ushort)sv[7]) + rt1.w, 0.f) * iv;
      *(float4*)&pre[(long)n * DD + d0] = pa;
      *(float4*)&pre[(long)n * DD + d0 + 4] = pb;
      s0.x += pa.x; s0.y += pa.y; s0.z += pa.z; s0.w += pa.w;
      s1.x += pb.x; s1.y += pb.y; s1.z += pb.z; s1.w += pb.w;
      q0.x += pa.x * pa.x; q0.y += pa.y * pa.y; q0.z += pa.z * pa.z; q0.w += pa.w * pa.w;
      q1.x += pb.x * pb.x; q1.y += pb.y * pb.y; q1.z += pb.z * pb.z; q1.w += pb.w * pb.w;
      enext = e_after;
    }
  }
  redS[t][0] = s0.x; redS[t][1] = s0.y; redS[t][2] = s0.z; redS[t][3] = s0.w;
  redS[t][4] = s1.x; redS[t][5] = s1.y; redS[t][6] = s1.z; redS[t][7] = s1.w;
  redQ[t][0] = q0.x; redQ[t][1] = q0.y; redQ[t][2] = q0.z; redQ[t][3] = q0.w;
  redQ[t][4] = q1.x; redQ[t][5] = q1.y; redQ[t][6] = q1.z; redQ[t][7] = q1.w;
  __syncthreads();
  if (t < 128) {                                   // d = t; lane qq=d>>3 covers d&7
    int qq = t >> 3, c = t & 7;
    float S = 0.f, Q = 0.f;
#pragma unroll
    for (int h = 0; h < 16; ++h) {
      S += redS[h * 16 + qq][c];
      Q += redQ[h * 16 + qq][c];
    }
    atomicAdd(&gsum[t], S);
    atomicAdd(&gss[t], Q);
  }
}

__global__ void k_bnfin(const float* __restrict__ gsum, const float* __restrict__ gss,
    const float* __restrict__ gl, const float* __restrict__ bl,
    float* __restrict__ scale, float* __restrict__ shift) {
  int d = threadIdx.x;
  float m = gsum[d] * (1.0f / NN);
  float v = gss[d] * (1.0f / NN) - m * m;
  float sc = gl[d] * rsqrtf(v + EPSV);
  scale[d] = sc;
  shift[d] = bl[d] - m * sc;
}

// ---------- final: out = (h+act0) + act1 + act2 + act3 + (pre4*scale4 + shift4)
// Pure write of out (no read; slot 0 already contains h+act0). ----------
__global__ __launch_bounds__(256) void k_apply_final(const float* __restrict__ pre,
    const ushort* __restrict__ acts, const float* __restrict__ scale,
    const float* __restrict__ shift, float* __restrict__ out) {
  const int NDH = NN * DD / 2;                    // uint elements per slot
  int idx = blockIdx.x * 256 + threadIdx.x;       // N*D/2 exact
  int dp = idx & 63;
  uint a0 = ((const uint*)acts)[idx];
  uint a1 = ((const uint*)acts)[idx + NDH];
  uint a2 = ((const uint*)acts)[idx + 2 * NDH];
  uint a3 = ((const uint*)acts)[idx + 3 * NDH];
  float2 pv = *(const float2*)&pre[idx * 2];
  float2 o;
  o.x = bf2f((ushort)a0) + bf2f((ushort)a1) + bf2f((ushort)a2) + bf2f((ushort)a3)
      + pv.x * scale[dp * 2] + shift[dp * 2];
  o.y = bf2f((ushort)(a0 >> 16)) + bf2f((ushort)(a1 >> 16)) + bf2f((ushort)(a2 >> 16))
      + bf2f((ushort)(a3 >> 16))
      + pv.y * scale[dp * 2 + 1] + shift[dp * 2 + 1];
  *(float2*)&out[idx * 2] = o;
}

extern "C" void kernel_launch(void* const* d_in, const int* in_sizes, int n_in,
                              void* d_out, int out_size, void* d_ws, size_t ws_size,
                              hipStream_t stream) {
  const int*   x     = (const int*)d_in[0];
  const int*   ei    = (const int*)d_in[1];
  const int*   ea    = (const int*)d_in[2];
  const float* at    = (const float*)d_in[3];
  const float* bt    = (const float*)d_in[4];
  const float* W     = (const float*)d_in[5];
  const float* b     = (const float*)d_in[6];
  const float* root  = (const float*)d_in[7];
  const float* gamma = (const float*)d_in[8];
  const float* beta  = (const float*)d_in[9];
  float* out = (float*)d_out;

  char* ws = (char*)d_ws;
  size_t ND = (size_t)NN * DD;
  ushort* hl   = (ushort*)ws;                       // ND bf16
  float*  pre  = (float*)(hl + ND);                 // ND fp32
  ushort* acts = (ushort*)(pre + ND);               // 4*ND bf16; slot0: h then h+act0
  int4*   recs = (int4*)(acts + 4 * ND);            // NE * 16B (byte off 14*ND, 16B-aligned)
  ushort* Wbf  = (ushort*)(recs + NE);              // 5*128*128 bf16
  float*  btc  = (float*)(Wbf + NL * DD * DD);      // 1000*128 fp32
  float*  deg  = btc + 1000 * DD;                   // N
  float*  dis  = deg + NN;                          // N
  float*  invd = dis + NN;                          // N
  int*    cnt  = (int*)(invd + NN);                 // N
  int*    offa = cnt + NN;                          // N+1 (+3 pad)
  int*    nxt  = offa + NN + 4;                     // N
  int*    bsum = nxt + NN;                          // 256
  int*    bbase= bsum + 256;                        // 256
  float*  gsum = (float*)(bbase + 256);             // D
  float*  gss  = gsum + DD;                         // D
  float*  scaleb = gss + DD;                        // D
  float*  shiftb = scaleb + DD;                     // D

  // ---- precompute ----
  k_deg_init<<<(NN + 255) / 256, 256, 0, stream>>>(deg, cnt);
  k_deg_count<<<(NE + 255) / 256, 256, 0, stream>>>(ei, deg, cnt);
  k_deg_fin<<<(NN + 255) / 256, 256, 0, stream>>>(deg, dis, invd);
  k_scan1<<<SCAN_BLKS, 256, 0, stream>>>(cnt, offa, bsum);
  k_scan2<<<1, 256, 0, stream>>>(bsum, bbase);
  k_scan3<<<(NN + 255) / 256, 256, 0, stream>>>(offa, bbase, nxt);
  k_fill<<<(NE + 255) / 256, 256, 0, stream>>>(ei, ea, dis, nxt, recs);
  k_btc<<<1000 * DD / 256, 256, 0, stream>>>(bt, btc);
  k_wconv<<<NL * DD * DD / 256, 256, 0, stream>>>(W, Wbf);
  k_encode<<<(int)(ND / 2 / 256), 256, 0, stream>>>(x, at, acts);

  // ---- layers ----
  for (int l = 0; l < NL; ++l) {
    hipMemsetAsync(gsum, 0, 2 * DD * sizeof(float), stream);
    // l==0: mode0 (A = h from slot0).  l==1: mode2 (store h+act0 into slot0,
    // reading the h that slot0 still holds).  l>=2: mode1 (plain act store).
    int mode = (l == 0) ? 0 : ((l == 1) ? 2 : 1);
    k_gemm<<<(NN + 127) / 128, 256, 0, stream>>>(
        acts, pre, Wbf + (size_t)l * DD * DD, b + l * DD,
        scaleb, shiftb, acts + (size_t)(l == 0 ? 0 : l - 1) * ND,
        hl, mode);
    k_aggregate<<<(NN + 127) / 128, 256, 0, stream>>>(hl, offa, recs, btc,
        root + l * DD, invd, pre, gsum, gss);
    k_bnfin<<<1, DD, 0, stream>>>(gsum, gss, gamma + l * DD, beta + l * DD,
                                  scaleb, shiftb);
  }
  k_apply_final<<<(int)(ND / 2 / 256), 256, 0, stream>>>(pre, acts, scaleb,
                                                         shiftb, out);
}

// Round 13
// 1024.171 us; speedup vs baseline: 1.6493x; 1.0208x over previous
//
#include <hip/hip_runtime.h>

#define NN 200000
#define NE 400000
#define DD 128
#define NL 5
#define AV 100
#define BV 10
#define EPSV 1e-5f
#define SCAN_BLKS 196   // ceil(NN/1024)

typedef short s8v __attribute__((ext_vector_type(8)));   // 8 bf16 (4 VGPRs)
typedef float f4v __attribute__((ext_vector_type(4)));   // 4 fp32 acc

__device__ __forceinline__ ushort f2bf(float f) {        // RNE float->bf16
  uint u = __float_as_uint(f);
  u += 0x7FFFu + ((u >> 16) & 1u);
  return (ushort)(u >> 16);
}

__device__ __forceinline__ float bf2f(ushort u) {        // bf16->float
  return __uint_as_float(((uint)u) << 16);
}

// ---------- encode: h = sum of atom embeddings -> acts slot 0 (bf16 only) ----------
__global__ __launch_bounds__(256) void k_encode(const int* __restrict__ x,
    const float* __restrict__ at, ushort* __restrict__ hbuf) {
  int idx = blockIdx.x * 256 + threadIdx.x;       // N*D/2 threads exact
  int n = idx >> 6, dp = idx & 63;                // wave = one node -> x row broadcast
  const int* xr = x + n * 9;
  float s0 = 0.f, s1 = 0.f;
#pragma unroll
  for (int c = 0; c < 9; ++c) {
    float2 v = *(const float2*)&at[(c * AV + xr[c]) * DD + dp * 2];
    s0 += v.x; s1 += v.y;
  }
  ((uint*)hbuf)[idx] = (uint)f2bf(s0) | ((uint)f2bf(s1) << 16);
}

// ---------- degree ----------
__global__ __launch_bounds__(256) void k_deg_init(float* __restrict__ deg,
                                                  int* __restrict__ cnt) {
  int i = blockIdx.x * 256 + threadIdx.x;
  if (i < NN) { deg[i] = 1.0f; cnt[i] = 0; }
}

__global__ __launch_bounds__(256) void k_deg_count(const int* __restrict__ ei,
    float* __restrict__ deg, int* __restrict__ cnt) {
  int e = blockIdx.x * 256 + threadIdx.x;
  if (e < NE) {
    atomicAdd(&deg[ei[e]], 1.0f);
    atomicAdd(&cnt[ei[NE + e]], 1);
  }
}

__global__ __launch_bounds__(256) void k_deg_fin(const float* __restrict__ deg,
    float* __restrict__ dis, float* __restrict__ invd) {
  int i = blockIdx.x * 256 + threadIdx.x;
  if (i < NN) {
    float dg = deg[i];
    dis[i] = rsqrtf(dg);
    invd[i] = 1.0f / dg;
  }
}

// ---------- exclusive scan of cnt -> off ----------
__global__ __launch_bounds__(256) void k_scan1(const int* __restrict__ cnt,
    int* __restrict__ off, int* __restrict__ bsum) {
  __shared__ int s[256];
  int t = threadIdx.x;
  int base = blockIdx.x * 1024 + t * 4;
  int c0 = (base + 0 < NN) ? cnt[base + 0] : 0;
  int c1 = (base + 1 < NN) ? cnt[base + 1] : 0;
  int c2 = (base + 2 < NN) ? cnt[base + 2] : 0;
  int c3 = (base + 3 < NN) ? cnt[base + 3] : 0;
  int tsum = c0 + c1 + c2 + c3;
  s[t] = tsum;
  __syncthreads();
  for (int o = 1; o < 256; o <<= 1) {
    int v = (t >= o) ? s[t - o] : 0;
    __syncthreads();
    s[t] += v;
    __syncthreads();
  }
  int excl = s[t] - tsum;
  if (base + 0 < NN) off[base + 0] = excl;
  if (base + 1 < NN) off[base + 1] = excl + c0;
  if (base + 2 < NN) off[base + 2] = excl + c0 + c1;
  if (base + 3 < NN) off[base + 3] = excl + c0 + c1 + c2;
  if (t == 255) bsum[blockIdx.x] = s[255];
}

__global__ __launch_bounds__(256) void k_scan2(const int* __restrict__ bsum,
    int* __restrict__ bbase) {
  __shared__ int s[256];
  int t = threadIdx.x;
  int v0 = (t < SCAN_BLKS) ? bsum[t] : 0;
  s[t] = v0;
  __syncthreads();
  for (int o = 1; o < 256; o <<= 1) {
    int v = (t >= o) ? s[t - o] : 0;
    __syncthreads();
    s[t] += v;
    __syncthreads();
  }
  if (t < SCAN_BLKS) bbase[t] = s[t] - v0;
}

__global__ __launch_bounds__(256) void k_scan3(int* __restrict__ off,
    const int* __restrict__ bbase, int* __restrict__ nxt) {
  int i = blockIdx.x * 256 + threadIdx.x;
  if (i < NN) {
    int v = off[i] + bbase[i >> 10];
    off[i] = v;
    nxt[i] = v;
  }
  if (i == 0) off[NN] = NE;
}

// ---------- fill CSR records: {row, packed_ea, norm_bits, 0} ----------
__global__ __launch_bounds__(256) void k_fill(const int* __restrict__ ei,
    const int* __restrict__ ea, const float* __restrict__ dis,
    int* __restrict__ nxt, int4* __restrict__ recs) {
  int e = blockIdx.x * 256 + threadIdx.x;
  if (e >= NE) return;
  int r = ei[e], c = ei[NE + e];
  int pa = ea[e * 3 + 0] + ea[e * 3 + 1] * 10 + ea[e * 3 + 2] * 100;
  float nr = dis[r] * dis[c];
  int pos = atomicAdd(&nxt[c], 1);
  recs[pos] = make_int4(r, pa, __float_as_int(nr), 0);
}

// ---------- combined bond table (fp32): btc[pa][d] ----------
__global__ __launch_bounds__(256) void k_btc(const float* __restrict__ bt,
    float* __restrict__ btc) {
  int idx = blockIdx.x * 256 + threadIdx.x;       // 1000*128 exact
  int p = idx >> 7, d = idx & 127;
  int a = p % 10, b = (p / 10) % 10, c = p / 100;
  btc[idx] = bt[(0 * BV + a) * DD + d] + bt[(1 * BV + b) * DD + d]
           + bt[(2 * BV + c) * DD + d];
}

// ---------- W -> bf16 ----------
__global__ __launch_bounds__(256) void k_wconv(const float* __restrict__ W,
    ushort* __restrict__ Wbf) {
  int i = blockIdx.x * 256 + threadIdx.x;         // 5*128*128 exact
  Wbf[i] = f2bf(W[i]);
}

// ---------- MFMA GEMM: hl(BF16) = A' @ Wl^T + bl ----------
// mode0: A' = srcbf (bf16 h from encode, = acts slot 0).
// mode1: A' = relu(pre_fp32*scale+shift); A' (bf16) stored to actl.
// mode2: like mode1 but folds the h still in actl: store bf16(h + A').
// BN-FOLD (R13): scale/shift computed IN-KERNEL from gsum/gss/gamma/beta of
// the PREVIOUS layer (replaces the 1-block k_bnfin launch). gsum memset must
// therefore run AFTER this kernel in the stream.
__global__ __launch_bounds__(256) void k_gemm(const ushort* __restrict__ srcbf,
    const float* __restrict__ srcp, const ushort* __restrict__ Wbf,
    const float* __restrict__ bl, const float* __restrict__ gsum,
    const float* __restrict__ gss, const float* __restrict__ gmm,
    const float* __restrict__ bbn, ushort* __restrict__ actl,
    ushort* __restrict__ hl, int mode) {
  __shared__ float s_sc[DD], s_sh[DD];
  int t = threadIdx.x;
  int lane = t & 63, wave = t >> 6;
  int col = lane & 15, quad = lane >> 4;
  int nb = blockIdx.x * 128 + wave * 32;
  int r0 = nb + col, r1 = nb + 16 + col;
  bool v0 = r0 < NN, v1 = r1 < NN;
  long a0off = (long)(v0 ? r0 : NN - 1) * DD;
  long a1off = (long)(v1 ? r1 : NN - 1) * DD;

  s8v af0[4], af1[4];                             // A fragments, 4 k-slices

  if (mode == 0) {
#pragma unroll
    for (int ks = 0; ks < 4; ++ks) {              // 8 loads, one burst
      int k0 = ks * 32 + quad * 8;
      af0[ks] = *(const s8v*)&srcbf[a0off + k0];
      af1[ks] = *(const s8v*)&srcbf[a1off + k0];
    }
  } else {
    if (t < DD) {                                 // BN fold: stats -> scale/shift
      float m = gsum[t] * (1.0f / NN);
      float v = gss[t] * (1.0f / NN) - m * m;
      float sc = gmm[t] * rsqrtf(v + EPSV);
      s_sc[t] = sc;
      s_sh[t] = bbn[t] - m * sc;
    }
    __syncthreads();
    float4 pA[4][2], pB[4][2];                    // 64 VGPR of fp32 pre
#pragma unroll
    for (int ks = 0; ks < 4; ++ks) {              // 16 loads, one burst
      int k0 = ks * 32 + quad * 8;
      pA[ks][0] = *(const float4*)&srcp[a0off + k0];
      pA[ks][1] = *(const float4*)&srcp[a0off + k0 + 4];
      pB[ks][0] = *(const float4*)&srcp[a1off + k0];
      pB[ks][1] = *(const float4*)&srcp[a1off + k0 + 4];
    }
#pragma unroll
    for (int ks = 0; ks < 4; ++ks) {              // activation + pack (VALU)
      int k0 = ks * 32 + quad * 8;
      float scv[8], shv[8];
#pragma unroll
      for (int j = 0; j < 8; ++j) { scv[j] = s_sc[k0 + j]; shv[j] = s_sh[k0 + j]; }
      float pv0[8] = {pA[ks][0].x, pA[ks][0].y, pA[ks][0].z, pA[ks][0].w,
                      pA[ks][1].x, pA[ks][1].y, pA[ks][1].z, pA[ks][1].w};
      float pv1[8] = {pB[ks][0].x, pB[ks][0].y, pB[ks][0].z, pB[ks][0].w,
                      pB[ks][1].x, pB[ks][1].y, pB[ks][1].z, pB[ks][1].w};
#pragma unroll
      for (int j = 0; j < 8; ++j) {
        float w = fmaxf(pv0[j] * scv[j] + shv[j], 0.f);
        af0[ks][j] = (short)f2bf(w);
        float u = fmaxf(pv1[j] * scv[j] + shv[j], 0.f);
        af1[ks][j] = (short)f2bf(u);
      }
    }
    // store A' (bf16); mode2 folds the h currently in actl
    if (v0) {
#pragma unroll
      for (int ks = 0; ks < 4; ++ks) {
        int k0 = ks * 32 + quad * 8;
        s8v st = af0[ks];
        if (mode == 2) {
          s8v h8 = *(const s8v*)&actl[a0off + k0];
#pragma unroll
          for (int j = 0; j < 8; ++j)
            st[j] = (short)f2bf(bf2f((ushort)h8[j]) + bf2f((ushort)af0[ks][j]));
        }
        *(s8v*)&actl[a0off + k0] = st;
      }
    }
    if (v1) {
#pragma unroll
      for (int ks = 0; ks < 4; ++ks) {
        int k0 = ks * 32 + quad * 8;
        s8v st = af1[ks];
        if (mode == 2) {
          s8v h8 = *(const s8v*)&actl[a1off + k0];
#pragma unroll
          for (int j = 0; j < 8; ++j)
            st[j] = (short)f2bf(bf2f((ushort)h8[j]) + bf2f((ushort)af1[ks][j]));
        }
        *(s8v*)&actl[a1off + k0] = st;
      }
    }
  }

  f4v acc[2][8];
#pragma unroll
  for (int i = 0; i < 2; ++i)
#pragma unroll
    for (int j = 0; j < 8; ++j) acc[i][j] = (f4v)0.f;

#pragma unroll
  for (int ks = 0; ks < 4; ++ks) {                // MFMA loop: W loads (L2) + 64 MFMA
    int k0 = ks * 32 + quad * 8;
#pragma unroll
    for (int j = 0; j < 8; ++j) {                 // B[k][n=col] for out-tile j = W[j*16+col][k]
      s8v bf = *(const s8v*)&Wbf[(j * 16 + col) * DD + k0];
      acc[0][j] = __builtin_amdgcn_mfma_f32_16x16x32_bf16(af0[ks], bf, acc[0][j], 0, 0, 0);
      acc[1][j] = __builtin_amdgcn_mfma_f32_16x16x32_bf16(af1[ks], bf, acc[1][j], 0, 0, 0);
    }
  }

  float bb[8];
#pragma unroll
  for (int j = 0; j < 8; ++j) bb[j] = bl[j * 16 + col];
#pragma unroll
  for (int i = 0; i < 2; ++i) {
    int rowb = nb + i * 16 + quad * 4;            // D: col=lane&15, row=quad*4+reg
#pragma unroll
    for (int r = 0; r < 4; ++r) {
      int n = rowb + r;
      if (n < NN) {
#pragma unroll
        for (int j = 0; j < 8; ++j)
          hl[(long)n * DD + j * 16 + col] = f2bf(acc[i][j][r] + bb[j]);
      }
    }
  }
}

// ---------- gather-aggregate + self term + BN partials ----------
// QUARTER-wave (16 lanes) owns a CONTIGUOUS run of 8 nodes; lane covers
// d = (lane&15)*8 .. +7. hl bf16; pre written FP32 for l<4 (recurrence
// accuracy) but BF16 for the LAST layer (bf16out=1): pre4 never re-enters the
// recurrence -- only k_apply_final reads it once, so quantization is safe.
// BN partials accumulate from fp32 values before quantization.
__global__ __launch_bounds__(256) void k_aggregate(const ushort* __restrict__ hl,
    const int* __restrict__ off, const int4* __restrict__ recs,
    const float* __restrict__ btc, const float* __restrict__ rootl,
    const float* __restrict__ invd, float* __restrict__ pre,
    float* __restrict__ gsum, float* __restrict__ gss, int bf16out) {
  __shared__ float redS[256][9], redQ[256][9];     // +1 pad: conflict-free
  int t = threadIdx.x;
  int ql = t & 15;                                 // lane within quarter-wave
  int qs = t >> 4;                                 // quarter-slot 0..15
  int d0 = ql * 8;
  int base = blockIdx.x * 128 + qs * 8;
  float4 rt0 = *(const float4*)&rootl[d0];
  float4 rt1 = *(const float4*)&rootl[d0 + 4];
  float4 s0 = make_float4(0.f, 0.f, 0.f, 0.f), s1 = s0;
  float4 q0 = s0, q1 = s0;
  if (base < NN) {
    int eptr = off[base];
    int enext = off[base + 1];
    int4 r0 = recs[(eptr < NE) ? eptr : (NE - 1)];           // rolling prefetch regs
    int4 r1 = recs[(eptr + 1 < NE) ? eptr + 1 : (NE - 1)];
#pragma unroll 1
    for (int j = 0; j < 8; ++j) {
      int n = base + j;
      int ia = base + j + 2; if (ia > NN) ia = NN;
      int e_after = off[ia];                       // issued early, used next iter
      int eend = enext;
      s8v sv = *(const s8v*)&hl[(long)n * DD + d0];          // self-term (bf16)
      float iv = invd[n];
      float4 aca = make_float4(0.f, 0.f, 0.f, 0.f), acb = aca;
      while (eptr + 2 <= eend) {                   // 2 edges per trip
        int4 ra = r0, rb = r1;
        int p0 = eptr + 2; if (p0 >= NE) p0 = NE - 1;
        int p1 = eptr + 3; if (p1 >= NE) p1 = NE - 1;
        r0 = recs[p0];                             // prefetch next pair
        r1 = recs[p1];
        s8v ha = *(const s8v*)&hl[(long)ra.x * DD + d0];     // 16B bf16 gather
        float4 ea0 = *(const float4*)&btc[ra.y * DD + d0];
        float4 ea1 = *(const float4*)&btc[ra.y * DD + d0 + 4];
        s8v hb = *(const s8v*)&hl[(long)rb.x * DD + d0];
        float4 eb0 = *(const float4*)&btc[rb.y * DD + d0];
        float4 eb1 = *(const float4*)&btc[rb.y * DD + d0 + 4];
        float na = __int_as_float(ra.z);
        float nb = __int_as_float(rb.z);
        aca.x += fmaxf(bf2f((ushort)ha[0]) + ea0.x, 0.f) * na + fmaxf(bf2f((ushort)hb[0]) + eb0.x, 0.f) * nb;
        aca.y += fmaxf(bf2f((ushort)ha[1]) + ea0.y, 0.f) * na + fmaxf(bf2f((ushort)hb[1]) + eb0.y, 0.f) * nb;
        aca.z += fmaxf(bf2f((ushort)ha[2]) + ea0.z, 0.f) * na + fmaxf(bf2f((ushort)hb[2]) + eb0.z, 0.f) * nb;
        aca.w += fmaxf(bf2f((ushort)ha[3]) + ea0.w, 0.f) * na + fmaxf(bf2f((ushort)hb[3]) + eb0.w, 0.f) * nb;
        acb.x += fmaxf(bf2f((ushort)ha[4]) + ea1.x, 0.f) * na + fmaxf(bf2f((ushort)hb[4]) + eb1.x, 0.f) * nb;
        acb.y += fmaxf(bf2f((ushort)ha[5]) + ea1.y, 0.f) * na + fmaxf(bf2f((ushort)hb[5]) + eb1.y, 0.f) * nb;
        acb.z += fmaxf(bf2f((ushort)ha[6]) + ea1.z, 0.f) * na + fmaxf(bf2f((ushort)hb[6]) + eb1.z, 0.f) * nb;
        acb.w += fmaxf(bf2f((ushort)ha[7]) + ea1.w, 0.f) * na + fmaxf(bf2f((ushort)hb[7]) + eb1.w, 0.f) * nb;
        eptr += 2;
      }
      if (eptr < eend) {                           // odd leftover edge
        int4 ra = r0;
        int4 tmp = r1;
        int p0 = eptr + 2; if (p0 >= NE) p0 = NE - 1;
        r1 = recs[p0];                             // maintain rolling invariant
        r0 = tmp;
        s8v hv = *(const s8v*)&hl[(long)ra.x * DD + d0];
        float4 ev0 = *(const float4*)&btc[ra.y * DD + d0];
        float4 ev1 = *(const float4*)&btc[ra.y * DD + d0 + 4];
        float nr = __int_as_float(ra.z);
        aca.x += fmaxf(bf2f((ushort)hv[0]) + ev0.x, 0.f) * nr;
        aca.y += fmaxf(bf2f((ushort)hv[1]) + ev0.y, 0.f) * nr;
        aca.z += fmaxf(bf2f((ushort)hv[2]) + ev0.z, 0.f) * nr;
        aca.w += fmaxf(bf2f((ushort)hv[3]) + ev0.w, 0.f) * nr;
        acb.x += fmaxf(bf2f((ushort)hv[4]) + ev1.x, 0.f) * nr;
        acb.y += fmaxf(bf2f((ushort)hv[5]) + ev1.y, 0.f) * nr;
        acb.z += fmaxf(bf2f((ushort)hv[6]) + ev1.z, 0.f) * nr;
        acb.w += fmaxf(bf2f((ushort)hv[7]) + ev1.w, 0.f) * nr;
        eptr += 1;
      }
      float4 pa, pb;
      pa.x = aca.x + fmaxf(bf2f((ushort)sv[0]) + rt0.x, 0.f) * iv;
      pa.y = aca.y + fmaxf(bf2f((ushort)sv[1]) + rt0.y, 0.f) * iv;
      pa.z = aca.z + fmaxf(bf2f((ushort)sv[2]) + rt0.z, 0.f) * iv;
      pa.w = aca.w + fmaxf(bf2f((ushort)sv[3]) + rt0.w, 0.f) * iv;
      pb.x = acb.x + fmaxf(bf2f((ushort)sv[4]) + rt1.x, 0.f) * iv;
      pb.y = acb.y + fmaxf(bf2f((ushort)sv[5]) + rt1.y, 0.f) * iv;
      pb.z = acb.z + fmaxf(bf2f((ushort)sv[6]) + rt1.z, 0.f) * iv;
      pb.w = acb.w + fmaxf(bf2f((ushort)sv[7]) + rt1.w, 0.f) * iv;
      if (bf16out) {                               // last layer: pre as bf16
        s8v pq;
        pq[0] = (short)f2bf(pa.x); pq[1] = (short)f2bf(pa.y);
        pq[2] = (short)f2bf(pa.z); pq[3] = (short)f2bf(pa.w);
        pq[4] = (short)f2bf(pb.x); pq[5] = (short)f2bf(pb.y);
        pq[6] = (short)f2bf(pb.z); pq[7] = (short)f2bf(pb.w);
        *(s8v*)&((ushort*)pre)[(long)n * DD + d0] = pq;
      } else {
        *(float4*)&pre[(long)n * DD + d0] = pa;
        *(float4*)&pre[(long)n * DD + d0 + 4] = pb;
      }
      s0.x += pa.x; s0.y += pa.y; s0.z += pa.z; s0.w += pa.w;
      s1.x += pb.x; s1.y += pb.y; s1.z += pb.z; s1.w += pb.w;
      q0.x += pa.x * pa.x; q0.y += pa.y * pa.y; q0.z += pa.z * pa.z; q0.w += pa.w * pa.w;
      q1.x += pb.x * pb.x; q1.y += pb.y * pb.y; q1.z += pb.z * pb.z; q1.w += pb.w * pb.w;
      enext = e_after;
    }
  }
  redS[t][0] = s0.x; redS[t][1] = s0.y; redS[t][2] = s0.z; redS[t][3] = s0.w;
  redS[t][4] = s1.x; redS[t][5] = s1.y; redS[t][6] = s1.z; redS[t][7] = s1.w;
  redQ[t][0] = q0.x; redQ[t][1] = q0.y; redQ[t][2] = q0.z; redQ[t][3] = q0.w;
  redQ[t][4] = q1.x; redQ[t][5] = q1.y; redQ[t][6] = q1.z; redQ[t][7] = q1.w;
  __syncthreads();
  if (t < 128) {                                   // d = t; lane qq=d>>3 covers d&7
    int qq = t >> 3, c = t & 7;
    float S = 0.f, Q = 0.f;
#pragma unroll
    for (int h = 0; h < 16; ++h) {
      S += redS[h * 16 + qq][c];
      Q += redQ[h * 16 + qq][c];
    }
    atomicAdd(&gsum[t], S);
    atomicAdd(&gss[t], Q);
  }
}

// ---------- final: out = (h+act0) + act1 + act2 + act3 + (pre4*scale4 + shift4)
// Pure write of out; scale4/shift4 computed in-kernel from layer-4 stats
// (k_bnfin removed); pre4 read as bf16. ----------
__global__ __launch_bounds__(256) void k_apply_final(const ushort* __restrict__ preb,
    const ushort* __restrict__ acts, const float* __restrict__ gsum,
    const float* __restrict__ gss, const float* __restrict__ gmm,
    const float* __restrict__ bbn, float* __restrict__ out) {
  __shared__ float s_sc[DD], s_sh[DD];
  const int NDH = NN * DD / 2;                    // uint elements per slot
  int t = threadIdx.x;
  if (t < DD) {
    float m = gsum[t] * (1.0f / NN);
    float v = gss[t] * (1.0f / NN) - m * m;
    float sc = gmm[t] * rsqrtf(v + EPSV);
    s_sc[t] = sc;
    s_sh[t] = bbn[t] - m * sc;
  }
  __syncthreads();
  int idx = blockIdx.x * 256 + t;                 // N*D/2 exact
  int dp = idx & 63;
  uint a0 = ((const uint*)acts)[idx];
  uint a1 = ((const uint*)acts)[idx + NDH];
  uint a2 = ((const uint*)acts)[idx + 2 * NDH];
  uint a3 = ((const uint*)acts)[idx + 3 * NDH];
  uint pv = ((const uint*)preb)[idx];
  float2 o;
  o.x = bf2f((ushort)a0) + bf2f((ushort)a1) + bf2f((ushort)a2) + bf2f((ushort)a3)
      + bf2f((ushort)pv) * s_sc[dp * 2] + s_sh[dp * 2];
  o.y = bf2f((ushort)(a0 >> 16)) + bf2f((ushort)(a1 >> 16)) + bf2f((ushort)(a2 >> 16))
      + bf2f((ushort)(a3 >> 16))
      + bf2f((ushort)(pv >> 16)) * s_sc[dp * 2 + 1] + s_sh[dp * 2 + 1];
  *(float2*)&out[idx * 2] = o;
}

extern "C" void kernel_launch(void* const* d_in, const int* in_sizes, int n_in,
                              void* d_out, int out_size, void* d_ws, size_t ws_size,
                              hipStream_t stream) {
  const int*   x     = (const int*)d_in[0];
  const int*   ei    = (const int*)d_in[1];
  const int*   ea    = (const int*)d_in[2];
  const float* at    = (const float*)d_in[3];
  const float* bt    = (const float*)d_in[4];
  const float* W     = (const float*)d_in[5];
  const float* b     = (const float*)d_in[6];
  const float* root  = (const float*)d_in[7];
  const float* gamma = (const float*)d_in[8];
  const float* beta  = (const float*)d_in[9];
  float* out = (float*)d_out;

  char* ws = (char*)d_ws;
  size_t ND = (size_t)NN * DD;
  ushort* hl   = (ushort*)ws;                       // ND bf16
  float*  pre  = (float*)(hl + ND);                 // ND fp32 (bf16 for layer 4)
  ushort* acts = (ushort*)(pre + ND);               // 4*ND bf16; slot0: h then h+act0
  int4*   recs = (int4*)(acts + 4 * ND);            // NE * 16B (byte off 14*ND, 16B-aligned)
  ushort* Wbf  = (ushort*)(recs + NE);              // 5*128*128 bf16
  float*  btc  = (float*)(Wbf + NL * DD * DD);      // 1000*128 fp32
  float*  deg  = btc + 1000 * DD;                   // N
  float*  dis  = deg + NN;                          // N
  float*  invd = dis + NN;                          // N
  int*    cnt  = (int*)(invd + NN);                 // N
  int*    offa = cnt + NN;                          // N+1 (+3 pad)
  int*    nxt  = offa + NN + 4;                     // N
  int*    bsum = nxt + NN;                          // 256
  int*    bbase= bsum + 256;                        // 256
  float*  gsum = (float*)(bbase + 256);             // D
  float*  gss  = gsum + DD;                         // D

  // ---- precompute ----
  k_deg_init<<<(NN + 255) / 256, 256, 0, stream>>>(deg, cnt);
  k_deg_count<<<(NE + 255) / 256, 256, 0, stream>>>(ei, deg, cnt);
  k_deg_fin<<<(NN + 255) / 256, 256, 0, stream>>>(deg, dis, invd);
  k_scan1<<<SCAN_BLKS, 256, 0, stream>>>(cnt, offa, bsum);
  k_scan2<<<1, 256, 0, stream>>>(bsum, bbase);
  k_scan3<<<(NN + 255) / 256, 256, 0, stream>>>(offa, bbase, nxt);
  k_fill<<<(NE + 255) / 256, 256, 0, stream>>>(ei, ea, dis, nxt, recs);
  k_btc<<<1000 * DD / 256, 256, 0, stream>>>(bt, btc);
  k_wconv<<<NL * DD * DD / 256, 256, 0, stream>>>(W, Wbf);
  k_encode<<<(int)(ND / 2 / 256), 256, 0, stream>>>(x, at, acts);

  // ---- layers ----
  for (int l = 0; l < NL; ++l) {
    // gemm_l consumes layer-(l-1) stats still in gsum/gss (BN folded in-kernel);
    // memset AFTER gemm, before agg_l refills the stats.
    int mode = (l == 0) ? 0 : ((l == 1) ? 2 : 1);
    k_gemm<<<(NN + 127) / 128, 256, 0, stream>>>(
        acts, pre, Wbf + (size_t)l * DD * DD, b + l * DD,
        gsum, gss, gamma + (size_t)(l == 0 ? 0 : l - 1) * DD,
        beta + (size_t)(l == 0 ? 0 : l - 1) * DD,
        acts + (size_t)(l == 0 ? 0 : l - 1) * ND,
        hl, mode);
    hipMemsetAsync(gsum, 0, 2 * DD * sizeof(float), stream);
    k_aggregate<<<(NN + 127) / 128, 256, 0, stream>>>(hl, offa, recs, btc,
        root + l * DD, invd, pre, gsum, gss, (l == NL - 1) ? 1 : 0);
  }
  k_apply_final<<<(int)(ND / 2 / 256), 256, 0, stream>>>((ushort*)pre, acts,
      gsum, gss, gamma + 4 * DD, beta + 4 * DD, out);
}

// Round 14
// 978.505 us; speedup vs baseline: 1.7263x; 1.0467x over previous
//
#include <hip/hip_runtime.h>
#include <hip/hip_fp16.h>

#define NN 200000
#define NE 400000
#define DD 128
#define NL 5
#define AV 100
#define BV 10
#define EPSV 1e-5f
#define SCAN_BLKS 196   // ceil(NN/1024)

typedef short s8v __attribute__((ext_vector_type(8)));   // 8 bf16/fp16 (4 VGPRs)
typedef float f4v __attribute__((ext_vector_type(4)));   // 4 fp32 acc

__device__ __forceinline__ ushort f2bf(float f) {        // RNE float->bf16
  uint u = __float_as_uint(f);
  u += 0x7FFFu + ((u >> 16) & 1u);
  return (ushort)(u >> 16);
}

__device__ __forceinline__ float bf2f(ushort u) {        // bf16->float
  return __uint_as_float(((uint)u) << 16);
}

__device__ __forceinline__ ushort f2h(float f) {         // RNE float->fp16
  return __half_as_ushort(__float2half(f));
}

__device__ __forceinline__ float h2f(ushort u) {         // fp16->float
  return __half2float(__ushort_as_half(u));
}

// ---------- encode: h = sum of atom embeddings -> acts slot 0 (bf16 only) ----------
__global__ __launch_bounds__(256) void k_encode(const int* __restrict__ x,
    const float* __restrict__ at, ushort* __restrict__ hbuf) {
  int idx = blockIdx.x * 256 + threadIdx.x;       // N*D/2 threads exact
  int n = idx >> 6, dp = idx & 63;                // wave = one node -> x row broadcast
  const int* xr = x + n * 9;
  float s0 = 0.f, s1 = 0.f;
#pragma unroll
  for (int c = 0; c < 9; ++c) {
    float2 v = *(const float2*)&at[(c * AV + xr[c]) * DD + dp * 2];
    s0 += v.x; s1 += v.y;
  }
  ((uint*)hbuf)[idx] = (uint)f2bf(s0) | ((uint)f2bf(s1) << 16);
}

// ---------- degree ----------
__global__ __launch_bounds__(256) void k_deg_init(float* __restrict__ deg,
                                                  int* __restrict__ cnt) {
  int i = blockIdx.x * 256 + threadIdx.x;
  if (i < NN) { deg[i] = 1.0f; cnt[i] = 0; }
}

__global__ __launch_bounds__(256) void k_deg_count(const int* __restrict__ ei,
    float* __restrict__ deg, int* __restrict__ cnt) {
  int e = blockIdx.x * 256 + threadIdx.x;
  if (e < NE) {
    atomicAdd(&deg[ei[e]], 1.0f);
    atomicAdd(&cnt[ei[NE + e]], 1);
  }
}

__global__ __launch_bounds__(256) void k_deg_fin(const float* __restrict__ deg,
    float* __restrict__ dis, float* __restrict__ invd) {
  int i = blockIdx.x * 256 + threadIdx.x;
  if (i < NN) {
    float dg = deg[i];
    dis[i] = rsqrtf(dg);
    invd[i] = 1.0f / dg;
  }
}

// ---------- exclusive scan of cnt -> off ----------
__global__ __launch_bounds__(256) void k_scan1(const int* __restrict__ cnt,
    int* __restrict__ off, int* __restrict__ bsum) {
  __shared__ int s[256];
  int t = threadIdx.x;
  int base = blockIdx.x * 1024 + t * 4;
  int c0 = (base + 0 < NN) ? cnt[base + 0] : 0;
  int c1 = (base + 1 < NN) ? cnt[base + 1] : 0;
  int c2 = (base + 2 < NN) ? cnt[base + 2] : 0;
  int c3 = (base + 3 < NN) ? cnt[base + 3] : 0;
  int tsum = c0 + c1 + c2 + c3;
  s[t] = tsum;
  __syncthreads();
  for (int o = 1; o < 256; o <<= 1) {
    int v = (t >= o) ? s[t - o] : 0;
    __syncthreads();
    s[t] += v;
    __syncthreads();
  }
  int excl = s[t] - tsum;
  if (base + 0 < NN) off[base + 0] = excl;
  if (base + 1 < NN) off[base + 1] = excl + c0;
  if (base + 2 < NN) off[base + 2] = excl + c0 + c1;
  if (base + 3 < NN) off[base + 3] = excl + c0 + c1 + c2;
  if (t == 255) bsum[blockIdx.x] = s[255];
}

__global__ __launch_bounds__(256) void k_scan2(const int* __restrict__ bsum,
    int* __restrict__ bbase) {
  __shared__ int s[256];
  int t = threadIdx.x;
  int v0 = (t < SCAN_BLKS) ? bsum[t] : 0;
  s[t] = v0;
  __syncthreads();
  for (int o = 1; o < 256; o <<= 1) {
    int v = (t >= o) ? s[t - o] : 0;
    __syncthreads();
    s[t] += v;
    __syncthreads();
  }
  if (t < SCAN_BLKS) bbase[t] = s[t] - v0;
}

__global__ __launch_bounds__(256) void k_scan3(int* __restrict__ off,
    const int* __restrict__ bbase, int* __restrict__ nxt) {
  int i = blockIdx.x * 256 + threadIdx.x;
  if (i < NN) {
    int v = off[i] + bbase[i >> 10];
    off[i] = v;
    nxt[i] = v;
  }
  if (i == 0) off[NN] = NE;
}

// ---------- fill CSR records: {row, packed_ea, norm_bits, 0} ----------
__global__ __launch_bounds__(256) void k_fill(const int* __restrict__ ei,
    const int* __restrict__ ea, const float* __restrict__ dis,
    int* __restrict__ nxt, int4* __restrict__ recs) {
  int e = blockIdx.x * 256 + threadIdx.x;
  if (e >= NE) return;
  int r = ei[e], c = ei[NE + e];
  int pa = ea[e * 3 + 0] + ea[e * 3 + 1] * 10 + ea[e * 3 + 2] * 100;
  float nr = dis[r] * dis[c];
  int pos = atomicAdd(&nxt[c], 1);
  recs[pos] = make_int4(r, pa, __float_as_int(nr), 0);
}

// ---------- combined bond table (fp32): btc[pa][d] ----------
__global__ __launch_bounds__(256) void k_btc(const float* __restrict__ bt,
    float* __restrict__ btc) {
  int idx = blockIdx.x * 256 + threadIdx.x;       // 1000*128 exact
  int p = idx >> 7, d = idx & 127;
  int a = p % 10, b = (p / 10) % 10, c = p / 100;
  btc[idx] = bt[(0 * BV + a) * DD + d] + bt[(1 * BV + b) * DD + d]
           + bt[(2 * BV + c) * DD + d];
}

// ---------- W -> bf16 ----------
__global__ __launch_bounds__(256) void k_wconv(const float* __restrict__ W,
    ushort* __restrict__ Wbf) {
  int i = blockIdx.x * 256 + threadIdx.x;         // 5*128*128 exact
  Wbf[i] = f2bf(W[i]);
}

// ---------- MFMA GEMM: hl(BF16) = A' @ Wl^T + bl ----------
// mode0: A' = srcbf (bf16 h from encode, = acts slot 0).
// mode1: A' = relu(pre_fp16*scale+shift); A' (bf16) stored to actl.
// mode2: like mode1 but folds the h still in actl: store bf16(h + A').
// pre is FP16 (R14): 8x tighter than bf16 (R9's failure mode); halves the
// pre stream. BN fold in-kernel from previous layer's stats (R13).
__global__ __launch_bounds__(256) void k_gemm(const ushort* __restrict__ srcbf,
    const ushort* __restrict__ srcp, const ushort* __restrict__ Wbf,
    const float* __restrict__ bl, const float* __restrict__ gsum,
    const float* __restrict__ gss, const float* __restrict__ gmm,
    const float* __restrict__ bbn, ushort* __restrict__ actl,
    ushort* __restrict__ hl, int mode) {
  __shared__ float s_sc[DD], s_sh[DD];
  int t = threadIdx.x;
  int lane = t & 63, wave = t >> 6;
  int col = lane & 15, quad = lane >> 4;
  int nb = blockIdx.x * 128 + wave * 32;
  int r0 = nb + col, r1 = nb + 16 + col;
  bool v0 = r0 < NN, v1 = r1 < NN;
  long a0off = (long)(v0 ? r0 : NN - 1) * DD;
  long a1off = (long)(v1 ? r1 : NN - 1) * DD;

  s8v af0[4], af1[4];                             // A fragments, 4 k-slices

  if (mode == 0) {
#pragma unroll
    for (int ks = 0; ks < 4; ++ks) {              // 8 loads, one burst
      int k0 = ks * 32 + quad * 8;
      af0[ks] = *(const s8v*)&srcbf[a0off + k0];
      af1[ks] = *(const s8v*)&srcbf[a1off + k0];
    }
  } else {
    if (t < DD) {                                 // BN fold: stats -> scale/shift
      float m = gsum[t] * (1.0f / NN);
      float v = gss[t] * (1.0f / NN) - m * m;
      float sc = gmm[t] * rsqrtf(v + EPSV);
      s_sc[t] = sc;
      s_sh[t] = bbn[t] - m * sc;
    }
    __syncthreads();
    s8v pF0[4], pF1[4];                           // fp16 pre, one burst (8 loads)
#pragma unroll
    for (int ks = 0; ks < 4; ++ks) {
      int k0 = ks * 32 + quad * 8;
      pF0[ks] = *(const s8v*)&srcp[a0off + k0];
      pF1[ks] = *(const s8v*)&srcp[a1off + k0];
    }
#pragma unroll
    for (int ks = 0; ks < 4; ++ks) {              // activation + pack (VALU)
      int k0 = ks * 32 + quad * 8;
      float scv[8], shv[8];
#pragma unroll
      for (int j = 0; j < 8; ++j) { scv[j] = s_sc[k0 + j]; shv[j] = s_sh[k0 + j]; }
#pragma unroll
      for (int j = 0; j < 8; ++j) {
        float w = fmaxf(h2f((ushort)pF0[ks][j]) * scv[j] + shv[j], 0.f);
        af0[ks][j] = (short)f2bf(w);
        float u = fmaxf(h2f((ushort)pF1[ks][j]) * scv[j] + shv[j], 0.f);
        af1[ks][j] = (short)f2bf(u);
      }
    }
    // store A' (bf16); mode2 folds the h currently in actl
    if (v0) {
#pragma unroll
      for (int ks = 0; ks < 4; ++ks) {
        int k0 = ks * 32 + quad * 8;
        s8v st = af0[ks];
        if (mode == 2) {
          s8v h8 = *(const s8v*)&actl[a0off + k0];
#pragma unroll
          for (int j = 0; j < 8; ++j)
            st[j] = (short)f2bf(bf2f((ushort)h8[j]) + bf2f((ushort)af0[ks][j]));
        }
        *(s8v*)&actl[a0off + k0] = st;
      }
    }
    if (v1) {
#pragma unroll
      for (int ks = 0; ks < 4; ++ks) {
        int k0 = ks * 32 + quad * 8;
        s8v st = af1[ks];
        if (mode == 2) {
          s8v h8 = *(const s8v*)&actl[a1off + k0];
#pragma unroll
          for (int j = 0; j < 8; ++j)
            st[j] = (short)f2bf(bf2f((ushort)h8[j]) + bf2f((ushort)af1[ks][j]));
        }
        *(s8v*)&actl[a1off + k0] = st;
      }
    }
  }

  f4v acc[2][8];
#pragma unroll
  for (int i = 0; i < 2; ++i)
#pragma unroll
    for (int j = 0; j < 8; ++j) acc[i][j] = (f4v)0.f;

#pragma unroll
  for (int ks = 0; ks < 4; ++ks) {                // MFMA loop: W loads (L2) + 64 MFMA
    int k0 = ks * 32 + quad * 8;
#pragma unroll
    for (int j = 0; j < 8; ++j) {                 // B[k][n=col] for out-tile j = W[j*16+col][k]
      s8v bf = *(const s8v*)&Wbf[(j * 16 + col) * DD + k0];
      acc[0][j] = __builtin_amdgcn_mfma_f32_16x16x32_bf16(af0[ks], bf, acc[0][j], 0, 0, 0);
      acc[1][j] = __builtin_amdgcn_mfma_f32_16x16x32_bf16(af1[ks], bf, acc[1][j], 0, 0, 0);
    }
  }

  float bb[8];
#pragma unroll
  for (int j = 0; j < 8; ++j) bb[j] = bl[j * 16 + col];
#pragma unroll
  for (int i = 0; i < 2; ++i) {
    int rowb = nb + i * 16 + quad * 4;            // D: col=lane&15, row=quad*4+reg
#pragma unroll
    for (int r = 0; r < 4; ++r) {
      int n = rowb + r;
      if (n < NN) {
#pragma unroll
        for (int j = 0; j < 8; ++j)
          hl[(long)n * DD + j * 16 + col] = f2bf(acc[i][j][r] + bb[j]);
      }
    }
  }
}

// ---------- gather-aggregate + self term + BN partials ----------
// QUARTER-wave (16 lanes) owns a CONTIGUOUS run of 8 nodes; lane covers
// d = (lane&15)*8 .. +7. hl bf16; pre written FP16 (halves the write stream;
// fp16's 2^-11 mantissa keeps the recurrence error ~8x below R9's failed bf16).
// BN partials accumulate from fp32 values before quantization.
__global__ __launch_bounds__(256) void k_aggregate(const ushort* __restrict__ hl,
    const int* __restrict__ off, const int4* __restrict__ recs,
    const float* __restrict__ btc, const float* __restrict__ rootl,
    const float* __restrict__ invd, ushort* __restrict__ pre,
    float* __restrict__ gsum, float* __restrict__ gss) {
  __shared__ float redS[256][9], redQ[256][9];     // +1 pad: conflict-free
  int t = threadIdx.x;
  int ql = t & 15;                                 // lane within quarter-wave
  int qs = t >> 4;                                 // quarter-slot 0..15
  int d0 = ql * 8;
  int base = blockIdx.x * 128 + qs * 8;
  float4 rt0 = *(const float4*)&rootl[d0];
  float4 rt1 = *(const float4*)&rootl[d0 + 4];
  float4 s0 = make_float4(0.f, 0.f, 0.f, 0.f), s1 = s0;
  float4 q0 = s0, q1 = s0;
  if (base < NN) {
    int eptr = off[base];
    int enext = off[base + 1];
    int4 r0 = recs[(eptr < NE) ? eptr : (NE - 1)];           // rolling prefetch regs
    int4 r1 = recs[(eptr + 1 < NE) ? eptr + 1 : (NE - 1)];
#pragma unroll 1
    for (int j = 0; j < 8; ++j) {
      int n = base + j;
      int ia = base + j + 2; if (ia > NN) ia = NN;
      int e_after = off[ia];                       // issued early, used next iter
      int eend = enext;
      s8v sv = *(const s8v*)&hl[(long)n * DD + d0];          // self-term (bf16)
      float iv = invd[n];
      float4 aca = make_float4(0.f, 0.f, 0.f, 0.f), acb = aca;
      while (eptr + 2 <= eend) {                   // 2 edges per trip
        int4 ra = r0, rb = r1;
        int p0 = eptr + 2; if (p0 >= NE) p0 = NE - 1;
        int p1 = eptr + 3; if (p1 >= NE) p1 = NE - 1;
        r0 = recs[p0];                             // prefetch next pair
        r1 = recs[p1];
        s8v ha = *(const s8v*)&hl[(long)ra.x * DD + d0];     // 16B bf16 gather
        float4 ea0 = *(const float4*)&btc[ra.y * DD + d0];
        float4 ea1 = *(const float4*)&btc[ra.y * DD + d0 + 4];
        s8v hb = *(const s8v*)&hl[(long)rb.x * DD + d0];
        float4 eb0 = *(const float4*)&btc[rb.y * DD + d0];
        float4 eb1 = *(const float4*)&btc[rb.y * DD + d0 + 4];
        float na = __int_as_float(ra.z);
        float nb = __int_as_float(rb.z);
        aca.x += fmaxf(bf2f((ushort)ha[0]) + ea0.x, 0.f) * na + fmaxf(bf2f((ushort)hb[0]) + eb0.x, 0.f) * nb;
        aca.y += fmaxf(bf2f((ushort)ha[1]) + ea0.y, 0.f) * na + fmaxf(bf2f((ushort)hb[1]) + eb0.y, 0.f) * nb;
        aca.z += fmaxf(bf2f((ushort)ha[2]) + ea0.z, 0.f) * na + fmaxf(bf2f((ushort)hb[2]) + eb0.z, 0.f) * nb;
        aca.w += fmaxf(bf2f((ushort)ha[3]) + ea0.w, 0.f) * na + fmaxf(bf2f((ushort)hb[3]) + eb0.w, 0.f) * nb;
        acb.x += fmaxf(bf2f((ushort)ha[4]) + ea1.x, 0.f) * na + fmaxf(bf2f((ushort)hb[4]) + eb1.x, 0.f) * nb;
        acb.y += fmaxf(bf2f((ushort)ha[5]) + ea1.y, 0.f) * na + fmaxf(bf2f((ushort)hb[5]) + eb1.y, 0.f) * nb;
        acb.z += fmaxf(bf2f((ushort)ha[6]) + ea1.z, 0.f) * na + fmaxf(bf2f((ushort)hb[6]) + eb1.z, 0.f) * nb;
        acb.w += fmaxf(bf2f((ushort)ha[7]) + ea1.w, 0.f) * na + fmaxf(bf2f((ushort)hb[7]) + eb1.w, 0.f) * nb;
        eptr += 2;
      }
      if (eptr < eend) {                           // odd leftover edge
        int4 ra = r0;
        int4 tmp = r1;
        int p0 = eptr + 2; if (p0 >= NE) p0 = NE - 1;
        r1 = recs[p0];                             // maintain rolling invariant
        r0 = tmp;
        s8v hv = *(const s8v*)&hl[(long)ra.x * DD + d0];
        float4 ev0 = *(const float4*)&btc[ra.y * DD + d0];
        float4 ev1 = *(const float4*)&btc[ra.y * DD + d0 + 4];
        float nr = __int_as_float(ra.z);
        aca.x += fmaxf(bf2f((ushort)hv[0]) + ev0.x, 0.f) * nr;
        aca.y += fmaxf(bf2f((ushort)hv[1]) + ev0.y, 0.f) * nr;
        aca.z += fmaxf(bf2f((ushort)hv[2]) + ev0.z, 0.f) * nr;
        aca.w += fmaxf(bf2f((ushort)hv[3]) + ev0.w, 0.f) * nr;
        acb.x += fmaxf(bf2f((ushort)hv[4]) + ev1.x, 0.f) * nr;
        acb.y += fmaxf(bf2f((ushort)hv[5]) + ev1.y, 0.f) * nr;
        acb.z += fmaxf(bf2f((ushort)hv[6]) + ev1.z, 0.f) * nr;
        acb.w += fmaxf(bf2f((ushort)hv[7]) + ev1.w, 0.f) * nr;
        eptr += 1;
      }
      float4 pa, pb;
      pa.x = aca.x + fmaxf(bf2f((ushort)sv[0]) + rt0.x, 0.f) * iv;
      pa.y = aca.y + fmaxf(bf2f((ushort)sv[1]) + rt0.y, 0.f) * iv;
      pa.z = aca.z + fmaxf(bf2f((ushort)sv[2]) + rt0.z, 0.f) * iv;
      pa.w = aca.w + fmaxf(bf2f((ushort)sv[3]) + rt0.w, 0.f) * iv;
      pb.x = acb.x + fmaxf(bf2f((ushort)sv[4]) + rt1.x, 0.f) * iv;
      pb.y = acb.y + fmaxf(bf2f((ushort)sv[5]) + rt1.y, 0.f) * iv;
      pb.z = acb.z + fmaxf(bf2f((ushort)sv[6]) + rt1.z, 0.f) * iv;
      pb.w = acb.w + fmaxf(bf2f((ushort)sv[7]) + rt1.w, 0.f) * iv;
      s8v pq;                                      // pre stored as fp16 (16B)
      pq[0] = (short)f2h(pa.x); pq[1] = (short)f2h(pa.y);
      pq[2] = (short)f2h(pa.z); pq[3] = (short)f2h(pa.w);
      pq[4] = (short)f2h(pb.x); pq[5] = (short)f2h(pb.y);
      pq[6] = (short)f2h(pb.z); pq[7] = (short)f2h(pb.w);
      *(s8v*)&pre[(long)n * DD + d0] = pq;
      s0.x += pa.x; s0.y += pa.y; s0.z += pa.z; s0.w += pa.w;
      s1.x += pb.x; s1.y += pb.y; s1.z += pb.z; s1.w += pb.w;
      q0.x += pa.x * pa.x; q0.y += pa.y * pa.y; q0.z += pa.z * pa.z; q0.w += pa.w * pa.w;
      q1.x += pb.x * pb.x; q1.y += pb.y * pb.y; q1.z += pb.z * pb.z; q1.w += pb.w * pb.w;
      enext = e_after;
    }
  }
  redS[t][0] = s0.x; redS[t][1] = s0.y; redS[t][2] = s0.z; redS[t][3] = s0.w;
  redS[t][4] = s1.x; redS[t][5] = s1.y; redS[t][6] = s1.z; redS[t][7] = s1.w;
  redQ[t][0] = q0.x; redQ[t][1] = q0.y; redQ[t][2] = q0.z; redQ[t][3] = q0.w;
  redQ[t][4] = q1.x; redQ[t][5] = q1.y; redQ[t][6] = q1.z; redQ[t][7] = q1.w;
  __syncthreads();
  if (t < 128) {                                   // d = t; lane qq=d>>3 covers d&7
    int qq = t >> 3, c = t & 7;
    float S = 0.f, Q = 0.f;
#pragma unroll
    for (int h = 0; h < 16; ++h) {
      S += redS[h * 16 + qq][c];
      Q += redQ[h * 16 + qq][c];
    }
    atomicAdd(&gsum[t], S);
    atomicAdd(&gss[t], Q);
  }
}

// ---------- final: out = (h+act0) + act1 + act2 + act3 + (pre4*scale4 + shift4)
// Pure write of out; scale4/shift4 computed in-kernel; pre4 read as fp16. ----------
__global__ __launch_bounds__(256) void k_apply_final(const ushort* __restrict__ preh,
    const ushort* __restrict__ acts, const float* __restrict__ gsum,
    const float* __restrict__ gss, const float* __restrict__ gmm,
    const float* __restrict__ bbn, float* __restrict__ out) {
  __shared__ float s_sc[DD], s_sh[DD];
  const int NDH = NN * DD / 2;                    // uint elements per slot
  int t = threadIdx.x;
  if (t < DD) {
    float m = gsum[t] * (1.0f / NN);
    float v = gss[t] * (1.0f / NN) - m * m;
    float sc = gmm[t] * rsqrtf(v + EPSV);
    s_sc[t] = sc;
    s_sh[t] = bbn[t] - m * sc;
  }
  __syncthreads();
  int idx = blockIdx.x * 256 + t;                 // N*D/2 exact
  int dp = idx & 63;
  uint a0 = ((const uint*)acts)[idx];
  uint a1 = ((const uint*)acts)[idx + NDH];
  uint a2 = ((const uint*)acts)[idx + 2 * NDH];
  uint a3 = ((const uint*)acts)[idx + 3 * NDH];
  uint pv = ((const uint*)preh)[idx];
  float2 o;
  o.x = bf2f((ushort)a0) + bf2f((ushort)a1) + bf2f((ushort)a2) + bf2f((ushort)a3)
      + h2f((ushort)pv) * s_sc[dp * 2] + s_sh[dp * 2];
  o.y = bf2f((ushort)(a0 >> 16)) + bf2f((ushort)(a1 >> 16)) + bf2f((ushort)(a2 >> 16))
      + bf2f((ushort)(a3 >> 16))
      + h2f((ushort)(pv >> 16)) * s_sc[dp * 2 + 1] + s_sh[dp * 2 + 1];
  *(float2*)&out[idx * 2] = o;
}

extern "C" void kernel_launch(void* const* d_in, const int* in_sizes, int n_in,
                              void* d_out, int out_size, void* d_ws, size_t ws_size,
                              hipStream_t stream) {
  const int*   x     = (const int*)d_in[0];
  const int*   ei    = (const int*)d_in[1];
  const int*   ea    = (const int*)d_in[2];
  const float* at    = (const float*)d_in[3];
  const float* bt    = (const float*)d_in[4];
  const float* W     = (const float*)d_in[5];
  const float* b     = (const float*)d_in[6];
  const float* root  = (const float*)d_in[7];
  const float* gamma = (const float*)d_in[8];
  const float* beta  = (const float*)d_in[9];
  float* out = (float*)d_out;

  char* ws = (char*)d_ws;
  size_t ND = (size_t)NN * DD;
  ushort* hl   = (ushort*)ws;                       // ND bf16
  ushort* pre  = hl + ND;                           // ND fp16
  ushort* acts = pre + ND;                          // 4*ND bf16; slot0: h then h+act0
  int4*   recs = (int4*)(acts + 4 * ND);            // NE * 16B (byte off 12*ND, 16B-aligned)
  ushort* Wbf  = (ushort*)(recs + NE);              // 5*128*128 bf16
  float*  btc  = (float*)(Wbf + NL * DD * DD);      // 1000*128 fp32
  float*  deg  = btc + 1000 * DD;                   // N
  float*  dis  = deg + NN;                          // N
  float*  invd = dis + NN;                          // N
  int*    cnt  = (int*)(invd + NN);                 // N
  int*    offa = cnt + NN;                          // N+1 (+3 pad)
  int*    nxt  = offa + NN + 4;                     // N
  int*    bsum = nxt + NN;                          // 256
  int*    bbase= bsum + 256;                        // 256
  float*  gsum = (float*)(bbase + 256);             // D
  float*  gss  = gsum + DD;                         // D

  // ---- precompute ----
  k_deg_init<<<(NN + 255) / 256, 256, 0, stream>>>(deg, cnt);
  k_deg_count<<<(NE + 255) / 256, 256, 0, stream>>>(ei, deg, cnt);
  k_deg_fin<<<(NN + 255) / 256, 256, 0, stream>>>(deg, dis, invd);
  k_scan1<<<SCAN_BLKS, 256, 0, stream>>>(cnt, offa, bsum);
  k_scan2<<<1, 256, 0, stream>>>(bsum, bbase);
  k_scan3<<<(NN + 255) / 256, 256, 0, stream>>>(offa, bbase, nxt);
  k_fill<<<(NE + 255) / 256, 256, 0, stream>>>(ei, ea, dis, nxt, recs);
  k_btc<<<1000 * DD / 256, 256, 0, stream>>>(bt, btc);
  k_wconv<<<NL * DD * DD / 256, 256, 0, stream>>>(W, Wbf);
  k_encode<<<(int)(ND / 2 / 256), 256, 0, stream>>>(x, at, acts);

  // ---- layers ----
  for (int l = 0; l < NL; ++l) {
    // gemm_l consumes layer-(l-1) stats still in gsum/gss (BN folded in-kernel);
    // memset AFTER gemm, before agg_l refills the stats.
    int mode = (l == 0) ? 0 : ((l == 1) ? 2 : 1);
    k_gemm<<<(NN + 127) / 128, 256, 0, stream>>>(
        acts, pre, Wbf + (size_t)l * DD * DD, b + l * DD,
        gsum, gss, gamma + (size_t)(l == 0 ? 0 : l - 1) * DD,
        beta + (size_t)(l == 0 ? 0 : l - 1) * DD,
        acts + (size_t)(l == 0 ? 0 : l - 1) * ND,
        hl, mode);
    hipMemsetAsync(gsum, 0, 2 * DD * sizeof(float), stream);
    k_aggregate<<<(NN + 127) / 128, 256, 0, stream>>>(hl, offa, recs, btc,
        root + l * DD, invd, pre, gsum, gss);
  }
  k_apply_final<<<(int)(ND / 2 / 256), 256, 0, stream>>>(pre, acts,
      gsum, gss, gamma + 4 * DD, beta + 4 * DD, out);
}

// Round 15
// 938.335 us; speedup vs baseline: 1.8002x; 1.0428x over previous
//
#include <hip/hip_runtime.h>
#include <hip/hip_fp16.h>

#define NN 200000
#define NE 400000
#define DD 128
#define NL 5
#define AV 100
#define BV 10
#define EPSV 1e-5f
#define SCAN_BLKS 196   // ceil(NN/1024)

typedef short s8v __attribute__((ext_vector_type(8)));   // 8 bf16/fp16 (4 VGPRs)
typedef float f4v __attribute__((ext_vector_type(4)));   // 4 fp32 acc

__device__ __forceinline__ ushort f2bf(float f) {        // RNE float->bf16
  uint u = __float_as_uint(f);
  u += 0x7FFFu + ((u >> 16) & 1u);
  return (ushort)(u >> 16);
}

__device__ __forceinline__ float bf2f(ushort u) {        // bf16->float
  return __uint_as_float(((uint)u) << 16);
}

__device__ __forceinline__ ushort f2h(float f) {         // RNE float->fp16
  return __half_as_ushort(__float2half(f));
}

__device__ __forceinline__ float h2f(ushort u) {         // fp16->float
  return __half2float(__ushort_as_half(u));
}

// ---------- encode: h = sum of atom embeddings -> acts slot 0 (bf16 only) ----------
__global__ __launch_bounds__(256) void k_encode(const int* __restrict__ x,
    const float* __restrict__ at, ushort* __restrict__ hbuf) {
  int idx = blockIdx.x * 256 + threadIdx.x;       // N*D/2 threads exact
  int n = idx >> 6, dp = idx & 63;                // wave = one node -> x row broadcast
  const int* xr = x + n * 9;
  float s0 = 0.f, s1 = 0.f;
#pragma unroll
  for (int c = 0; c < 9; ++c) {
    float2 v = *(const float2*)&at[(c * AV + xr[c]) * DD + dp * 2];
    s0 += v.x; s1 += v.y;
  }
  ((uint*)hbuf)[idx] = (uint)f2bf(s0) | ((uint)f2bf(s1) << 16);
}

// ---------- degree ----------
__global__ __launch_bounds__(256) void k_deg_init(float* __restrict__ deg,
                                                  int* __restrict__ cnt) {
  int i = blockIdx.x * 256 + threadIdx.x;
  if (i < NN) { deg[i] = 1.0f; cnt[i] = 0; }
}

__global__ __launch_bounds__(256) void k_deg_count(const int* __restrict__ ei,
    float* __restrict__ deg, int* __restrict__ cnt) {
  int e = blockIdx.x * 256 + threadIdx.x;
  if (e < NE) {
    atomicAdd(&deg[ei[e]], 1.0f);
    atomicAdd(&cnt[ei[NE + e]], 1);
  }
}

__global__ __launch_bounds__(256) void k_deg_fin(const float* __restrict__ deg,
    float* __restrict__ dis, float* __restrict__ invd) {
  int i = blockIdx.x * 256 + threadIdx.x;
  if (i < NN) {
    float dg = deg[i];
    dis[i] = rsqrtf(dg);
    invd[i] = 1.0f / dg;
  }
}

// ---------- exclusive scan of cnt -> off ----------
__global__ __launch_bounds__(256) void k_scan1(const int* __restrict__ cnt,
    int* __restrict__ off, int* __restrict__ bsum) {
  __shared__ int s[256];
  int t = threadIdx.x;
  int base = blockIdx.x * 1024 + t * 4;
  int c0 = (base + 0 < NN) ? cnt[base + 0] : 0;
  int c1 = (base + 1 < NN) ? cnt[base + 1] : 0;
  int c2 = (base + 2 < NN) ? cnt[base + 2] : 0;
  int c3 = (base + 3 < NN) ? cnt[base + 3] : 0;
  int tsum = c0 + c1 + c2 + c3;
  s[t] = tsum;
  __syncthreads();
  for (int o = 1; o < 256; o <<= 1) {
    int v = (t >= o) ? s[t - o] : 0;
    __syncthreads();
    s[t] += v;
    __syncthreads();
  }
  int excl = s[t] - tsum;
  if (base + 0 < NN) off[base + 0] = excl;
  if (base + 1 < NN) off[base + 1] = excl + c0;
  if (base + 2 < NN) off[base + 2] = excl + c0 + c1;
  if (base + 3 < NN) off[base + 3] = excl + c0 + c1 + c2;
  if (t == 255) bsum[blockIdx.x] = s[255];
}

__global__ __launch_bounds__(256) void k_scan2(const int* __restrict__ bsum,
    int* __restrict__ bbase) {
  __shared__ int s[256];
  int t = threadIdx.x;
  int v0 = (t < SCAN_BLKS) ? bsum[t] : 0;
  s[t] = v0;
  __syncthreads();
  for (int o = 1; o < 256; o <<= 1) {
    int v = (t >= o) ? s[t - o] : 0;
    __syncthreads();
    s[t] += v;
    __syncthreads();
  }
  if (t < SCAN_BLKS) bbase[t] = s[t] - v0;
}

__global__ __launch_bounds__(256) void k_scan3(int* __restrict__ off,
    const int* __restrict__ bbase, int* __restrict__ nxt) {
  int i = blockIdx.x * 256 + threadIdx.x;
  if (i < NN) {
    int v = off[i] + bbase[i >> 10];
    off[i] = v;
    nxt[i] = v;
  }
  if (i == 0) off[NN] = NE;
}

// ---------- fill CSR records: {row, packed_ea, norm_bits, 0} ----------
__global__ __launch_bounds__(256) void k_fill(const int* __restrict__ ei,
    const int* __restrict__ ea, const float* __restrict__ dis,
    int* __restrict__ nxt, int4* __restrict__ recs) {
  int e = blockIdx.x * 256 + threadIdx.x;
  if (e >= NE) return;
  int r = ei[e], c = ei[NE + e];
  int pa = ea[e * 3 + 0] + ea[e * 3 + 1] * 10 + ea[e * 3 + 2] * 100;
  float nr = dis[r] * dis[c];
  int pos = atomicAdd(&nxt[c], 1);
  recs[pos] = make_int4(r, pa, __float_as_int(nr), 0);
}

// ---------- combined bond table (fp32): btc[pa][d] ----------
__global__ __launch_bounds__(256) void k_btc(const float* __restrict__ bt,
    float* __restrict__ btc) {
  int idx = blockIdx.x * 256 + threadIdx.x;       // 1000*128 exact
  int p = idx >> 7, d = idx & 127;
  int a = p % 10, b = (p / 10) % 10, c = p / 100;
  btc[idx] = bt[(0 * BV + a) * DD + d] + bt[(1 * BV + b) * DD + d]
           + bt[(2 * BV + c) * DD + d];
}

// ---------- W -> bf16 ----------
__global__ __launch_bounds__(256) void k_wconv(const float* __restrict__ W,
    ushort* __restrict__ Wbf) {
  int i = blockIdx.x * 256 + threadIdx.x;         // 5*128*128 exact
  Wbf[i] = f2bf(W[i]);
}

// ---------- MFMA GEMM: hl(BF16) = A' @ Wl^T + bl ----------
// mode0: A' = srcbf (bf16 h from encode, = acts slot 0).
// mode1: A' = relu(pre_fp16*scale+shift); A' (bf16) stored to actl.
// mode2: like mode1 but folds the h still in actl: store bf16(h + A').
// pre is FP16; BN fold in-kernel from previous layer's stats (R13/R14).
__global__ __launch_bounds__(256) void k_gemm(const ushort* __restrict__ srcbf,
    const ushort* __restrict__ srcp, const ushort* __restrict__ Wbf,
    const float* __restrict__ bl, const float* __restrict__ gsum,
    const float* __restrict__ gss, const float* __restrict__ gmm,
    const float* __restrict__ bbn, ushort* __restrict__ actl,
    ushort* __restrict__ hl, int mode) {
  __shared__ float s_sc[DD], s_sh[DD];
  int t = threadIdx.x;
  int lane = t & 63, wave = t >> 6;
  int col = lane & 15, quad = lane >> 4;
  int nb = blockIdx.x * 128 + wave * 32;
  int r0 = nb + col, r1 = nb + 16 + col;
  bool v0 = r0 < NN, v1 = r1 < NN;
  long a0off = (long)(v0 ? r0 : NN - 1) * DD;
  long a1off = (long)(v1 ? r1 : NN - 1) * DD;

  s8v af0[4], af1[4];                             // A fragments, 4 k-slices

  if (mode == 0) {
#pragma unroll
    for (int ks = 0; ks < 4; ++ks) {              // 8 loads, one burst
      int k0 = ks * 32 + quad * 8;
      af0[ks] = *(const s8v*)&srcbf[a0off + k0];
      af1[ks] = *(const s8v*)&srcbf[a1off + k0];
    }
  } else {
    if (t < DD) {                                 // BN fold: stats -> scale/shift
      float m = gsum[t] * (1.0f / NN);
      float v = gss[t] * (1.0f / NN) - m * m;
      float sc = gmm[t] * rsqrtf(v + EPSV);
      s_sc[t] = sc;
      s_sh[t] = bbn[t] - m * sc;
    }
    __syncthreads();
    s8v pF0[4], pF1[4];                           // fp16 pre, one burst (8 loads)
#pragma unroll
    for (int ks = 0; ks < 4; ++ks) {
      int k0 = ks * 32 + quad * 8;
      pF0[ks] = *(const s8v*)&srcp[a0off + k0];
      pF1[ks] = *(const s8v*)&srcp[a1off + k0];
    }
#pragma unroll
    for (int ks = 0; ks < 4; ++ks) {              // activation + pack (VALU)
      int k0 = ks * 32 + quad * 8;
      float scv[8], shv[8];
#pragma unroll
      for (int j = 0; j < 8; ++j) { scv[j] = s_sc[k0 + j]; shv[j] = s_sh[k0 + j]; }
#pragma unroll
      for (int j = 0; j < 8; ++j) {
        float w = fmaxf(h2f((ushort)pF0[ks][j]) * scv[j] + shv[j], 0.f);
        af0[ks][j] = (short)f2bf(w);
        float u = fmaxf(h2f((ushort)pF1[ks][j]) * scv[j] + shv[j], 0.f);
        af1[ks][j] = (short)f2bf(u);
      }
    }
    // store A' (bf16); mode2 folds the h currently in actl
    if (v0) {
#pragma unroll
      for (int ks = 0; ks < 4; ++ks) {
        int k0 = ks * 32 + quad * 8;
        s8v st = af0[ks];
        if (mode == 2) {
          s8v h8 = *(const s8v*)&actl[a0off + k0];
#pragma unroll
          for (int j = 0; j < 8; ++j)
            st[j] = (short)f2bf(bf2f((ushort)h8[j]) + bf2f((ushort)af0[ks][j]));
        }
        *(s8v*)&actl[a0off + k0] = st;
      }
    }
    if (v1) {
#pragma unroll
      for (int ks = 0; ks < 4; ++ks) {
        int k0 = ks * 32 + quad * 8;
        s8v st = af1[ks];
        if (mode == 2) {
          s8v h8 = *(const s8v*)&actl[a1off + k0];
#pragma unroll
          for (int j = 0; j < 8; ++j)
            st[j] = (short)f2bf(bf2f((ushort)h8[j]) + bf2f((ushort)af1[ks][j]));
        }
        *(s8v*)&actl[a1off + k0] = st;
      }
    }
  }

  f4v acc[2][8];
#pragma unroll
  for (int i = 0; i < 2; ++i)
#pragma unroll
    for (int j = 0; j < 8; ++j) acc[i][j] = (f4v)0.f;

#pragma unroll
  for (int ks = 0; ks < 4; ++ks) {                // MFMA loop: W loads (L2) + 64 MFMA
    int k0 = ks * 32 + quad * 8;
#pragma unroll
    for (int j = 0; j < 8; ++j) {                 // B[k][n=col] for out-tile j = W[j*16+col][k]
      s8v bf = *(const s8v*)&Wbf[(j * 16 + col) * DD + k0];
      acc[0][j] = __builtin_amdgcn_mfma_f32_16x16x32_bf16(af0[ks], bf, acc[0][j], 0, 0, 0);
      acc[1][j] = __builtin_amdgcn_mfma_f32_16x16x32_bf16(af1[ks], bf, acc[1][j], 0, 0, 0);
    }
  }

  float bb[8];
#pragma unroll
  for (int j = 0; j < 8; ++j) bb[j] = bl[j * 16 + col];
#pragma unroll
  for (int i = 0; i < 2; ++i) {
    int rowb = nb + i * 16 + quad * 4;            // D: col=lane&15, row=quad*4+reg
#pragma unroll
    for (int r = 0; r < 4; ++r) {
      int n = rowb + r;
      if (n < NN) {
#pragma unroll
        for (int j = 0; j < 8; ++j)
          hl[(long)n * DD + j * 16 + col] = f2bf(acc[i][j][r] + bb[j]);
      }
    }
  }
}

// ---------- gather-aggregate + self term + BN partials ----------
// EIGHTH-wave (8 lanes) owns a CONTIGUOUS run of 8 nodes (R15): lane covers
// d = (lane&7)*16 .. +15 (32B bf16 gathers, 64B btc). 8 independent chains
// per wave (vs 4) -> 2x memory-level parallelism for the latency-bound
// serial chain. Block = 256 nodes, grid 782 (single co-residency round).
// Rolling 2-record recs prefetch, 2-edge unroll, fp16 pre store unchanged.
__global__ __launch_bounds__(256) void k_aggregate(const ushort* __restrict__ hl,
    const int* __restrict__ off, const int4* __restrict__ recs,
    const float* __restrict__ btc, const float* __restrict__ rootl,
    const float* __restrict__ invd, ushort* __restrict__ pre,
    float* __restrict__ gsum, float* __restrict__ gss) {
  __shared__ float redS[256][17], redQ[256][17];   // +1 pad: conflict-free
  int t = threadIdx.x;
  int ql = t & 7;                                  // lane within eighth-wave
  int qs = t >> 3;                                 // chain slot 0..31
  int d0 = ql * 16;
  int base = blockIdx.x * 256 + qs * 8;
  float rt[16];
#pragma unroll
  for (int j = 0; j < 16; ++j) rt[j] = rootl[d0 + j];
  float sa[16], qa[16];
#pragma unroll
  for (int j = 0; j < 16; ++j) { sa[j] = 0.f; qa[j] = 0.f; }
  if (base < NN) {
    int eptr = off[base];
    int enext = off[base + 1];
    int4 r0 = recs[(eptr < NE) ? eptr : (NE - 1)];           // rolling prefetch regs
    int4 r1 = recs[(eptr + 1 < NE) ? eptr + 1 : (NE - 1)];
#pragma unroll 1
    for (int j = 0; j < 8; ++j) {
      int n = base + j;
      int ia = base + j + 2; if (ia > NN) ia = NN;
      int e_after = off[ia];                       // issued early, used next iter
      int eend = enext;
      s8v sv0 = *(const s8v*)&hl[(long)n * DD + d0];         // self-term (bf16)
      s8v sv1 = *(const s8v*)&hl[(long)n * DD + d0 + 8];
      float iv = invd[n];
      float acc[16];
#pragma unroll
      for (int k = 0; k < 16; ++k) acc[k] = 0.f;
      while (eptr + 2 <= eend) {                   // 2 edges per trip
        int4 ra = r0, rb = r1;
        int p0 = eptr + 2; if (p0 >= NE) p0 = NE - 1;
        int p1 = eptr + 3; if (p1 >= NE) p1 = NE - 1;
        r0 = recs[p0];                             // prefetch next pair
        r1 = recs[p1];
        s8v ha0 = *(const s8v*)&hl[(long)ra.x * DD + d0];    // 32B bf16 gather
        s8v ha1 = *(const s8v*)&hl[(long)ra.x * DD + d0 + 8];
        float4 ea0 = *(const float4*)&btc[ra.y * DD + d0];
        float4 ea1 = *(const float4*)&btc[ra.y * DD + d0 + 4];
        float4 ea2 = *(const float4*)&btc[ra.y * DD + d0 + 8];
        float4 ea3 = *(const float4*)&btc[ra.y * DD + d0 + 12];
        s8v hb0 = *(const s8v*)&hl[(long)rb.x * DD + d0];
        s8v hb1 = *(const s8v*)&hl[(long)rb.x * DD + d0 + 8];
        float4 eb0 = *(const float4*)&btc[rb.y * DD + d0];
        float4 eb1 = *(const float4*)&btc[rb.y * DD + d0 + 4];
        float4 eb2 = *(const float4*)&btc[rb.y * DD + d0 + 8];
        float4 eb3 = *(const float4*)&btc[rb.y * DD + d0 + 12];
        float na = __int_as_float(ra.z);
        float nb = __int_as_float(rb.z);
        float eav[16] = {ea0.x, ea0.y, ea0.z, ea0.w, ea1.x, ea1.y, ea1.z, ea1.w,
                         ea2.x, ea2.y, ea2.z, ea2.w, ea3.x, ea3.y, ea3.z, ea3.w};
        float ebv[16] = {eb0.x, eb0.y, eb0.z, eb0.w, eb1.x, eb1.y, eb1.z, eb1.w,
                         eb2.x, eb2.y, eb2.z, eb2.w, eb3.x, eb3.y, eb3.z, eb3.w};
#pragma unroll
        for (int k = 0; k < 8; ++k) {
          acc[k]     += fmaxf(bf2f((ushort)ha0[k]) + eav[k],     0.f) * na
                      + fmaxf(bf2f((ushort)hb0[k]) + ebv[k],     0.f) * nb;
          acc[8 + k] += fmaxf(bf2f((ushort)ha1[k]) + eav[8 + k], 0.f) * na
                      + fmaxf(bf2f((ushort)hb1[k]) + ebv[8 + k], 0.f) * nb;
        }
        eptr += 2;
      }
      if (eptr < eend) {                           // odd leftover edge
        int4 ra = r0;
        int4 tmp = r1;
        int p0 = eptr + 2; if (p0 >= NE) p0 = NE - 1;
        r1 = recs[p0];                             // maintain rolling invariant
        r0 = tmp;
        s8v hv0 = *(const s8v*)&hl[(long)ra.x * DD + d0];
        s8v hv1 = *(const s8v*)&hl[(long)ra.x * DD + d0 + 8];
        float4 ev0 = *(const float4*)&btc[ra.y * DD + d0];
        float4 ev1 = *(const float4*)&btc[ra.y * DD + d0 + 4];
        float4 ev2 = *(const float4*)&btc[ra.y * DD + d0 + 8];
        float4 ev3 = *(const float4*)&btc[ra.y * DD + d0 + 12];
        float nr = __int_as_float(ra.z);
        float evv[16] = {ev0.x, ev0.y, ev0.z, ev0.w, ev1.x, ev1.y, ev1.z, ev1.w,
                         ev2.x, ev2.y, ev2.z, ev2.w, ev3.x, ev3.y, ev3.z, ev3.w};
#pragma unroll
        for (int k = 0; k < 8; ++k) {
          acc[k]     += fmaxf(bf2f((ushort)hv0[k]) + evv[k],     0.f) * nr;
          acc[8 + k] += fmaxf(bf2f((ushort)hv1[k]) + evv[8 + k], 0.f) * nr;
        }
        eptr += 1;
      }
      float pv[16];
#pragma unroll
      for (int k = 0; k < 8; ++k) {
        pv[k]     = acc[k]     + fmaxf(bf2f((ushort)sv0[k]) + rt[k],     0.f) * iv;
        pv[8 + k] = acc[8 + k] + fmaxf(bf2f((ushort)sv1[k]) + rt[8 + k], 0.f) * iv;
      }
      s8v pq0, pq1;                                // pre stored as fp16 (32B)
#pragma unroll
      for (int k = 0; k < 8; ++k) {
        pq0[k] = (short)f2h(pv[k]);
        pq1[k] = (short)f2h(pv[8 + k]);
      }
      *(s8v*)&pre[(long)n * DD + d0] = pq0;
      *(s8v*)&pre[(long)n * DD + d0 + 8] = pq1;
#pragma unroll
      for (int k = 0; k < 16; ++k) {
        sa[k] += pv[k];
        qa[k] += pv[k] * pv[k];
      }
      enext = e_after;
    }
  }
#pragma unroll
  for (int k = 0; k < 16; ++k) { redS[t][k] = sa[k]; redQ[t][k] = qa[k]; }
  __syncthreads();
  if (t < 128) {                                   // d = t; ql=d>>4, c=d&15
    int qq = t >> 4, c = t & 15;
    float S = 0.f, Q = 0.f;
#pragma unroll
    for (int h = 0; h < 32; ++h) {
      S += redS[h * 8 + qq][c];
      Q += redQ[h * 8 + qq][c];
    }
    atomicAdd(&gsum[t], S);
    atomicAdd(&gss[t], Q);
  }
}

// ---------- final: out = (h+act0) + act1 + act2 + act3 + (pre4*scale4 + shift4)
// Pure write of out; scale4/shift4 computed in-kernel; pre4 read as fp16. ----------
__global__ __launch_bounds__(256) void k_apply_final(const ushort* __restrict__ preh,
    const ushort* __restrict__ acts, const float* __restrict__ gsum,
    const float* __restrict__ gss, const float* __restrict__ gmm,
    const float* __restrict__ bbn, float* __restrict__ out) {
  __shared__ float s_sc[DD], s_sh[DD];
  const int NDH = NN * DD / 2;                    // uint elements per slot
  int t = threadIdx.x;
  if (t < DD) {
    float m = gsum[t] * (1.0f / NN);
    float v = gss[t] * (1.0f / NN) - m * m;
    float sc = gmm[t] * rsqrtf(v + EPSV);
    s_sc[t] = sc;
    s_sh[t] = bbn[t] - m * sc;
  }
  __syncthreads();
  int idx = blockIdx.x * 256 + t;                 // N*D/2 exact
  int dp = idx & 63;
  uint a0 = ((const uint*)acts)[idx];
  uint a1 = ((const uint*)acts)[idx + NDH];
  uint a2 = ((const uint*)acts)[idx + 2 * NDH];
  uint a3 = ((const uint*)acts)[idx + 3 * NDH];
  uint pv = ((const uint*)preh)[idx];
  float2 o;
  o.x = bf2f((ushort)a0) + bf2f((ushort)a1) + bf2f((ushort)a2) + bf2f((ushort)a3)
      + h2f((ushort)pv) * s_sc[dp * 2] + s_sh[dp * 2];
  o.y = bf2f((ushort)(a0 >> 16)) + bf2f((ushort)(a1 >> 16)) + bf2f((ushort)(a2 >> 16))
      + bf2f((ushort)(a3 >> 16))
      + h2f((ushort)(pv >> 16)) * s_sc[dp * 2 + 1] + s_sh[dp * 2 + 1];
  *(float2*)&out[idx * 2] = o;
}

extern "C" void kernel_launch(void* const* d_in, const int* in_sizes, int n_in,
                              void* d_out, int out_size, void* d_ws, size_t ws_size,
                              hipStream_t stream) {
  const int*   x     = (const int*)d_in[0];
  const int*   ei    = (const int*)d_in[1];
  const int*   ea    = (const int*)d_in[2];
  const float* at    = (const float*)d_in[3];
  const float* bt    = (const float*)d_in[4];
  const float* W     = (const float*)d_in[5];
  const float* b     = (const float*)d_in[6];
  const float* root  = (const float*)d_in[7];
  const float* gamma = (const float*)d_in[8];
  const float* beta  = (const float*)d_in[9];
  float* out = (float*)d_out;

  char* ws = (char*)d_ws;
  size_t ND = (size_t)NN * DD;
  ushort* hl   = (ushort*)ws;                       // ND bf16
  ushort* pre  = hl + ND;                           // ND fp16
  ushort* acts = pre + ND;                          // 4*ND bf16; slot0: h then h+act0
  int4*   recs = (int4*)(acts + 4 * ND);            // NE * 16B (byte off 12*ND, 16B-aligned)
  ushort* Wbf  = (ushort*)(recs + NE);              // 5*128*128 bf16
  float*  btc  = (float*)(Wbf + NL * DD * DD);      // 1000*128 fp32
  float*  deg  = btc + 1000 * DD;                   // N
  float*  dis  = deg + NN;                          // N
  float*  invd = dis + NN;                          // N
  int*    cnt  = (int*)(invd + NN);                 // N
  int*    offa = cnt + NN;                          // N+1 (+3 pad)
  int*    nxt  = offa + NN + 4;                     // N
  int*    bsum = nxt + NN;                          // 256
  int*    bbase= bsum + 256;                        // 256
  float*  gsum = (float*)(bbase + 256);             // D
  float*  gss  = gsum + DD;                         // D

  // ---- precompute ----
  k_deg_init<<<(NN + 255) / 256, 256, 0, stream>>>(deg, cnt);
  k_deg_count<<<(NE + 255) / 256, 256, 0, stream>>>(ei, deg, cnt);
  k_deg_fin<<<(NN + 255) / 256, 256, 0, stream>>>(deg, dis, invd);
  k_scan1<<<SCAN_BLKS, 256, 0, stream>>>(cnt, offa, bsum);
  k_scan2<<<1, 256, 0, stream>>>(bsum, bbase);
  k_scan3<<<(NN + 255) / 256, 256, 0, stream>>>(offa, bbase, nxt);
  k_fill<<<(NE + 255) / 256, 256, 0, stream>>>(ei, ea, dis, nxt, recs);
  k_btc<<<1000 * DD / 256, 256, 0, stream>>>(bt, btc);
  k_wconv<<<NL * DD * DD / 256, 256, 0, stream>>>(W, Wbf);
  k_encode<<<(int)(ND / 2 / 256), 256, 0, stream>>>(x, at, acts);

  // ---- layers ----
  for (int l = 0; l < NL; ++l) {
    // gemm_l consumes layer-(l-1) stats still in gsum/gss (BN folded in-kernel);
    // memset AFTER gemm, before agg_l refills the stats.
    int mode = (l == 0) ? 0 : ((l == 1) ? 2 : 1);
    k_gemm<<<(NN + 127) / 128, 256, 0, stream>>>(
        acts, pre, Wbf + (size_t)l * DD * DD, b + l * DD,
        gsum, gss, gamma + (size_t)(l == 0 ? 0 : l - 1) * DD,
        beta + (size_t)(l == 0 ? 0 : l - 1) * DD,
        acts + (size_t)(l == 0 ? 0 : l - 1) * ND,
        hl, mode);
    hipMemsetAsync(gsum, 0, 2 * DD * sizeof(float), stream);
    k_aggregate<<<(NN + 255) / 256, 256, 0, stream>>>(hl, offa, recs, btc,
        root + l * DD, invd, pre, gsum, gss);
  }
  k_apply_final<<<(int)(ND / 2 / 256), 256, 0, stream>>>(pre, acts,
      gsum, gss, gamma + 4 * DD, beta + 4 * DD, out);
}

// Round 16
// 915.042 us; speedup vs baseline: 1.8461x; 1.0255x over previous
//
#include <hip/hip_runtime.h>
#include <hip/hip_fp16.h>

#define NN 200000
#define NE 400000
#define DD 128
#define NL 5
#define AV 100
#define BV 10
#define EPSV 1e-5f
#define SCAN_BLKS 196   // ceil(NN/1024)

typedef short s8v __attribute__((ext_vector_type(8)));   // 8 bf16/fp16 (4 VGPRs)
typedef float f4v __attribute__((ext_vector_type(4)));   // 4 fp32 acc

__device__ __forceinline__ ushort f2bf(float f) {        // RNE float->bf16
  uint u = __float_as_uint(f);
  u += 0x7FFFu + ((u >> 16) & 1u);
  return (ushort)(u >> 16);
}

__device__ __forceinline__ float bf2f(ushort u) {        // bf16->float
  return __uint_as_float(((uint)u) << 16);
}

__device__ __forceinline__ ushort f2h(float f) {         // RNE float->fp16
  return __half_as_ushort(__float2half(f));
}

__device__ __forceinline__ float h2f(ushort u) {         // fp16->float
  return __half2float(__ushort_as_half(u));
}

// ---------- atom table -> bf16 (halves encode's L2 stream) ----------
__global__ __launch_bounds__(256) void k_atc(const float* __restrict__ at,
    ushort* __restrict__ atb) {
  int i = blockIdx.x * 256 + threadIdx.x;         // 9*100*128 = 115200 exact
  atb[i] = f2bf(at[i]);
}

// ---------- encode: h = sum of atom embeddings -> acts slot 0 (bf16) ----------
// HALF-wave (32 lanes) per node, 4 dims/lane via ushort4 (8B) gathers from the
// bf16 table: halves both L2 bytes (921->460 MB) and VMEM instructions vs the
// old 64-lane/float2/fp32-table version (77 us, 0.77 TB/s effective).
__global__ __launch_bounds__(256) void k_encode(const int* __restrict__ x,
    const ushort* __restrict__ atb, ushort* __restrict__ hbuf) {
  int idx = blockIdx.x * 256 + threadIdx.x;       // N*32 threads: grid 25000 exact
  int n = idx >> 5, dp = idx & 31;                // half-wave = one node
  const int* xr = x + n * 9;
  float s0 = 0.f, s1 = 0.f, s2 = 0.f, s3 = 0.f;
#pragma unroll
  for (int c = 0; c < 9; ++c) {
    ushort4 v = *(const ushort4*)&atb[(c * AV + xr[c]) * DD + dp * 4];
    s0 += bf2f(v.x); s1 += bf2f(v.y); s2 += bf2f(v.z); s3 += bf2f(v.w);
  }
  ushort4 o;
  o.x = f2bf(s0); o.y = f2bf(s1); o.z = f2bf(s2); o.w = f2bf(s3);
  *(ushort4*)&hbuf[(long)n * DD + dp * 4] = o;
}

// ---------- degree ----------
__global__ __launch_bounds__(256) void k_deg_init(float* __restrict__ deg,
                                                  int* __restrict__ cnt) {
  int i = blockIdx.x * 256 + threadIdx.x;
  if (i < NN) { deg[i] = 1.0f; cnt[i] = 0; }
}

__global__ __launch_bounds__(256) void k_deg_count(const int* __restrict__ ei,
    float* __restrict__ deg, int* __restrict__ cnt) {
  int e = blockIdx.x * 256 + threadIdx.x;
  if (e < NE) {
    atomicAdd(&deg[ei[e]], 1.0f);
    atomicAdd(&cnt[ei[NE + e]], 1);
  }
}

__global__ __launch_bounds__(256) void k_deg_fin(const float* __restrict__ deg,
    float* __restrict__ dis, float* __restrict__ invd) {
  int i = blockIdx.x * 256 + threadIdx.x;
  if (i < NN) {
    float dg = deg[i];
    dis[i] = rsqrtf(dg);
    invd[i] = 1.0f / dg;
  }
}

// ---------- exclusive scan of cnt -> off ----------
__global__ __launch_bounds__(256) void k_scan1(const int* __restrict__ cnt,
    int* __restrict__ off, int* __restrict__ bsum) {
  __shared__ int s[256];
  int t = threadIdx.x;
  int base = blockIdx.x * 1024 + t * 4;
  int c0 = (base + 0 < NN) ? cnt[base + 0] : 0;
  int c1 = (base + 1 < NN) ? cnt[base + 1] : 0;
  int c2 = (base + 2 < NN) ? cnt[base + 2] : 0;
  int c3 = (base + 3 < NN) ? cnt[base + 3] : 0;
  int tsum = c0 + c1 + c2 + c3;
  s[t] = tsum;
  __syncthreads();
  for (int o = 1; o < 256; o <<= 1) {
    int v = (t >= o) ? s[t - o] : 0;
    __syncthreads();
    s[t] += v;
    __syncthreads();
  }
  int excl = s[t] - tsum;
  if (base + 0 < NN) off[base + 0] = excl;
  if (base + 1 < NN) off[base + 1] = excl + c0;
  if (base + 2 < NN) off[base + 2] = excl + c0 + c1;
  if (base + 3 < NN) off[base + 3] = excl + c0 + c1 + c2;
  if (t == 255) bsum[blockIdx.x] = s[255];
}

__global__ __launch_bounds__(256) void k_scan2(const int* __restrict__ bsum,
    int* __restrict__ bbase) {
  __shared__ int s[256];
  int t = threadIdx.x;
  int v0 = (t < SCAN_BLKS) ? bsum[t] : 0;
  s[t] = v0;
  __syncthreads();
  for (int o = 1; o < 256; o <<= 1) {
    int v = (t >= o) ? s[t - o] : 0;
    __syncthreads();
    s[t] += v;
    __syncthreads();
  }
  if (t < SCAN_BLKS) bbase[t] = s[t] - v0;
}

__global__ __launch_bounds__(256) void k_scan3(int* __restrict__ off,
    const int* __restrict__ bbase, int* __restrict__ nxt) {
  int i = blockIdx.x * 256 + threadIdx.x;
  if (i < NN) {
    int v = off[i] + bbase[i >> 10];
    off[i] = v;
    nxt[i] = v;
  }
  if (i == 0) off[NN] = NE;
}

// ---------- fill CSR records: {row, packed_ea, norm_bits, 0} ----------
__global__ __launch_bounds__(256) void k_fill(const int* __restrict__ ei,
    const int* __restrict__ ea, const float* __restrict__ dis,
    int* __restrict__ nxt, int4* __restrict__ recs) {
  int e = blockIdx.x * 256 + threadIdx.x;
  if (e >= NE) return;
  int r = ei[e], c = ei[NE + e];
  int pa = ea[e * 3 + 0] + ea[e * 3 + 1] * 10 + ea[e * 3 + 2] * 100;
  float nr = dis[r] * dis[c];
  int pos = atomicAdd(&nxt[c], 1);
  recs[pos] = make_int4(r, pa, __float_as_int(nr), 0);
}

// ---------- combined bond table (fp32): btc[pa][d] ----------
__global__ __launch_bounds__(256) void k_btc(const float* __restrict__ bt,
    float* __restrict__ btc) {
  int idx = blockIdx.x * 256 + threadIdx.x;       // 1000*128 exact
  int p = idx >> 7, d = idx & 127;
  int a = p % 10, b = (p / 10) % 10, c = p / 100;
  btc[idx] = bt[(0 * BV + a) * DD + d] + bt[(1 * BV + b) * DD + d]
           + bt[(2 * BV + c) * DD + d];
}

// ---------- W -> bf16 ----------
__global__ __launch_bounds__(256) void k_wconv(const float* __restrict__ W,
    ushort* __restrict__ Wbf) {
  int i = blockIdx.x * 256 + threadIdx.x;         // 5*128*128 exact
  Wbf[i] = f2bf(W[i]);
}

// ---------- MFMA GEMM: hl(BF16) = A' @ Wl^T + bl ----------
// mode0: A' = srcbf (bf16 h from encode, = acts slot 0).
// mode1: A' = relu(pre_fp16*scale+shift); A' (bf16) stored to actl.
// mode2: like mode1 but folds the h still in actl: store bf16(h + A').
// pre is FP16; BN fold in-kernel from previous layer's stats (R13/R14).
__global__ __launch_bounds__(256) void k_gemm(const ushort* __restrict__ srcbf,
    const ushort* __restrict__ srcp, const ushort* __restrict__ Wbf,
    const float* __restrict__ bl, const float* __restrict__ gsum,
    const float* __restrict__ gss, const float* __restrict__ gmm,
    const float* __restrict__ bbn, ushort* __restrict__ actl,
    ushort* __restrict__ hl, int mode) {
  __shared__ float s_sc[DD], s_sh[DD];
  int t = threadIdx.x;
  int lane = t & 63, wave = t >> 6;
  int col = lane & 15, quad = lane >> 4;
  int nb = blockIdx.x * 128 + wave * 32;
  int r0 = nb + col, r1 = nb + 16 + col;
  bool v0 = r0 < NN, v1 = r1 < NN;
  long a0off = (long)(v0 ? r0 : NN - 1) * DD;
  long a1off = (long)(v1 ? r1 : NN - 1) * DD;

  s8v af0[4], af1[4];                             // A fragments, 4 k-slices

  if (mode == 0) {
#pragma unroll
    for (int ks = 0; ks < 4; ++ks) {              // 8 loads, one burst
      int k0 = ks * 32 + quad * 8;
      af0[ks] = *(const s8v*)&srcbf[a0off + k0];
      af1[ks] = *(const s8v*)&srcbf[a1off + k0];
    }
  } else {
    if (t < DD) {                                 // BN fold: stats -> scale/shift
      float m = gsum[t] * (1.0f / NN);
      float v = gss[t] * (1.0f / NN) - m * m;
      float sc = gmm[t] * rsqrtf(v + EPSV);
      s_sc[t] = sc;
      s_sh[t] = bbn[t] - m * sc;
    }
    __syncthreads();
    s8v pF0[4], pF1[4];                           // fp16 pre, one burst (8 loads)
#pragma unroll
    for (int ks = 0; ks < 4; ++ks) {
      int k0 = ks * 32 + quad * 8;
      pF0[ks] = *(const s8v*)&srcp[a0off + k0];
      pF1[ks] = *(const s8v*)&srcp[a1off + k0];
    }
#pragma unroll
    for (int ks = 0; ks < 4; ++ks) {              // activation + pack (VALU)
      int k0 = ks * 32 + quad * 8;
      float scv[8], shv[8];
#pragma unroll
      for (int j = 0; j < 8; ++j) { scv[j] = s_sc[k0 + j]; shv[j] = s_sh[k0 + j]; }
#pragma unroll
      for (int j = 0; j < 8; ++j) {
        float w = fmaxf(h2f((ushort)pF0[ks][j]) * scv[j] + shv[j], 0.f);
        af0[ks][j] = (short)f2bf(w);
        float u = fmaxf(h2f((ushort)pF1[ks][j]) * scv[j] + shv[j], 0.f);
        af1[ks][j] = (short)f2bf(u);
      }
    }
    // store A' (bf16); mode2 folds the h currently in actl
    if (v0) {
#pragma unroll
      for (int ks = 0; ks < 4; ++ks) {
        int k0 = ks * 32 + quad * 8;
        s8v st = af0[ks];
        if (mode == 2) {
          s8v h8 = *(const s8v*)&actl[a0off + k0];
#pragma unroll
          for (int j = 0; j < 8; ++j)
            st[j] = (short)f2bf(bf2f((ushort)h8[j]) + bf2f((ushort)af0[ks][j]));
        }
        *(s8v*)&actl[a0off + k0] = st;
      }
    }
    if (v1) {
#pragma unroll
      for (int ks = 0; ks < 4; ++ks) {
        int k0 = ks * 32 + quad * 8;
        s8v st = af1[ks];
        if (mode == 2) {
          s8v h8 = *(const s8v*)&actl[a1off + k0];
#pragma unroll
          for (int j = 0; j < 8; ++j)
            st[j] = (short)f2bf(bf2f((ushort)h8[j]) + bf2f((ushort)af1[ks][j]));
        }
        *(s8v*)&actl[a1off + k0] = st;
      }
    }
  }

  f4v acc[2][8];
#pragma unroll
  for (int i = 0; i < 2; ++i)
#pragma unroll
    for (int j = 0; j < 8; ++j) acc[i][j] = (f4v)0.f;

#pragma unroll
  for (int ks = 0; ks < 4; ++ks) {                // MFMA loop: W loads (L2) + 64 MFMA
    int k0 = ks * 32 + quad * 8;
#pragma unroll
    for (int j = 0; j < 8; ++j) {                 // B[k][n=col] for out-tile j = W[j*16+col][k]
      s8v bf = *(const s8v*)&Wbf[(j * 16 + col) * DD + k0];
      acc[0][j] = __builtin_amdgcn_mfma_f32_16x16x32_bf16(af0[ks], bf, acc[0][j], 0, 0, 0);
      acc[1][j] = __builtin_amdgcn_mfma_f32_16x16x32_bf16(af1[ks], bf, acc[1][j], 0, 0, 0);
    }
  }

  float bb[8];
#pragma unroll
  for (int j = 0; j < 8; ++j) bb[j] = bl[j * 16 + col];
#pragma unroll
  for (int i = 0; i < 2; ++i) {
    int rowb = nb + i * 16 + quad * 4;            // D: col=lane&15, row=quad*4+reg
#pragma unroll
    for (int r = 0; r < 4; ++r) {
      int n = rowb + r;
      if (n < NN) {
#pragma unroll
        for (int j = 0; j < 8; ++j)
          hl[(long)n * DD + j * 16 + col] = f2bf(acc[i][j][r] + bb[j]);
      }
    }
  }
}

// ---------- gather-aggregate + self term + BN partials ----------
// EIGHTH-wave (8 lanes) owns a CONTIGUOUS run of 8 nodes: lane covers
// d = (lane&7)*16 .. +15 (32B bf16 gathers, 64B btc). 8 independent chains
// per wave. Block = 256 nodes, grid 782. Rolling 2-record recs prefetch,
// 2-edge unroll, fp16 pre store.
__global__ __launch_bounds__(256) void k_aggregate(const ushort* __restrict__ hl,
    const int* __restrict__ off, const int4* __restrict__ recs,
    const float* __restrict__ btc, const float* __restrict__ rootl,
    const float* __restrict__ invd, ushort* __restrict__ pre,
    float* __restrict__ gsum, float* __restrict__ gss) {
  __shared__ float redS[256][17], redQ[256][17];   // +1 pad: conflict-free
  int t = threadIdx.x;
  int ql = t & 7;                                  // lane within eighth-wave
  int qs = t >> 3;                                 // chain slot 0..31
  int d0 = ql * 16;
  int base = blockIdx.x * 256 + qs * 8;
  float rt[16];
#pragma unroll
  for (int j = 0; j < 16; ++j) rt[j] = rootl[d0 + j];
  float sa[16], qa[16];
#pragma unroll
  for (int j = 0; j < 16; ++j) { sa[j] = 0.f; qa[j] = 0.f; }
  if (base < NN) {
    int eptr = off[base];
    int enext = off[base + 1];
    int4 r0 = recs[(eptr < NE) ? eptr : (NE - 1)];           // rolling prefetch regs
    int4 r1 = recs[(eptr + 1 < NE) ? eptr + 1 : (NE - 1)];
#pragma unroll 1
    for (int j = 0; j < 8; ++j) {
      int n = base + j;
      int ia = base + j + 2; if (ia > NN) ia = NN;
      int e_after = off[ia];                       // issued early, used next iter
      int eend = enext;
      s8v sv0 = *(const s8v*)&hl[(long)n * DD + d0];         // self-term (bf16)
      s8v sv1 = *(const s8v*)&hl[(long)n * DD + d0 + 8];
      float iv = invd[n];
      float acc[16];
#pragma unroll
      for (int k = 0; k < 16; ++k) acc[k] = 0.f;
      while (eptr + 2 <= eend) {                   // 2 edges per trip
        int4 ra = r0, rb = r1;
        int p0 = eptr + 2; if (p0 >= NE) p0 = NE - 1;
        int p1 = eptr + 3; if (p1 >= NE) p1 = NE - 1;
        r0 = recs[p0];                             // prefetch next pair
        r1 = recs[p1];
        s8v ha0 = *(const s8v*)&hl[(long)ra.x * DD + d0];    // 32B bf16 gather
        s8v ha1 = *(const s8v*)&hl[(long)ra.x * DD + d0 + 8];
        float4 ea0 = *(const float4*)&btc[ra.y * DD + d0];
        float4 ea1 = *(const float4*)&btc[ra.y * DD + d0 + 4];
        float4 ea2 = *(const float4*)&btc[ra.y * DD + d0 + 8];
        float4 ea3 = *(const float4*)&btc[ra.y * DD + d0 + 12];
        s8v hb0 = *(const s8v*)&hl[(long)rb.x * DD + d0];
        s8v hb1 = *(const s8v*)&hl[(long)rb.x * DD + d0 + 8];
        float4 eb0 = *(const float4*)&btc[rb.y * DD + d0];
        float4 eb1 = *(const float4*)&btc[rb.y * DD + d0 + 4];
        float4 eb2 = *(const float4*)&btc[rb.y * DD + d0 + 8];
        float4 eb3 = *(const float4*)&btc[rb.y * DD + d0 + 12];
        float na = __int_as_float(ra.z);
        float nb = __int_as_float(rb.z);
        float eav[16] = {ea0.x, ea0.y, ea0.z, ea0.w, ea1.x, ea1.y, ea1.z, ea1.w,
                         ea2.x, ea2.y, ea2.z, ea2.w, ea3.x, ea3.y, ea3.z, ea3.w};
        float ebv[16] = {eb0.x, eb0.y, eb0.z, eb0.w, eb1.x, eb1.y, eb1.z, eb1.w,
                         eb2.x, eb2.y, eb2.z, eb2.w, eb3.x, eb3.y, eb3.z, eb3.w};
#pragma unroll
        for (int k = 0; k < 8; ++k) {
          acc[k]     += fmaxf(bf2f((ushort)ha0[k]) + eav[k],     0.f) * na
                      + fmaxf(bf2f((ushort)hb0[k]) + ebv[k],     0.f) * nb;
          acc[8 + k] += fmaxf(bf2f((ushort)ha1[k]) + eav[8 + k], 0.f) * na
                      + fmaxf(bf2f((ushort)hb1[k]) + ebv[8 + k], 0.f) * nb;
        }
        eptr += 2;
      }
      if (eptr < eend) {                           // odd leftover edge
        int4 ra = r0;
        int4 tmp = r1;
        int p0 = eptr + 2; if (p0 >= NE) p0 = NE - 1;
        r1 = recs[p0];                             // maintain rolling invariant
        r0 = tmp;
        s8v hv0 = *(const s8v*)&hl[(long)ra.x * DD + d0];
        s8v hv1 = *(const s8v*)&hl[(long)ra.x * DD + d0 + 8];
        float4 ev0 = *(const float4*)&btc[ra.y * DD + d0];
        float4 ev1 = *(const float4*)&btc[ra.y * DD + d0 + 4];
        float4 ev2 = *(const float4*)&btc[ra.y * DD + d0 + 8];
        float4 ev3 = *(const float4*)&btc[ra.y * DD + d0 + 12];
        float nr = __int_as_float(ra.z);
        float evv[16] = {ev0.x, ev0.y, ev0.z, ev0.w, ev1.x, ev1.y, ev1.z, ev1.w,
                         ev2.x, ev2.y, ev2.z, ev2.w, ev3.x, ev3.y, ev3.z, ev3.w};
#pragma unroll
        for (int k = 0; k < 8; ++k) {
          acc[k]     += fmaxf(bf2f((ushort)hv0[k]) + evv[k],     0.f) * nr;
          acc[8 + k] += fmaxf(bf2f((ushort)hv1[k]) + evv[8 + k], 0.f) * nr;
        }
        eptr += 1;
      }
      float pv[16];
#pragma unroll
      for (int k = 0; k < 8; ++k) {
        pv[k]     = acc[k]     + fmaxf(bf2f((ushort)sv0[k]) + rt[k],     0.f) * iv;
        pv[8 + k] = acc[8 + k] + fmaxf(bf2f((ushort)sv1[k]) + rt[8 + k], 0.f) * iv;
      }
      s8v pq0, pq1;                                // pre stored as fp16 (32B)
#pragma unroll
      for (int k = 0; k < 8; ++k) {
        pq0[k] = (short)f2h(pv[k]);
        pq1[k] = (short)f2h(pv[8 + k]);
      }
      *(s8v*)&pre[(long)n * DD + d0] = pq0;
      *(s8v*)&pre[(long)n * DD + d0 + 8] = pq1;
#pragma unroll
      for (int k = 0; k < 16; ++k) {
        sa[k] += pv[k];
        qa[k] += pv[k] * pv[k];
      }
      enext = e_after;
    }
  }
#pragma unroll
  for (int k = 0; k < 16; ++k) { redS[t][k] = sa[k]; redQ[t][k] = qa[k]; }
  __syncthreads();
  if (t < 128) {                                   // d = t; ql=d>>4, c=d&15
    int qq = t >> 4, c = t & 15;
    float S = 0.f, Q = 0.f;
#pragma unroll
    for (int h = 0; h < 32; ++h) {
      S += redS[h * 8 + qq][c];
      Q += redQ[h * 8 + qq][c];
    }
    atomicAdd(&gsum[t], S);
    atomicAdd(&gss[t], Q);
  }
}

// ---------- final: out = (h+act0) + act1 + act2 + act3 + (pre4*scale4 + shift4)
// Pure write of out; scale4/shift4 computed in-kernel; pre4 read as fp16. ----------
__global__ __launch_bounds__(256) void k_apply_final(const ushort* __restrict__ preh,
    const ushort* __restrict__ acts, const float* __restrict__ gsum,
    const float* __restrict__ gss, const float* __restrict__ gmm,
    const float* __restrict__ bbn, float* __restrict__ out) {
  __shared__ float s_sc[DD], s_sh[DD];
  const int NDH = NN * DD / 2;                    // uint elements per slot
  int t = threadIdx.x;
  if (t < DD) {
    float m = gsum[t] * (1.0f / NN);
    float v = gss[t] * (1.0f / NN) - m * m;
    float sc = gmm[t] * rsqrtf(v + EPSV);
    s_sc[t] = sc;
    s_sh[t] = bbn[t] - m * sc;
  }
  __syncthreads();
  int idx = blockIdx.x * 256 + t;                 // N*D/2 exact
  int dp = idx & 63;
  uint a0 = ((const uint*)acts)[idx];
  uint a1 = ((const uint*)acts)[idx + NDH];
  uint a2 = ((const uint*)acts)[idx + 2 * NDH];
  uint a3 = ((const uint*)acts)[idx + 3 * NDH];
  uint pv = ((const uint*)preh)[idx];
  float2 o;
  o.x = bf2f((ushort)a0) + bf2f((ushort)a1) + bf2f((ushort)a2) + bf2f((ushort)a3)
      + h2f((ushort)pv) * s_sc[dp * 2] + s_sh[dp * 2];
  o.y = bf2f((ushort)(a0 >> 16)) + bf2f((ushort)(a1 >> 16)) + bf2f((ushort)(a2 >> 16))
      + bf2f((ushort)(a3 >> 16))
      + h2f((ushort)(pv >> 16)) * s_sc[dp * 2 + 1] + s_sh[dp * 2 + 1];
  *(float2*)&out[idx * 2] = o;
}

extern "C" void kernel_launch(void* const* d_in, const int* in_sizes, int n_in,
                              void* d_out, int out_size, void* d_ws, size_t ws_size,
                              hipStream_t stream) {
  const int*   x     = (const int*)d_in[0];
  const int*   ei    = (const int*)d_in[1];
  const int*   ea    = (const int*)d_in[2];
  const float* at    = (const float*)d_in[3];
  const float* bt    = (const float*)d_in[4];
  const float* W     = (const float*)d_in[5];
  const float* b     = (const float*)d_in[6];
  const float* root  = (const float*)d_in[7];
  const float* gamma = (const float*)d_in[8];
  const float* beta  = (const float*)d_in[9];
  float* out = (float*)d_out;

  char* ws = (char*)d_ws;
  size_t ND = (size_t)NN * DD;
  ushort* hl   = (ushort*)ws;                       // ND bf16
  ushort* pre  = hl + ND;                           // ND fp16
  ushort* acts = pre + ND;                          // 4*ND bf16; slot0: h then h+act0
  int4*   recs = (int4*)(acts + 4 * ND);            // NE * 16B (byte off 12*ND, 16B-aligned)
  ushort* Wbf  = (ushort*)(recs + NE);              // 5*128*128 bf16
  float*  btc  = (float*)(Wbf + NL * DD * DD);      // 1000*128 fp32
  float*  deg  = btc + 1000 * DD;                   // N
  float*  dis  = deg + NN;                          // N
  float*  invd = dis + NN;                          // N
  int*    cnt  = (int*)(invd + NN);                 // N
  int*    offa = cnt + NN;                          // N+1 (+3 pad)
  int*    nxt  = offa + NN + 4;                     // N
  int*    bsum = nxt + NN;                          // 256
  int*    bbase= bsum + 256;                        // 256
  float*  gsum = (float*)(bbase + 256);             // D
  float*  gss  = gsum + DD;                         // D
  ushort* atb  = (ushort*)(gss + DD);               // 9*100*128 bf16 (230 KB)

  // ---- precompute ----
  k_deg_init<<<(NN + 255) / 256, 256, 0, stream>>>(deg, cnt);
  k_deg_count<<<(NE + 255) / 256, 256, 0, stream>>>(ei, deg, cnt);
  k_deg_fin<<<(NN + 255) / 256, 256, 0, stream>>>(deg, dis, invd);
  k_scan1<<<SCAN_BLKS, 256, 0, stream>>>(cnt, offa, bsum);
  k_scan2<<<1, 256, 0, stream>>>(bsum, bbase);
  k_scan3<<<(NN + 255) / 256, 256, 0, stream>>>(offa, bbase, nxt);
  k_fill<<<(NE + 255) / 256, 256, 0, stream>>>(ei, ea, dis, nxt, recs);
  k_btc<<<1000 * DD / 256, 256, 0, stream>>>(bt, btc);
  k_wconv<<<NL * DD * DD / 256, 256, 0, stream>>>(W, Wbf);
  k_atc<<<9 * AV * DD / 256, 256, 0, stream>>>(at, atb);
  k_encode<<<NN * 32 / 256, 256, 0, stream>>>(x, atb, acts);

  // ---- layers ----
  for (int l = 0; l < NL; ++l) {
    // gemm_l consumes layer-(l-1) stats still in gsum/gss (BN folded in-kernel);
    // memset AFTER gemm, before agg_l refills the stats.
    int mode = (l == 0) ? 0 : ((l == 1) ? 2 : 1);
    k_gemm<<<(NN + 127) / 128, 256, 0, stream>>>(
        acts, pre, Wbf + (size_t)l * DD * DD, b + l * DD,
        gsum, gss, gamma + (size_t)(l == 0 ? 0 : l - 1) * DD,
        beta + (size_t)(l == 0 ? 0 : l - 1) * DD,
        acts + (size_t)(l == 0 ? 0 : l - 1) * ND,
        hl, mode);
    hipMemsetAsync(gsum, 0, 2 * DD * sizeof(float), stream);
    k_aggregate<<<(NN + 255) / 256, 256, 0, stream>>>(hl, offa, recs, btc,
        root + l * DD, invd, pre, gsum, gss);
  }
  k_apply_final<<<(int)(ND / 2 / 256), 256, 0, stream>>>(pre, acts,
      gsum, gss, gamma + 4 * DD, beta + 4 * DD, out);
}

// Round 17
// 894.594 us; speedup vs baseline: 1.8882x; 1.0229x over previous
//
#include <hip/hip_runtime.h>
#include <hip/hip_fp16.h>

#define NN 200000
#define NE 400000
#define DD 128
#define NL 5
#define AV 100
#define BV 10
#define EPSV 1e-5f
#define SCAN_BLKS 196   // ceil(NN/1024)

typedef short s8v __attribute__((ext_vector_type(8)));   // 8 bf16/fp16 (4 VGPRs)
typedef float f4v __attribute__((ext_vector_type(4)));   // 4 fp32 acc

__device__ __forceinline__ ushort f2bf(float f) {        // RNE float->bf16
  uint u = __float_as_uint(f);
  u += 0x7FFFu + ((u >> 16) & 1u);
  return (ushort)(u >> 16);
}

__device__ __forceinline__ float bf2f(ushort u) {        // bf16->float
  return __uint_as_float(((uint)u) << 16);
}

__device__ __forceinline__ ushort f2h(float f) {         // RNE float->fp16
  return __half_as_ushort(__float2half(f));
}

__device__ __forceinline__ float h2f(ushort u) {         // fp16->float
  return __half2float(__ushort_as_half(u));
}

// ---------- atom table -> bf16 (halves encode's L2 stream) ----------
__global__ __launch_bounds__(256) void k_atc(const float* __restrict__ at,
    ushort* __restrict__ atb) {
  int i = blockIdx.x * 256 + threadIdx.x;         // 9*100*128 = 115200 exact
  atb[i] = f2bf(at[i]);
}

// ---------- encode: h = sum of atom embeddings -> acts slot 0 (bf16) ----------
// HALF-wave (32 lanes) per node, 4 dims/lane via ushort4 (8B) gathers from the
// bf16 table.
__global__ __launch_bounds__(256) void k_encode(const int* __restrict__ x,
    const ushort* __restrict__ atb, ushort* __restrict__ hbuf) {
  int idx = blockIdx.x * 256 + threadIdx.x;       // N*32 threads: grid 25000 exact
  int n = idx >> 5, dp = idx & 31;                // half-wave = one node
  const int* xr = x + n * 9;
  float s0 = 0.f, s1 = 0.f, s2 = 0.f, s3 = 0.f;
#pragma unroll
  for (int c = 0; c < 9; ++c) {
    ushort4 v = *(const ushort4*)&atb[(c * AV + xr[c]) * DD + dp * 4];
    s0 += bf2f(v.x); s1 += bf2f(v.y); s2 += bf2f(v.z); s3 += bf2f(v.w);
  }
  ushort4 o;
  o.x = f2bf(s0); o.y = f2bf(s1); o.z = f2bf(s2); o.w = f2bf(s3);
  *(ushort4*)&hbuf[(long)n * DD + dp * 4] = o;
}

// ---------- degree ----------
__global__ __launch_bounds__(256) void k_deg_init(float* __restrict__ deg,
                                                  int* __restrict__ cnt) {
  int i = blockIdx.x * 256 + threadIdx.x;
  if (i < NN) { deg[i] = 1.0f; cnt[i] = 0; }
}

__global__ __launch_bounds__(256) void k_deg_count(const int* __restrict__ ei,
    float* __restrict__ deg, int* __restrict__ cnt) {
  int e = blockIdx.x * 256 + threadIdx.x;
  if (e < NE) {
    atomicAdd(&deg[ei[e]], 1.0f);
    atomicAdd(&cnt[ei[NE + e]], 1);
  }
}

__global__ __launch_bounds__(256) void k_deg_fin(const float* __restrict__ deg,
    float* __restrict__ dis, float* __restrict__ invd) {
  int i = blockIdx.x * 256 + threadIdx.x;
  if (i < NN) {
    float dg = deg[i];
    dis[i] = rsqrtf(dg);
    invd[i] = 1.0f / dg;
  }
}

// ---------- exclusive scan of cnt -> off ----------
__global__ __launch_bounds__(256) void k_scan1(const int* __restrict__ cnt,
    int* __restrict__ off, int* __restrict__ bsum) {
  __shared__ int s[256];
  int t = threadIdx.x;
  int base = blockIdx.x * 1024 + t * 4;
  int c0 = (base + 0 < NN) ? cnt[base + 0] : 0;
  int c1 = (base + 1 < NN) ? cnt[base + 1] : 0;
  int c2 = (base + 2 < NN) ? cnt[base + 2] : 0;
  int c3 = (base + 3 < NN) ? cnt[base + 3] : 0;
  int tsum = c0 + c1 + c2 + c3;
  s[t] = tsum;
  __syncthreads();
  for (int o = 1; o < 256; o <<= 1) {
    int v = (t >= o) ? s[t - o] : 0;
    __syncthreads();
    s[t] += v;
    __syncthreads();
  }
  int excl = s[t] - tsum;
  if (base + 0 < NN) off[base + 0] = excl;
  if (base + 1 < NN) off[base + 1] = excl + c0;
  if (base + 2 < NN) off[base + 2] = excl + c0 + c1;
  if (base + 3 < NN) off[base + 3] = excl + c0 + c1 + c2;
  if (t == 255) bsum[blockIdx.x] = s[255];
}

__global__ __launch_bounds__(256) void k_scan2(const int* __restrict__ bsum,
    int* __restrict__ bbase) {
  __shared__ int s[256];
  int t = threadIdx.x;
  int v0 = (t < SCAN_BLKS) ? bsum[t] : 0;
  s[t] = v0;
  __syncthreads();
  for (int o = 1; o < 256; o <<= 1) {
    int v = (t >= o) ? s[t - o] : 0;
    __syncthreads();
    s[t] += v;
    __syncthreads();
  }
  if (t < SCAN_BLKS) bbase[t] = s[t] - v0;
}

__global__ __launch_bounds__(256) void k_scan3(int* __restrict__ off,
    const int* __restrict__ bbase, int* __restrict__ nxt) {
  int i = blockIdx.x * 256 + threadIdx.x;
  if (i < NN) {
    int v = off[i] + bbase[i >> 10];
    off[i] = v;
    nxt[i] = v;
  }
  if (i == 0) off[NN] = NE;
}

// ---------- fill CSR records: {row, packed_ea, norm_bits, 0} ----------
__global__ __launch_bounds__(256) void k_fill(const int* __restrict__ ei,
    const int* __restrict__ ea, const float* __restrict__ dis,
    int* __restrict__ nxt, int4* __restrict__ recs) {
  int e = blockIdx.x * 256 + threadIdx.x;
  if (e >= NE) return;
  int r = ei[e], c = ei[NE + e];
  int pa = ea[e * 3 + 0] + ea[e * 3 + 1] * 10 + ea[e * 3 + 2] * 100;
  float nr = dis[r] * dis[c];
  int pos = atomicAdd(&nxt[c], 1);
  recs[pos] = make_int4(r, pa, __float_as_int(nr), 0);
}

// ---------- combined bond table (BF16, R17): btc[pa][d] ----------
// bf16 halves agg's per-edge btc L2 stream (512->256 B/edge) and halves the
// btc load instruction count (4x float4 -> 2x s8v).
__global__ __launch_bounds__(256) void k_btc(const float* __restrict__ bt,
    ushort* __restrict__ btc) {
  int idx = blockIdx.x * 256 + threadIdx.x;       // 1000*128 exact
  int p = idx >> 7, d = idx & 127;
  int a = p % 10, b = (p / 10) % 10, c = p / 100;
  btc[idx] = f2bf(bt[(0 * BV + a) * DD + d] + bt[(1 * BV + b) * DD + d]
                + bt[(2 * BV + c) * DD + d]);
}

// ---------- W -> bf16 ----------
__global__ __launch_bounds__(256) void k_wconv(const float* __restrict__ W,
    ushort* __restrict__ Wbf) {
  int i = blockIdx.x * 256 + threadIdx.x;         // 5*128*128 exact
  Wbf[i] = f2bf(W[i]);
}

// ---------- MFMA GEMM: hl(BF16) = A' @ Wl^T + bl ----------
// mode0: A' = srcbf (bf16 h from encode, = acts slot 0).
// mode1: A' = relu(pre_fp16*scale+shift); A' (bf16) stored to actl.
// mode2: like mode1 but folds the h still in actl: store bf16(h + A').
// pre is FP16; BN fold in-kernel from the PREVIOUS layer's stat slice
// (per-layer gsum/gss slices, R17 -- no in-loop memsets needed).
__global__ __launch_bounds__(256) void k_gemm(const ushort* __restrict__ srcbf,
    const ushort* __restrict__ srcp, const ushort* __restrict__ Wbf,
    const float* __restrict__ bl, const float* __restrict__ gsum,
    const float* __restrict__ gss, const float* __restrict__ gmm,
    const float* __restrict__ bbn, ushort* __restrict__ actl,
    ushort* __restrict__ hl, int mode) {
  __shared__ float s_sc[DD], s_sh[DD];
  int t = threadIdx.x;
  int lane = t & 63, wave = t >> 6;
  int col = lane & 15, quad = lane >> 4;
  int nb = blockIdx.x * 128 + wave * 32;
  int r0 = nb + col, r1 = nb + 16 + col;
  bool v0 = r0 < NN, v1 = r1 < NN;
  long a0off = (long)(v0 ? r0 : NN - 1) * DD;
  long a1off = (long)(v1 ? r1 : NN - 1) * DD;

  s8v af0[4], af1[4];                             // A fragments, 4 k-slices

  if (mode == 0) {
#pragma unroll
    for (int ks = 0; ks < 4; ++ks) {              // 8 loads, one burst
      int k0 = ks * 32 + quad * 8;
      af0[ks] = *(const s8v*)&srcbf[a0off + k0];
      af1[ks] = *(const s8v*)&srcbf[a1off + k0];
    }
  } else {
    if (t < DD) {                                 // BN fold: stats -> scale/shift
      float m = gsum[t] * (1.0f / NN);
      float v = gss[t] * (1.0f / NN) - m * m;
      float sc = gmm[t] * rsqrtf(v + EPSV);
      s_sc[t] = sc;
      s_sh[t] = bbn[t] - m * sc;
    }
    __syncthreads();
    s8v pF0[4], pF1[4];                           // fp16 pre, one burst (8 loads)
#pragma unroll
    for (int ks = 0; ks < 4; ++ks) {
      int k0 = ks * 32 + quad * 8;
      pF0[ks] = *(const s8v*)&srcp[a0off + k0];
      pF1[ks] = *(const s8v*)&srcp[a1off + k0];
    }
#pragma unroll
    for (int ks = 0; ks < 4; ++ks) {              // activation + pack (VALU)
      int k0 = ks * 32 + quad * 8;
      float scv[8], shv[8];
#pragma unroll
      for (int j = 0; j < 8; ++j) { scv[j] = s_sc[k0 + j]; shv[j] = s_sh[k0 + j]; }
#pragma unroll
      for (int j = 0; j < 8; ++j) {
        float w = fmaxf(h2f((ushort)pF0[ks][j]) * scv[j] + shv[j], 0.f);
        af0[ks][j] = (short)f2bf(w);
        float u = fmaxf(h2f((ushort)pF1[ks][j]) * scv[j] + shv[j], 0.f);
        af1[ks][j] = (short)f2bf(u);
      }
    }
    // store A' (bf16); mode2 folds the h currently in actl
    if (v0) {
#pragma unroll
      for (int ks = 0; ks < 4; ++ks) {
        int k0 = ks * 32 + quad * 8;
        s8v st = af0[ks];
        if (mode == 2) {
          s8v h8 = *(const s8v*)&actl[a0off + k0];
#pragma unroll
          for (int j = 0; j < 8; ++j)
            st[j] = (short)f2bf(bf2f((ushort)h8[j]) + bf2f((ushort)af0[ks][j]));
        }
        *(s8v*)&actl[a0off + k0] = st;
      }
    }
    if (v1) {
#pragma unroll
      for (int ks = 0; ks < 4; ++ks) {
        int k0 = ks * 32 + quad * 8;
        s8v st = af1[ks];
        if (mode == 2) {
          s8v h8 = *(const s8v*)&actl[a1off + k0];
#pragma unroll
          for (int j = 0; j < 8; ++j)
            st[j] = (short)f2bf(bf2f((ushort)h8[j]) + bf2f((ushort)af1[ks][j]));
        }
        *(s8v*)&actl[a1off + k0] = st;
      }
    }
  }

  f4v acc[2][8];
#pragma unroll
  for (int i = 0; i < 2; ++i)
#pragma unroll
    for (int j = 0; j < 8; ++j) acc[i][j] = (f4v)0.f;

#pragma unroll
  for (int ks = 0; ks < 4; ++ks) {                // MFMA loop: W loads (L2) + 64 MFMA
    int k0 = ks * 32 + quad * 8;
#pragma unroll
    for (int j = 0; j < 8; ++j) {                 // B[k][n=col] for out-tile j = W[j*16+col][k]
      s8v bf = *(const s8v*)&Wbf[(j * 16 + col) * DD + k0];
      acc[0][j] = __builtin_amdgcn_mfma_f32_16x16x32_bf16(af0[ks], bf, acc[0][j], 0, 0, 0);
      acc[1][j] = __builtin_amdgcn_mfma_f32_16x16x32_bf16(af1[ks], bf, acc[1][j], 0, 0, 0);
    }
  }

  float bb[8];
#pragma unroll
  for (int j = 0; j < 8; ++j) bb[j] = bl[j * 16 + col];
#pragma unroll
  for (int i = 0; i < 2; ++i) {
    int rowb = nb + i * 16 + quad * 4;            // D: col=lane&15, row=quad*4+reg
#pragma unroll
    for (int r = 0; r < 4; ++r) {
      int n = rowb + r;
      if (n < NN) {
#pragma unroll
        for (int j = 0; j < 8; ++j)
          hl[(long)n * DD + j * 16 + col] = f2bf(acc[i][j][r] + bb[j]);
      }
    }
  }
}

// ---------- gather-aggregate + self term + BN partials ----------
// EIGHTH-wave (8 lanes) owns a CONTIGUOUS run of 8 nodes: lane covers
// d = (lane&7)*16 .. +15 (32B bf16 gathers; btc now bf16 -> 32B, was 64B fp32).
// Block = 256 nodes, grid 782. Rolling 2-record recs prefetch, 2-edge unroll,
// fp16 pre store. Stats accumulate into this layer's gsum/gss slice.
__global__ __launch_bounds__(256) void k_aggregate(const ushort* __restrict__ hl,
    const int* __restrict__ off, const int4* __restrict__ recs,
    const ushort* __restrict__ btc, const float* __restrict__ rootl,
    const float* __restrict__ invd, ushort* __restrict__ pre,
    float* __restrict__ gsum, float* __restrict__ gss) {
  __shared__ float redS[256][17], redQ[256][17];   // +1 pad: conflict-free
  int t = threadIdx.x;
  int ql = t & 7;                                  // lane within eighth-wave
  int qs = t >> 3;                                 // chain slot 0..31
  int d0 = ql * 16;
  int base = blockIdx.x * 256 + qs * 8;
  float rt[16];
#pragma unroll
  for (int j = 0; j < 16; ++j) rt[j] = rootl[d0 + j];
  float sa[16], qa[16];
#pragma unroll
  for (int j = 0; j < 16; ++j) { sa[j] = 0.f; qa[j] = 0.f; }
  if (base < NN) {
    int eptr = off[base];
    int enext = off[base + 1];
    int4 r0 = recs[(eptr < NE) ? eptr : (NE - 1)];           // rolling prefetch regs
    int4 r1 = recs[(eptr + 1 < NE) ? eptr + 1 : (NE - 1)];
#pragma unroll 1
    for (int j = 0; j < 8; ++j) {
      int n = base + j;
      int ia = base + j + 2; if (ia > NN) ia = NN;
      int e_after = off[ia];                       // issued early, used next iter
      int eend = enext;
      s8v sv0 = *(const s8v*)&hl[(long)n * DD + d0];         // self-term (bf16)
      s8v sv1 = *(const s8v*)&hl[(long)n * DD + d0 + 8];
      float iv = invd[n];
      float acc[16];
#pragma unroll
      for (int k = 0; k < 16; ++k) acc[k] = 0.f;
      while (eptr + 2 <= eend) {                   // 2 edges per trip
        int4 ra = r0, rb = r1;
        int p0 = eptr + 2; if (p0 >= NE) p0 = NE - 1;
        int p1 = eptr + 3; if (p1 >= NE) p1 = NE - 1;
        r0 = recs[p0];                             // prefetch next pair
        r1 = recs[p1];
        s8v ha0 = *(const s8v*)&hl[(long)ra.x * DD + d0];    // 32B bf16 gather
        s8v ha1 = *(const s8v*)&hl[(long)ra.x * DD + d0 + 8];
        s8v ea0 = *(const s8v*)&btc[ra.y * DD + d0];         // 32B bf16 btc
        s8v ea1 = *(const s8v*)&btc[ra.y * DD + d0 + 8];
        s8v hb0 = *(const s8v*)&hl[(long)rb.x * DD + d0];
        s8v hb1 = *(const s8v*)&hl[(long)rb.x * DD + d0 + 8];
        s8v eb0 = *(const s8v*)&btc[rb.y * DD + d0];
        s8v eb1 = *(const s8v*)&btc[rb.y * DD + d0 + 8];
        float na = __int_as_float(ra.z);
        float nb = __int_as_float(rb.z);
#pragma unroll
        for (int k = 0; k < 8; ++k) {
          acc[k]     += fmaxf(bf2f((ushort)ha0[k]) + bf2f((ushort)ea0[k]), 0.f) * na
                      + fmaxf(bf2f((ushort)hb0[k]) + bf2f((ushort)eb0[k]), 0.f) * nb;
          acc[8 + k] += fmaxf(bf2f((ushort)ha1[k]) + bf2f((ushort)ea1[k]), 0.f) * na
                      + fmaxf(bf2f((ushort)hb1[k]) + bf2f((ushort)eb1[k]), 0.f) * nb;
        }
        eptr += 2;
      }
      if (eptr < eend) {                           // odd leftover edge
        int4 ra = r0;
        int4 tmp = r1;
        int p0 = eptr + 2; if (p0 >= NE) p0 = NE - 1;
        r1 = recs[p0];                             // maintain rolling invariant
        r0 = tmp;
        s8v hv0 = *(const s8v*)&hl[(long)ra.x * DD + d0];
        s8v hv1 = *(const s8v*)&hl[(long)ra.x * DD + d0 + 8];
        s8v ev0 = *(const s8v*)&btc[ra.y * DD + d0];
        s8v ev1 = *(const s8v*)&btc[ra.y * DD + d0 + 8];
        float nr = __int_as_float(ra.z);
#pragma unroll
        for (int k = 0; k < 8; ++k) {
          acc[k]     += fmaxf(bf2f((ushort)hv0[k]) + bf2f((ushort)ev0[k]), 0.f) * nr;
          acc[8 + k] += fmaxf(bf2f((ushort)hv1[k]) + bf2f((ushort)ev1[k]), 0.f) * nr;
        }
        eptr += 1;
      }
      float pv[16];
#pragma unroll
      for (int k = 0; k < 8; ++k) {
        pv[k]     = acc[k]     + fmaxf(bf2f((ushort)sv0[k]) + rt[k],     0.f) * iv;
        pv[8 + k] = acc[8 + k] + fmaxf(bf2f((ushort)sv1[k]) + rt[8 + k], 0.f) * iv;
      }
      s8v pq0, pq1;                                // pre stored as fp16 (32B)
#pragma unroll
      for (int k = 0; k < 8; ++k) {
        pq0[k] = (short)f2h(pv[k]);
        pq1[k] = (short)f2h(pv[8 + k]);
      }
      *(s8v*)&pre[(long)n * DD + d0] = pq0;
      *(s8v*)&pre[(long)n * DD + d0 + 8] = pq1;
#pragma unroll
      for (int k = 0; k < 16; ++k) {
        sa[k] += pv[k];
        qa[k] += pv[k] * pv[k];
      }
      enext = e_after;
    }
  }
#pragma unroll
  for (int k = 0; k < 16; ++k) { redS[t][k] = sa[k]; redQ[t][k] = qa[k]; }
  __syncthreads();
  if (t < 128) {                                   // d = t; ql=d>>4, c=d&15
    int qq = t >> 4, c = t & 15;
    float S = 0.f, Q = 0.f;
#pragma unroll
    for (int h = 0; h < 32; ++h) {
      S += redS[h * 8 + qq][c];
      Q += redQ[h * 8 + qq][c];
    }
    atomicAdd(&gsum[t], S);
    atomicAdd(&gss[t], Q);
  }
}

// ---------- final: out = (h+act0) + act1 + act2 + act3 + (pre4*scale4 + shift4)
// Pure write of out; scale4/shift4 computed in-kernel; pre4 read as fp16. ----------
__global__ __launch_bounds__(256) void k_apply_final(const ushort* __restrict__ preh,
    const ushort* __restrict__ acts, const float* __restrict__ gsum,
    const float* __restrict__ gss, const float* __restrict__ gmm,
    const float* __restrict__ bbn, float* __restrict__ out) {
  __shared__ float s_sc[DD], s_sh[DD];
  const int NDH = NN * DD / 2;                    // uint elements per slot
  int t = threadIdx.x;
  if (t < DD) {
    float m = gsum[t] * (1.0f / NN);
    float v = gss[t] * (1.0f / NN) - m * m;
    float sc = gmm[t] * rsqrtf(v + EPSV);
    s_sc[t] = sc;
    s_sh[t] = bbn[t] - m * sc;
  }
  __syncthreads();
  int idx = blockIdx.x * 256 + t;                 // N*D/2 exact
  int dp = idx & 63;
  uint a0 = ((const uint*)acts)[idx];
  uint a1 = ((const uint*)acts)[idx + NDH];
  uint a2 = ((const uint*)acts)[idx + 2 * NDH];
  uint a3 = ((const uint*)acts)[idx + 3 * NDH];
  uint pv = ((const uint*)preh)[idx];
  float2 o;
  o.x = bf2f((ushort)a0) + bf2f((ushort)a1) + bf2f((ushort)a2) + bf2f((ushort)a3)
      + h2f((ushort)pv) * s_sc[dp * 2] + s_sh[dp * 2];
  o.y = bf2f((ushort)(a0 >> 16)) + bf2f((ushort)(a1 >> 16)) + bf2f((ushort)(a2 >> 16))
      + bf2f((ushort)(a3 >> 16))
      + h2f((ushort)(pv >> 16)) * s_sc[dp * 2 + 1] + s_sh[dp * 2 + 1];
  *(float2*)&out[idx * 2] = o;
}

extern "C" void kernel_launch(void* const* d_in, const int* in_sizes, int n_in,
                              void* d_out, int out_size, void* d_ws, size_t ws_size,
                              hipStream_t stream) {
  const int*   x     = (const int*)d_in[0];
  const int*   ei    = (const int*)d_in[1];
  const int*   ea    = (const int*)d_in[2];
  const float* at    = (const float*)d_in[3];
  const float* bt    = (const float*)d_in[4];
  const float* W     = (const float*)d_in[5];
  const float* b     = (const float*)d_in[6];
  const float* root  = (const float*)d_in[7];
  const float* gamma = (const float*)d_in[8];
  const float* beta  = (const float*)d_in[9];
  float* out = (float*)d_out;

  char* ws = (char*)d_ws;
  size_t ND = (size_t)NN * DD;
  ushort* hl   = (ushort*)ws;                       // ND bf16
  ushort* pre  = hl + ND;                           // ND fp16
  ushort* acts = pre + ND;                          // 4*ND bf16; slot0: h then h+act0
  int4*   recs = (int4*)(acts + 4 * ND);            // NE * 16B (byte off 12*ND, 16B-aligned)
  ushort* Wbf  = (ushort*)(recs + NE);              // 5*128*128 bf16
  ushort* btc  = Wbf + NL * DD * DD;                // 1000*128 bf16 (256 KB)
  float*  deg  = (float*)(btc + 1000 * DD);         // N
  float*  dis  = deg + NN;                          // N
  float*  invd = dis + NN;                          // N
  int*    cnt  = (int*)(invd + NN);                 // N
  int*    offa = cnt + NN;                          // N+1 (+3 pad)
  int*    nxt  = offa + NN + 4;                     // N
  int*    bsum = nxt + NN;                          // 256
  int*    bbase= bsum + 256;                        // 256
  float*  gsum = (float*)(bbase + 256);             // NL*D (per-layer slices)
  float*  gss  = gsum + NL * DD;                    // NL*D
  ushort* atb  = (ushort*)(gss + NL * DD);          // 9*100*128 bf16 (230 KB)

  // ---- precompute ----
  hipMemsetAsync(gsum, 0, 2 * NL * DD * sizeof(float), stream);  // all stat slices
  k_deg_init<<<(NN + 255) / 256, 256, 0, stream>>>(deg, cnt);
  k_deg_count<<<(NE + 255) / 256, 256, 0, stream>>>(ei, deg, cnt);
  k_deg_fin<<<(NN + 255) / 256, 256, 0, stream>>>(deg, dis, invd);
  k_scan1<<<SCAN_BLKS, 256, 0, stream>>>(cnt, offa, bsum);
  k_scan2<<<1, 256, 0, stream>>>(bsum, bbase);
  k_scan3<<<(NN + 255) / 256, 256, 0, stream>>>(offa, bbase, nxt);
  k_fill<<<(NE + 255) / 256, 256, 0, stream>>>(ei, ea, dis, nxt, recs);
  k_btc<<<1000 * DD / 256, 256, 0, stream>>>(bt, btc);
  k_wconv<<<NL * DD * DD / 256, 256, 0, stream>>>(W, Wbf);
  k_atc<<<9 * AV * DD / 256, 256, 0, stream>>>(at, atb);
  k_encode<<<NN * 32 / 256, 256, 0, stream>>>(x, atb, acts);

  // ---- layers ----
  for (int l = 0; l < NL; ++l) {
    int mode = (l == 0) ? 0 : ((l == 1) ? 2 : 1);
    int lp = (l == 0) ? 0 : l - 1;                 // previous layer's stat slice
    k_gemm<<<(NN + 127) / 128, 256, 0, stream>>>(
        acts, pre, Wbf + (size_t)l * DD * DD, b + l * DD,
        gsum + (size_t)lp * DD, gss + (size_t)lp * DD,
        gamma + (size_t)lp * DD, beta + (size_t)lp * DD,
        acts + (size_t)(l == 0 ? 0 : l - 1) * ND,
        hl, mode);
    k_aggregate<<<(NN + 255) / 256, 256, 0, stream>>>(hl, offa, recs, btc,
        root + l * DD, invd, pre, gsum + (size_t)l * DD, gss + (size_t)l * DD);
  }
  k_apply_final<<<(int)(ND / 2 / 256), 256, 0, stream>>>(pre, acts,
      gsum + 4 * DD, gss + 4 * DD, gamma + 4 * DD, beta + 4 * DD, out);
}